// Round 9
// baseline (2605.354 us; speedup 1.0000x reference)
//
#include <hip/hip_runtime.h>
#include <cstdint>
#include <cstddef>

#define NB 4
#define NN 4096
#define KK 16
#define DP 64
#define DM 128
#define EPS 1e-5f

typedef __attribute__((ext_vector_type(8))) short bf16x8;
typedef __attribute__((ext_vector_type(4))) float f32x4;
typedef __attribute__((ext_vector_type(4))) unsigned int u32x4;

__device__ __forceinline__ float lrelu(float x){ return x >= 0.f ? x : 0.2f*x; }

__device__ __forceinline__ unsigned short f2bf(float x){
  union { float f; uint32_t u; } a; a.f = x;
  return (unsigned short)((a.u + 0x7fffu + ((a.u >> 16) & 1u)) >> 16);
}
__device__ __forceinline__ float bf2f(unsigned short h){
  union { uint32_t u; float f; } a; a.u = ((uint32_t)h) << 16; return a.f;
}
__device__ __forceinline__ uint32_t pk2(float a, float b){
  return (uint32_t)f2bf(a) | ((uint32_t)f2bf(b) << 16);
}

__device__ __forceinline__ f32x4 mfma16(bf16x8 a, bf16x8 b, f32x4 c){
  return __builtin_amdgcn_mfma_f32_16x16x32_bf16(a, b, c, 0, 0, 0);
}
__device__ __forceinline__ float sx16(float v, int m){ return __shfl_xor(v, m, 16); }
__device__ __forceinline__ f32x4 vmax4(f32x4 a, f32x4 b){
  f32x4 r; r[0]=fmaxf(a[0],b[0]); r[1]=fmaxf(a[1],b[1]); r[2]=fmaxf(a[2],b[2]); r[3]=fmaxf(a[3],b[3]); return r;
}

// ---------------------------------------------------------------- sq norms
__global__ __launch_bounds__(256) void k_sqnorm(const float* __restrict__ feats,
                                                float* __restrict__ sqn){
  const int i = blockIdx.x*256 + threadIdx.x;
  const int b = i >> 12, n = i & (NN-1);
  const float* f = feats + (size_t)b*DP*NN + n;
  float s = 0.f;
  #pragma unroll
  for (int c=0;c<DP;c++){ const float v = f[(size_t)c*NN]; s += v*v; }
  sqn[i] = s;
}

// ---------------------------------------------------------------- feats -> bf16 hi/lo MFMA fragments + point-major f32 copy
__global__ __launch_bounds__(256) void k_fprep(const float* __restrict__ feats,
                                               unsigned short* __restrict__ cfrag,
                                               unsigned short* __restrict__ qfrag,
                                               float* __restrict__ fpm){
  __shared__ float ft[DP][65];
  const int t = threadIdx.x;
  const int b = blockIdx.x >> 6;
  const int n0 = (blockIdx.x & 63) * 64;
  for (int i=t; i<DP*64; i+=256){
    const int dim = i >> 6, pt = i & 63;
    ft[dim][pt] = feats[(size_t)b*DP*NN + (size_t)dim*NN + n0 + pt];
  }
  __syncthreads();
  for (int i=t; i<64*DP; i+=256){
    const int pt = i >> 6, dim = i & 63;
    fpm[((size_t)(b*NN) + n0 + pt)*DP + dim] = ft[dim][pt];
  }
  #pragma unroll
  for (int v = t; v < 1024; v += 256){
    const int l = v & 63, hl = (v>>6)&1, ks = (v>>7)&1, ntl = v>>8;
    const int ptl = ntl*16 + (l&15);
    const int d0 = ks*32 + (l>>4)*8;
    unsigned short qo[8], co[8];
    #pragma unroll
    for (int j=0;j<8;j++){
      const float x = ft[d0+j][ptl];
      const unsigned short qh = f2bf(x);
      const float y = -2.f*x;
      const unsigned short ch = f2bf(y);
      qo[j] = hl ? f2bf(x - bf2f(qh)) : qh;
      co[j] = hl ? f2bf(y - bf2f(ch)) : ch;
    }
    const int nt = (n0 >> 4) + ntl;
    const size_t off = ((size_t)((b*256 + nt)*4 + ks*2 + hl))*512 + l*8;
    uint4 qv, cv;
    qv.x = (uint32_t)qo[0] | ((uint32_t)qo[1]<<16);
    qv.y = (uint32_t)qo[2] | ((uint32_t)qo[3]<<16);
    qv.z = (uint32_t)qo[4] | ((uint32_t)qo[5]<<16);
    qv.w = (uint32_t)qo[6] | ((uint32_t)qo[7]<<16);
    cv.x = (uint32_t)co[0] | ((uint32_t)co[1]<<16);
    cv.y = (uint32_t)co[2] | ((uint32_t)co[3]<<16);
    cv.z = (uint32_t)co[4] | ((uint32_t)co[5]<<16);
    cv.w = (uint32_t)co[6] | ((uint32_t)co[7]<<16);
    *reinterpret_cast<uint4*>(qfrag + off) = qv;
    *reinterpret_cast<uint4*>(cfrag + off) = cv;
  }
}

// ---------------------------------------------------------------- MFMA kNN: approx top-32 candidates per query
__global__ __launch_bounds__(256) void k_knn2(const unsigned short* __restrict__ cfrag,
                                              const unsigned short* __restrict__ qfrag,
                                              const float* __restrict__ sqn,
                                              int* __restrict__ cand){
  const int t = threadIdx.x, w = t >> 6, l = t & 63, g = l >> 4;
  const int b = blockIdx.x >> 6;
  const int qt = (blockIdx.x & 63)*4 + w;

  bf16x8 qf00, qf01, qf10, qf11;
  {
    const unsigned short* qb = qfrag + ((size_t)(b*256 + qt))*2048 + l*8;
    qf00 = *reinterpret_cast<const bf16x8*>(qb);
    qf01 = *reinterpret_cast<const bf16x8*>(qb + 512);
    qf10 = *reinterpret_cast<const bf16x8*>(qb + 1024);
    qf11 = *reinterpret_cast<const bf16x8*>(qb + 1536);
  }
  const unsigned short* cb = cfrag + ((size_t)(b*256))*2048 + l*8;

  float dd[16]; int ii[16];
  #pragma unroll
  for (int s=0;s<16;s++){ dd[s]=3.4e38f; ii[s]=0; }
  float dmax = 3.4e38f;

  bf16x8 c00 = *reinterpret_cast<const bf16x8*>(cb);
  bf16x8 c01 = *reinterpret_cast<const bf16x8*>(cb + 512);
  bf16x8 c10 = *reinterpret_cast<const bf16x8*>(cb + 1024);
  bf16x8 c11 = *reinterpret_cast<const bf16x8*>(cb + 1536);

  const float* sqb = sqn + b*NN + g*4;

  #pragma unroll 1
  for (int ct=0; ct<256; ++ct){
    bf16x8 n00, n01, n10, n11;
    if (ct < 255){
      const unsigned short* nb_ = cb + (size_t)(ct+1)*2048;
      n00 = *reinterpret_cast<const bf16x8*>(nb_);
      n01 = *reinterpret_cast<const bf16x8*>(nb_ + 512);
      n10 = *reinterpret_cast<const bf16x8*>(nb_ + 1024);
      n11 = *reinterpret_cast<const bf16x8*>(nb_ + 1536);
    }
    f32x4 acc = {0.f,0.f,0.f,0.f};
    acc = mfma16(c00, qf00, acc);
    acc = mfma16(c10, qf10, acc);
    acc = mfma16(c00, qf01, acc);
    acc = mfma16(c01, qf00, acc);
    acc = mfma16(c10, qf11, acc);
    acc = mfma16(c11, qf10, acc);
    const float4 sq4 = *reinterpret_cast<const float4*>(&sqb[ct*16]);
    const float d0 = acc[0] + sq4.x;
    const float d1 = acc[1] + sq4.y;
    const float d2 = acc[2] + sq4.z;
    const float d3 = acc[3] + sq4.w;
    const float mn = fminf(fminf(d0,d1), fminf(d2,d3));
    if (mn < dmax){
      const int cbase = ct*16 + g*4;
      float dv[4] = {d0,d1,d2,d3};
      #pragma unroll
      for (int u=0;u<4;u++){
        if (dv[u] < dmax){
          bool done=false;
          #pragma unroll
          for (int s=0;s<16;s++){
            if (!done && dd[s]==dmax){ dd[s]=dv[u]; ii[s]=cbase+u; done=true; }
          }
          dmax = dd[0];
          #pragma unroll
          for (int s=1;s<16;s++) dmax = fmaxf(dmax, dd[s]);
        }
      }
    }
    c00 = n00; c01 = n01; c10 = n10; c11 = n11;
  }

  const int q = qt*16 + (l & 15);
  int* op = cand + ((size_t)(b*NN) + q)*32;
  #pragma unroll 1
  for (int r=0; r<32; ++r){
    float bd = dd[0]; int bi = ii[0];
    #pragma unroll
    for (int s=1;s<16;s++){
      if (dd[s] < bd){ bd = dd[s]; bi = ii[s]; }
    }
    const int mi0 = bi;
    float od; int oi;
    od = __shfl_xor(bd, 16); oi = __shfl_xor(bi, 16);
    if (od < bd){ bd = od; bi = oi; }
    od = __shfl_xor(bd, 32); oi = __shfl_xor(bi, 32);
    if (od < bd){ bd = od; bi = oi; }
    const bool win = (bi == mi0);
    #pragma unroll
    for (int s=0;s<16;s++){
      if (win && ii[s]==bi) dd[s] = 3.4e38f;
    }
    if (g == 0) op[r] = bi;
  }
}

// ---------------------------------------------------------------- exact f32 refine: top-16 set from 32 candidates
__global__ __launch_bounds__(256) void k_refine(const float* __restrict__ fpm,
                                                const float* __restrict__ sqn,
                                                const int* __restrict__ cand,
                                                int* __restrict__ idx_ws){
  const int t = threadIdx.x, w = t >> 6, l = t & 63;
  const int q = blockIdx.x*4 + w;
  const int b = q >> 12;
  const int c = l & 31, h = l >> 5;
  const int mi = cand[(size_t)q*32 + c];
  const float* qv = fpm + (size_t)q*DP + h*32;
  const float* cv = fpm + ((size_t)(b*NN) + mi)*DP + h*32;
  float dot = 0.f;
  #pragma unroll
  for (int d=0; d<32; d+=4){
    const float4 a = *reinterpret_cast<const float4*>(&qv[d]);
    const float4 x = *reinterpret_cast<const float4*>(&cv[d]);
    dot += a.x*x.x; dot += a.y*x.y; dot += a.z*x.z; dot += a.w*x.w;
  }
  dot += __shfl_xor(dot, 32);
  const float dist = sqn[q] + sqn[b*NN + mi] - 2.f*dot;
  int rank = 0;
  #pragma unroll
  for (int j=0; j<32; j++){
    const float dj = __shfl(dist, j);
    const int   ij = __shfl(mi,  j);
    rank += (dj < dist || (dj == dist && ij < mi)) ? 1 : 0;
  }
  if (h == 0 && rank < KK) idx_ws[(size_t)q*KK + rank] = mi;
}

// ---------------------------------------------------------------- x (bf16 point-major) + q (f32 point-major), fused
__global__ __launch_bounds__(256) void k_xq(const float* __restrict__ feats,
                                            const float* __restrict__ W1,
                                            const float* __restrict__ bn1,
                                            const float* __restrict__ Wq,
                                            unsigned short* __restrict__ xbf,
                                            float* __restrict__ q_ws){
  __shared__ float W1s[DM][DP+1];
  __shared__ float ft[DP][64];
  __shared__ float xt[64][DM+4];
  __shared__ float Wqs[DM][DM+4];
  __shared__ float bS[DM], bT[DM];
  const int t = threadIdx.x;
  const int b = blockIdx.x >> 6;
  const int n0 = (blockIdx.x & 63) * 64;
  for (int i=t; i<DM*DP; i+=256){ W1s[i>>6][i&63] = W1[i]; }
  if (t < DM){
    float g = bn1[t], be = bn1[DM+t], mn = bn1[2*DM+t], vr = bn1[3*DM+t];
    float s = g*rsqrtf(vr+EPS); bS[t]=s; bT[t]=be-mn*s;
  }
  for (int i=t; i<DP*64; i+=256){
    const int c = i>>6, j = i&63;
    ft[c][j] = feats[(size_t)b*DP*NN + (size_t)c*NN + n0 + j];
  }
  for (int i=t; i<DM*DM; i+=256){ Wqs[i>>7][i&127] = Wq[i]; }
  __syncthreads();
  const int j = t >> 2, cq = t & 3;
  {
    float acc[32];
    #pragma unroll
    for (int i=0;i<32;i++) acc[i]=0.f;
    for (int c=0;c<DP;c++){
      const float fv = ft[c][j];
      #pragma unroll
      for (int i=0;i<32;i++) acc[i] += W1s[cq+4*i][c]*fv;
    }
    #pragma unroll
    for (int i=0;i<32;i++){
      const int ch = cq + 4*i;
      xt[j][ch] = lrelu(acc[i]*bS[ch] + bT[ch]);
    }
  }
  __syncthreads();
  for (int i=t; i<64*32; i+=256){
    const int pt = i >> 5, c4 = (i & 31)*4;
    ushort4 o;
    o.x = f2bf(xt[pt][c4+0]); o.y = f2bf(xt[pt][c4+1]);
    o.z = f2bf(xt[pt][c4+2]); o.w = f2bf(xt[pt][c4+3]);
    *reinterpret_cast<ushort4*>(&xbf[((size_t)(b*NN) + n0 + pt)*DM + c4]) = o;
  }
  {
    float acc[32];
    #pragma unroll
    for (int i=0;i<32;i++) acc[i]=0.f;
    for (int c=0;c<DM;c+=4){
      const float4 xv = *reinterpret_cast<const float4*>(&xt[j][c]);
      #pragma unroll
      for (int i=0;i<32;i++){
        const float4 wv = *reinterpret_cast<const float4*>(&Wqs[cq+4*i][c]);
        acc[i] += wv.x*xv.x + wv.y*xv.y + wv.z*xv.z + wv.w*xv.w;
      }
    }
    float* op = q_ws + ((size_t)(b*NN) + n0 + j)*DM;
    #pragma unroll
    for (int i=0;i<32;i++) op[cq+4*i] = acc[i];
  }
}

// ---------------------------------------------------------------- weight prep: 168 bf16 MFMA fragments
__global__ __launch_bounds__(256) void k_wprep2(
    const float* __restrict__ Wd1, const float* __restrict__ bnd1,
    const float* __restrict__ Wd2, const float* __restrict__ bnd2,
    const float* __restrict__ Wg1, const float* __restrict__ bng1,
    const float* __restrict__ Wg2, const float* __restrict__ bng2,
    const float* __restrict__ Wk, const float* __restrict__ Wv,
    unsigned short* __restrict__ wfrag){
  const int i = blockIdx.x*256 + threadIdx.x;
  if (i >= 168*64) return;
  const int f = i >> 6, l = i & 63;
  const int r16 = l & 15, kg = (l >> 4) * 8;
  unsigned short o8[8];
  if (f < 96){
    const int mat = f >> 5, tt = (f >> 2) & 7, ks = f & 3;
    const float* W; const float* bn;
    if (mat == 0){ W = Wd2; bn = bnd2; }
    else if (mat == 1){ W = Wg1; bn = bng1; }
    else { W = Wg2; bn = bng2; }
    const int row = tt*16 + r16;
    const float s = bn[row] * rsqrtf(bn[3*DM+row] + EPS);
    const float* src = W + (size_t)row*DM + ks*32 + kg;
    #pragma unroll
    for (int j=0;j<8;j++) o8[j] = f2bf(s * src[j]);
  } else if (f < 104){
    const int tt = f - 96;
    const int row = tt*16 + r16;
    const float s = bnd1[row] * rsqrtf(bnd1[3*DM+row] + EPS);
    #pragma unroll
    for (int j=0;j<8;j++){
      const int k = kg + j;
      o8[j] = (k < 3) ? f2bf(s * Wd1[row*3 + k]) : (unsigned short)0;
    }
  } else {
    const int fp = f - 104;
    const float* W = (fp < 32) ? Wk : Wv;
    const int r = fp & 31, tt = r >> 2, ks = r & 3;
    const int row = tt*16 + r16;
    const float* src = W + (size_t)row*DM + ks*32 + kg;
    #pragma unroll
    for (int j=0;j<8;j++) o8[j] = f2bf(src[j]);
  }
  uint4 v;
  v.x = (uint32_t)o8[0] | ((uint32_t)o8[1]<<16);
  v.y = (uint32_t)o8[2] | ((uint32_t)o8[3]<<16);
  v.z = (uint32_t)o8[4] | ((uint32_t)o8[5]<<16);
  v.w = (uint32_t)o8[6] | ((uint32_t)o8[7]<<16);
  *reinterpret_cast<uint4*>(wfrag + (size_t)i*8) = v;
}

// ---------------------------------------------------------------- fused MFMA attention v4 -- ABLATION TEMPLATE
// MODE 0: real (random gather + full compute)     -> res (final)
// MODE 1: self-gather (mi = contiguous) + full compute  -> res (overwritten by MODE 0)
// MODE 2: random gather + NO compute (int-sum keepalive) -> res (overwritten by MODE 0)
#define PPW 4

#define FR(fi) (*reinterpret_cast<const bf16x8*>(&wfrag[(size_t)(fi)*512 + l*8]))

#define H1_STEP(tt) { \
  f32x4 acc = {0.f,0.f,0.f,0.f}; \
  acc = mfma16(FR(96+(tt)), bv, acc); \
  const f32x4 sh = *reinterpret_cast<const f32x4*>(&bnT[0][(tt)*16 + g*4]); \
  uint2 hp; \
  hp.x = pk2(lrelu(acc[0]+sh[0]), lrelu(acc[1]+sh[1])); \
  hp.y = pk2(lrelu(acc[2]+sh[2]), lrelu(acc[3]+sh[3])); \
  *reinterpret_cast<uint2*>(&hb[hwb + (((tt)*2 + (g>>1))^p)*8]) = hp; }

#define RD_B() \
  const bf16x8 b0 = *reinterpret_cast<const bf16x8*>(&hb[p*128 + ((0*4+g)^p)*8]); \
  const bf16x8 b1 = *reinterpret_cast<const bf16x8*>(&hb[p*128 + ((1*4+g)^p)*8]); \
  const bf16x8 b2 = *reinterpret_cast<const bf16x8*>(&hb[p*128 + ((2*4+g)^p)*8]); \
  const bf16x8 b3 = *reinterpret_cast<const bf16x8*>(&hb[p*128 + ((3*4+g)^p)*8]);

#define PE_STEP(tt, PE) { \
  f32x4 acc = {0.f,0.f,0.f,0.f}; \
  acc = mfma16(FR(0+(tt)*4+0), b0, acc); \
  acc = mfma16(FR(0+(tt)*4+1), b1, acc); \
  acc = mfma16(FR(0+(tt)*4+2), b2, acc); \
  acc = mfma16(FR(0+(tt)*4+3), b3, acc); \
  const f32x4 sh = *reinterpret_cast<const f32x4*>(&bnT[1][(tt)*16 + g*4]); \
  PE[0]=lrelu(acc[0]+sh[0]); PE[1]=lrelu(acc[1]+sh[1]); \
  PE[2]=lrelu(acc[2]+sh[2]); PE[3]=lrelu(acc[3]+sh[3]); }

#define K_STEP(tt, PE) { \
  f32x4 acc = {0.f,0.f,0.f,0.f}; \
  acc = mfma16(FR(104+(tt)*4+0), xu0, acc); \
  acc = mfma16(FR(104+(tt)*4+1), xu1, acc); \
  acc = mfma16(FR(104+(tt)*4+2), xu2, acc); \
  acc = mfma16(FR(104+(tt)*4+3), xu3, acc); \
  const float4 qv = *reinterpret_cast<const float4*>(&qrow[(tt)*16 + g*4]); \
  uint2 hp; \
  hp.x = pk2(qv.x - acc[0] + PE[0], qv.y - acc[1] + PE[1]); \
  hp.y = pk2(qv.z - acc[2] + PE[2], qv.w - acc[3] + PE[3]); \
  *reinterpret_cast<uint2*>(&hb[hwb + (((tt)*2 + (g>>1))^p)*8]) = hp; }

#define G1_STEP(tt) { \
  f32x4 acc = {0.f,0.f,0.f,0.f}; \
  acc = mfma16(FR(32+(tt)*4+0), b0, acc); \
  acc = mfma16(FR(32+(tt)*4+1), b1, acc); \
  acc = mfma16(FR(32+(tt)*4+2), b2, acc); \
  acc = mfma16(FR(32+(tt)*4+3), b3, acc); \
  const f32x4 sh = *reinterpret_cast<const f32x4*>(&bnT[2][(tt)*16 + g*4]); \
  uint2 hp; \
  hp.x = pk2(lrelu(acc[0]+sh[0]), lrelu(acc[1]+sh[1])); \
  hp.y = pk2(lrelu(acc[2]+sh[2]), lrelu(acc[3]+sh[3])); \
  *reinterpret_cast<uint2*>(&hb[hwb + (((tt)*2 + (g>>1))^p)*8]) = hp; }

#define E_STEP(tt, E) { \
  f32x4 acc = {0.f,0.f,0.f,0.f}; \
  acc = mfma16(FR(64+(tt)*4+0), b0, acc); \
  acc = mfma16(FR(64+(tt)*4+1), b1, acc); \
  acc = mfma16(FR(64+(tt)*4+2), b2, acc); \
  acc = mfma16(FR(64+(tt)*4+3), b3, acc); \
  const f32x4 sh = *reinterpret_cast<const f32x4*>(&bnT[3][(tt)*16 + g*4]); \
  E[0]=lrelu(acc[0]+sh[0])*0.015625f; E[1]=lrelu(acc[1]+sh[1])*0.015625f; \
  E[2]=lrelu(acc[2]+sh[2])*0.015625f; E[3]=lrelu(acc[3]+sh[3])*0.015625f; }

#define EXP_STEP(E) { \
  E[0]=__expf(E[0]-m); E[1]=__expf(E[1]-m); E[2]=__expf(E[2]-m); E[3]=__expf(E[3]-m); }

#define RED1(vc, PE, E, r) { \
  float num = E[r]*((vc) + PE[r]); \
  float den = E[r]; \
  num += sx16(num,1); den += sx16(den,1); \
  num += sx16(num,2); den += sx16(den,2); \
  num += sx16(num,4); den += sx16(den,4); \
  num += sx16(num,8); den += sx16(den,8); \
  PE[r] = num * __builtin_amdgcn_rcpf(den); }

#define RED_STEP(tt, PE, E) { \
  f32x4 vacc = {0.f,0.f,0.f,0.f}; \
  vacc = mfma16(FR(136+(tt)*4+0), xu0, vacc); \
  vacc = mfma16(FR(136+(tt)*4+1), xu1, vacc); \
  vacc = mfma16(FR(136+(tt)*4+2), xu2, vacc); \
  vacc = mfma16(FR(136+(tt)*4+3), xu3, vacc); \
  RED1(vacc[0], PE, E, 0) RED1(vacc[1], PE, E, 1) \
  RED1(vacc[2], PE, E, 2) RED1(vacc[3], PE, E, 3) }

#define ST_STEP(tt, PE) { \
  float4 o; o.x=PE[0]; o.y=PE[1]; o.z=PE[2]; o.w=PE[3]; \
  *reinterpret_cast<float4*>(&res_ws[(size_t)gp*DM + (tt)*16 + g*4]) = o; }

template<int MODE>
__global__ __launch_bounds__(512, 2) void k_attn4t(
    const float* __restrict__ pos, const float* __restrict__ q_ws,
    const unsigned short* __restrict__ xbf,
    const int* __restrict__ idx_ws, const unsigned short* __restrict__ wfrag,
    const float* __restrict__ bnd1, const float* __restrict__ bnd2,
    const float* __restrict__ bng1, const float* __restrict__ bng2,
    float* __restrict__ res_ws){
  __shared__ __align__(16) unsigned short Hb[8][2048];
  __shared__ float bnT[4][DM];

  const int t = threadIdx.x;
  if (t < DM){
    const float* bp[4] = {bnd1, bnd2, bng1, bng2};
    #pragma unroll
    for (int s4=0;s4<4;s4++){
      const float g = bp[s4][t], be = bp[s4][DM+t], mn = bp[s4][2*DM+t], vr = bp[s4][3*DM+t];
      const float sc = g * rsqrtf(vr + EPS);
      bnT[s4][t] = be - mn*sc;
    }
  }
  __syncthreads();

  const int w = t >> 6, l = t & 63;
  const int p = l & 15, g = l >> 4;
  unsigned short* hb = Hb[w];
  const int hwb = p*128 + ((g & 1) * 4);

  #pragma unroll 1
  for (int pp = 0; pp < PPW; ++pp){
    const int gp = blockIdx.x*(8*PPW) + w*PPW + pp;
    const int b = gp >> 12, n = gp & (NN-1);
    const int mi = (MODE == 1) ? ((n & ~15) | p) : idx_ws[gp*KK + p];

    const unsigned short* xrow = xbf + ((size_t)(b*NN) + mi)*DM;

    if (MODE == 2){
      // pure-memory ablation: same gathers + q stream, no MFMA/LDS/wfrag
      u32x4 a0 = *reinterpret_cast<const u32x4*>(&xrow[ 0 + g*8]);
      u32x4 a1 = *reinterpret_cast<const u32x4*>(&xrow[32 + g*8]);
      u32x4 a2 = *reinterpret_cast<const u32x4*>(&xrow[64 + g*8]);
      u32x4 a3 = *reinterpret_cast<const u32x4*>(&xrow[96 + g*8]);
      u32x4 av = a0 + a1 + a2 + a3;
      uint32_t s = av[0] + av[1] + av[2] + av[3];
      const float* posb = pos + (size_t)b*3*NN;
      s += __float_as_uint(posb[n]) + __float_as_uint(posb[mi]);
      s += __float_as_uint(posb[NN+mi]) + __float_as_uint(posb[2*NN+mi]);
      const float* qrow = q_ws + (size_t)gp*DM;
      #pragma unroll
      for (int tt=0; tt<8; ++tt){
        const uint4 qv = *reinterpret_cast<const uint4*>(&qrow[tt*16 + g*4]);
        s += qv.x + qv.y + qv.z + qv.w;
      }
      if (p == 0){
        #pragma unroll
        for (int tt=0; tt<8; ++tt){
          uint4 o = make_uint4(s, s + tt, s*2u, s ^ (uint32_t)tt);
          *reinterpret_cast<uint4*>(&res_ws[(size_t)gp*DM + tt*16 + g*4]) = o;
        }
      }
      continue;
    }

    const bf16x8 xu0 = *reinterpret_cast<const bf16x8*>(&xrow[ 0 + g*8]);
    const bf16x8 xu1 = *reinterpret_cast<const bf16x8*>(&xrow[32 + g*8]);
    const bf16x8 xu2 = *reinterpret_cast<const bf16x8*>(&xrow[64 + g*8]);
    const bf16x8 xu3 = *reinterpret_cast<const bf16x8*>(&xrow[96 + g*8]);

    uint32_t bw0 = 0u, bw1 = 0u;
    if (g == 0){
      const float* posb = pos + (size_t)b*3*NN;
      const float rx = posb[n]      - posb[mi];
      const float ry = posb[NN+n]   - posb[NN+mi];
      const float rz = posb[2*NN+n] - posb[2*NN+mi];
      bw0 = pk2(rx, ry);
      bw1 = pk2(rz, 0.f);
    }
    u32x4 bwv = {bw0, bw1, 0u, 0u};
    const bf16x8 bv = __builtin_bit_cast(bf16x8, bwv);

    H1_STEP(0) H1_STEP(1) H1_STEP(2) H1_STEP(3)
    H1_STEP(4) H1_STEP(5) H1_STEP(6) H1_STEP(7)

    f32x4 pe0, pe1, pe2, pe3, pe4, pe5, pe6, pe7;
    {
      RD_B()
      PE_STEP(0, pe0) PE_STEP(1, pe1) PE_STEP(2, pe2) PE_STEP(3, pe3)
      PE_STEP(4, pe4) PE_STEP(5, pe5) PE_STEP(6, pe6) PE_STEP(7, pe7)
    }

    const float* qrow = q_ws + (size_t)gp*DM;
    K_STEP(0, pe0) K_STEP(1, pe1) K_STEP(2, pe2) K_STEP(3, pe3)
    K_STEP(4, pe4) K_STEP(5, pe5) K_STEP(6, pe6) K_STEP(7, pe7)

    {
      RD_B()
      G1_STEP(0) G1_STEP(1) G1_STEP(2) G1_STEP(3)
      G1_STEP(4) G1_STEP(5) G1_STEP(6) G1_STEP(7)
    }

    f32x4 e0, e1, e2, e3, e4, e5, e6, e7;
    {
      RD_B()
      E_STEP(0, e0) E_STEP(1, e1) E_STEP(2, e2) E_STEP(3, e3)
      E_STEP(4, e4) E_STEP(5, e5) E_STEP(6, e6) E_STEP(7, e7)
    }

    f32x4 mm = vmax4(vmax4(vmax4(e0,e1), vmax4(e2,e3)), vmax4(vmax4(e4,e5), vmax4(e6,e7)));
    float m = fmaxf(fmaxf(mm[0],mm[1]), fmaxf(mm[2],mm[3]));
    m = fmaxf(m, sx16(m,1)); m = fmaxf(m, sx16(m,2));
    m = fmaxf(m, sx16(m,4)); m = fmaxf(m, sx16(m,8));
    EXP_STEP(e0) EXP_STEP(e1) EXP_STEP(e2) EXP_STEP(e3)
    EXP_STEP(e4) EXP_STEP(e5) EXP_STEP(e6) EXP_STEP(e7)

    RED_STEP(0, pe0, e0) RED_STEP(1, pe1, e1) RED_STEP(2, pe2, e2) RED_STEP(3, pe3, e3)
    RED_STEP(4, pe4, e4) RED_STEP(5, pe5, e5) RED_STEP(6, pe6, e6) RED_STEP(7, pe7, e7)

    if (p == 0){
      ST_STEP(0, pe0) ST_STEP(1, pe1) ST_STEP(2, pe2) ST_STEP(3, pe3)
      ST_STEP(4, pe4) ST_STEP(5, pe5) ST_STEP(6, pe6) ST_STEP(7, pe7)
    }
  }
}

// ---------------------------------------------------------------- out = lrelu(bn2(W2@res)) + feats
__global__ __launch_bounds__(256) void k_out(const float* __restrict__ res_ws,
                                             const float* __restrict__ W2,
                                             const float* __restrict__ bn2,
                                             const float* __restrict__ feats,
                                             float* __restrict__ out){
  __shared__ float W2s[DP][DM+4];
  __shared__ float rt[128][DM+4];
  __shared__ float ob[DP][132];
  __shared__ float bS[DP], bT[DP];
  const int t = threadIdx.x;
  const int b = blockIdx.x >> 5;
  const int n0 = (blockIdx.x & 31) * 128;
  for (int i=t; i<DP*DM; i+=256){ W2s[i>>7][i&127] = W2[i]; }
  if (t < DP){
    float g=bn2[t], be=bn2[DP+t], mn=bn2[2*DP+t], vr=bn2[3*DP+t];
    float s = g*rsqrtf(vr+EPS); bS[t]=s; bT[t]=be-mn*s;
  }
  for (int i=t; i<128*DM; i+=256){
    const int j=i>>7, c=i&127;
    rt[j][c] = res_ws[((size_t)(b*NN)+n0+j)*DM + c];
  }
  __syncthreads();
  const int j = t>>1, cq = t&1;
  float acc[32];
  #pragma unroll
  for (int i=0;i<32;i++) acc[i]=0.f;
  for (int c=0;c<DM;c+=4){
    const float4 rv = *reinterpret_cast<const float4*>(&rt[j][c]);
    #pragma unroll
    for (int i=0;i<32;i++){
      const float4 wv = *reinterpret_cast<const float4*>(&W2s[cq+2*i][c]);
      acc[i] += wv.x*rv.x + wv.y*rv.y + wv.z*rv.z + wv.w*rv.w;
    }
  }
  #pragma unroll
  for (int i=0;i<32;i++) ob[cq+2*i][j] = acc[i];
  __syncthreads();
  for (int i=t; i<DP*128; i+=256){
    const int ch=i>>7, jj=i&127;
    const size_t o = (size_t)b*DP*NN + (size_t)ch*NN + n0 + jj;
    out[o] = lrelu(ob[ch][jj]*bS[ch] + bT[ch]) + feats[o];
  }
}

// ----------------------------------------------------------------
extern "C" void kernel_launch(void* const* d_in, const int* in_sizes, int n_in,
                              void* d_out, int out_size, void* d_ws, size_t ws_size,
                              hipStream_t stream) {
  const float* feats = (const float*)d_in[0];
  const float* pos   = (const float*)d_in[1];
  const float* W1    = (const float*)d_in[2];
  const float* bn1   = (const float*)d_in[3];
  const float* W2    = (const float*)d_in[4];
  const float* bn2   = (const float*)d_in[5];
  const float* Wq    = (const float*)d_in[6];
  const float* Wk    = (const float*)d_in[7];
  const float* Wv    = (const float*)d_in[8];
  const float* Wd1   = (const float*)d_in[9];
  const float* bnd1  = (const float*)d_in[10];
  const float* Wd2   = (const float*)d_in[11];
  const float* bnd2  = (const float*)d_in[12];
  const float* Wg1   = (const float*)d_in[13];
  const float* bng1  = (const float*)d_in[14];
  const float* Wg2   = (const float*)d_in[15];
  const float* bng2  = (const float*)d_in[16];
  float* out = (float*)d_out;

  float* ws    = (float*)d_ws;
  float* q_ws  = ws;                                        // 2M f32 (8 MB)
  float* fpm   = q_ws + (size_t)NB*NN*DM;                   // 1M f32 (4 MB)
  float* sqn   = fpm + (size_t)NB*NN*DP;                    // 16K f32
  int*   idx   = (int*)(sqn + (size_t)NB*NN);               // 256K i32 (1 MB)
  int*   cand  = idx + (size_t)NB*NN*KK;                    // 512K i32 (2 MB)
  unsigned short* xbf   = (unsigned short*)(cand + (size_t)NB*NN*32);  // 2M bf16 (4 MB)
  unsigned short* wfrag = xbf + (size_t)NB*NN*DM;           // 168*512 bf16
  unsigned short* cfrag = wfrag + (size_t)168*512;          // 4 MB
  unsigned short* qfrag = cfrag + (size_t)NB*256*2048;      // 4 MB
  float* res   = (float*)cfrag;                             // 8 MB, overlays cfrag+qfrag (dead after knn2)

  k_sqnorm<<<(NB*NN)/256, 256, 0, stream>>>(feats, sqn);
  k_fprep <<<NB*(NN/64), 256, 0, stream>>>(feats, cfrag, qfrag, fpm);
  k_knn2  <<<NB*(NN/64), 256, 0, stream>>>(cfrag, qfrag, sqn, cand);
  k_refine<<<(NB*NN)/4, 256, 0, stream>>>(fpm, sqn, cand, idx);
  k_wprep2<<<42, 256, 0, stream>>>(Wd1, bnd1, Wd2, bnd2, Wg1, bng1, Wg2, bng2, Wk, Wv, wfrag);
  k_xq    <<<NB*(NN/64), 256, 0, stream>>>(feats, W1, bn1, Wq, xbf, q_ws);

  // ---- ablation dispatches (res fully overwritten by the final MODE 0 run)
  k_attn4t<1><<<(NB*NN)/(8*PPW), 512, 0, stream>>>(pos, q_ws, xbf, idx, wfrag,
                                                   bnd1, bnd2, bng1, bng2, res);
  k_attn4t<2><<<(NB*NN)/(8*PPW), 512, 0, stream>>>(pos, q_ws, xbf, idx, wfrag,
                                                   bnd1, bnd2, bng1, bng2, res);
  k_attn4t<0><<<(NB*NN)/(8*PPW), 512, 0, stream>>>(pos, q_ws, xbf, idx, wfrag,
                                                   bnd1, bnd2, bng1, bng2, res);

  k_out   <<<NB*(NN/128), 256, 0, stream>>>(res, W2, bn2, feats, out);
}

// Round 10
// 869.945 us; speedup vs baseline: 2.9948x; 2.9948x over previous
//
#include <hip/hip_runtime.h>
#include <cstdint>
#include <cstddef>

#define NB 4
#define NN 4096
#define KK 16
#define DP 64
#define DM 128
#define EPS 1e-5f
#define NCHUNK 8
#define CHPTS (NN*NB/NCHUNK)   // 2048 points per chunk

typedef __attribute__((ext_vector_type(8))) short bf16x8;
typedef __attribute__((ext_vector_type(4))) float f32x4;
typedef __attribute__((ext_vector_type(4))) unsigned int u32x4;

__device__ __forceinline__ float lrelu(float x){ return x >= 0.f ? x : 0.2f*x; }

__device__ __forceinline__ unsigned short f2bf(float x){
  union { float f; uint32_t u; } a; a.f = x;
  return (unsigned short)((a.u + 0x7fffu + ((a.u >> 16) & 1u)) >> 16);
}
__device__ __forceinline__ float bf2f(unsigned short h){
  union { uint32_t u; float f; } a; a.u = ((uint32_t)h) << 16; return a.f;
}
__device__ __forceinline__ uint32_t pk2(float a, float b){
  return (uint32_t)f2bf(a) | ((uint32_t)f2bf(b) << 16);
}
__device__ __forceinline__ float bfl(uint32_t w){ return __uint_as_float(w << 16); }
__device__ __forceinline__ float bfh(uint32_t w){ return __uint_as_float(w & 0xffff0000u); }

__device__ __forceinline__ f32x4 mfma16(bf16x8 a, bf16x8 b, f32x4 c){
  return __builtin_amdgcn_mfma_f32_16x16x32_bf16(a, b, c, 0, 0, 0);
}
__device__ __forceinline__ float sx16(float v, int m){ return __shfl_xor(v, m, 16); }
__device__ __forceinline__ f32x4 vmax4(f32x4 a, f32x4 b){
  f32x4 r; r[0]=fmaxf(a[0],b[0]); r[1]=fmaxf(a[1],b[1]); r[2]=fmaxf(a[2],b[2]); r[3]=fmaxf(a[3],b[3]); return r;
}
__device__ __forceinline__ u32x4 sub8(u32x4 a, u32x4 k){
  u32x4 r;
  r[0] = pk2(bfl(a[0])-bfl(k[0]), bfh(a[0])-bfh(k[0]));
  r[1] = pk2(bfl(a[1])-bfl(k[1]), bfh(a[1])-bfh(k[1]));
  r[2] = pk2(bfl(a[2])-bfl(k[2]), bfh(a[2])-bfh(k[2]));
  r[3] = pk2(bfl(a[3])-bfl(k[3]), bfh(a[3])-bfh(k[3]));
  return r;
}

// ---------------------------------------------------------------- sq norms
__global__ __launch_bounds__(256) void k_sqnorm(const float* __restrict__ feats,
                                                float* __restrict__ sqn){
  const int i = blockIdx.x*256 + threadIdx.x;
  const int b = i >> 12, n = i & (NN-1);
  const float* f = feats + (size_t)b*DP*NN + n;
  float s = 0.f;
  #pragma unroll
  for (int c=0;c<DP;c++){ const float v = f[(size_t)c*NN]; s += v*v; }
  sqn[i] = s;
}

// ---------------------------------------------------------------- feats -> bf16 hi/lo MFMA fragments + point-major f32 copy
__global__ __launch_bounds__(256) void k_fprep(const float* __restrict__ feats,
                                               unsigned short* __restrict__ cfrag,
                                               unsigned short* __restrict__ qfrag,
                                               float* __restrict__ fpm){
  __shared__ float ft[DP][65];
  const int t = threadIdx.x;
  const int b = blockIdx.x >> 6;
  const int n0 = (blockIdx.x & 63) * 64;
  for (int i=t; i<DP*64; i+=256){
    const int dim = i >> 6, pt = i & 63;
    ft[dim][pt] = feats[(size_t)b*DP*NN + (size_t)dim*NN + n0 + pt];
  }
  __syncthreads();
  for (int i=t; i<64*DP; i+=256){
    const int pt = i >> 6, dim = i & 63;
    fpm[((size_t)(b*NN) + n0 + pt)*DP + dim] = ft[dim][pt];
  }
  #pragma unroll
  for (int v = t; v < 1024; v += 256){
    const int l = v & 63, hl = (v>>6)&1, ks = (v>>7)&1, ntl = v>>8;
    const int ptl = ntl*16 + (l&15);
    const int d0 = ks*32 + (l>>4)*8;
    unsigned short qo[8], co[8];
    #pragma unroll
    for (int j=0;j<8;j++){
      const float x = ft[d0+j][ptl];
      const unsigned short qh = f2bf(x);
      const float y = -2.f*x;
      const unsigned short ch = f2bf(y);
      qo[j] = hl ? f2bf(x - bf2f(qh)) : qh;
      co[j] = hl ? f2bf(y - bf2f(ch)) : ch;
    }
    const int nt = (n0 >> 4) + ntl;
    const size_t off = ((size_t)((b*256 + nt)*4 + ks*2 + hl))*512 + l*8;
    uint4 qv, cv;
    qv.x = (uint32_t)qo[0] | ((uint32_t)qo[1]<<16);
    qv.y = (uint32_t)qo[2] | ((uint32_t)qo[3]<<16);
    qv.z = (uint32_t)qo[4] | ((uint32_t)qo[5]<<16);
    qv.w = (uint32_t)qo[6] | ((uint32_t)qo[7]<<16);
    cv.x = (uint32_t)co[0] | ((uint32_t)co[1]<<16);
    cv.y = (uint32_t)co[2] | ((uint32_t)co[3]<<16);
    cv.z = (uint32_t)co[4] | ((uint32_t)co[5]<<16);
    cv.w = (uint32_t)co[6] | ((uint32_t)co[7]<<16);
    *reinterpret_cast<uint4*>(qfrag + off) = qv;
    *reinterpret_cast<uint4*>(cfrag + off) = cv;
  }
}

// ---------------------------------------------------------------- MFMA kNN: approx top-32 candidates per query
__global__ __launch_bounds__(256) void k_knn2(const unsigned short* __restrict__ cfrag,
                                              const unsigned short* __restrict__ qfrag,
                                              const float* __restrict__ sqn,
                                              int* __restrict__ cand){
  const int t = threadIdx.x, w = t >> 6, l = t & 63, g = l >> 4;
  const int b = blockIdx.x >> 6;
  const int qt = (blockIdx.x & 63)*4 + w;

  bf16x8 qf00, qf01, qf10, qf11;
  {
    const unsigned short* qb = qfrag + ((size_t)(b*256 + qt))*2048 + l*8;
    qf00 = *reinterpret_cast<const bf16x8*>(qb);
    qf01 = *reinterpret_cast<const bf16x8*>(qb + 512);
    qf10 = *reinterpret_cast<const bf16x8*>(qb + 1024);
    qf11 = *reinterpret_cast<const bf16x8*>(qb + 1536);
  }
  const unsigned short* cb = cfrag + ((size_t)(b*256))*2048 + l*8;

  float dd[16]; int ii[16];
  #pragma unroll
  for (int s=0;s<16;s++){ dd[s]=3.4e38f; ii[s]=0; }
  float dmax = 3.4e38f;

  bf16x8 c00 = *reinterpret_cast<const bf16x8*>(cb);
  bf16x8 c01 = *reinterpret_cast<const bf16x8*>(cb + 512);
  bf16x8 c10 = *reinterpret_cast<const bf16x8*>(cb + 1024);
  bf16x8 c11 = *reinterpret_cast<const bf16x8*>(cb + 1536);

  const float* sqb = sqn + b*NN + g*4;

  #pragma unroll 1
  for (int ct=0; ct<256; ++ct){
    bf16x8 n00, n01, n10, n11;
    if (ct < 255){
      const unsigned short* nb_ = cb + (size_t)(ct+1)*2048;
      n00 = *reinterpret_cast<const bf16x8*>(nb_);
      n01 = *reinterpret_cast<const bf16x8*>(nb_ + 512);
      n10 = *reinterpret_cast<const bf16x8*>(nb_ + 1024);
      n11 = *reinterpret_cast<const bf16x8*>(nb_ + 1536);
    }
    f32x4 acc = {0.f,0.f,0.f,0.f};
    acc = mfma16(c00, qf00, acc);
    acc = mfma16(c10, qf10, acc);
    acc = mfma16(c00, qf01, acc);
    acc = mfma16(c01, qf00, acc);
    acc = mfma16(c10, qf11, acc);
    acc = mfma16(c11, qf10, acc);
    const float4 sq4 = *reinterpret_cast<const float4*>(&sqb[ct*16]);
    const float d0 = acc[0] + sq4.x;
    const float d1 = acc[1] + sq4.y;
    const float d2 = acc[2] + sq4.z;
    const float d3 = acc[3] + sq4.w;
    const float mn = fminf(fminf(d0,d1), fminf(d2,d3));
    if (mn < dmax){
      const int cbase = ct*16 + g*4;
      float dv[4] = {d0,d1,d2,d3};
      #pragma unroll
      for (int u=0;u<4;u++){
        if (dv[u] < dmax){
          bool done=false;
          #pragma unroll
          for (int s=0;s<16;s++){
            if (!done && dd[s]==dmax){ dd[s]=dv[u]; ii[s]=cbase+u; done=true; }
          }
          dmax = dd[0];
          #pragma unroll
          for (int s=1;s<16;s++) dmax = fmaxf(dmax, dd[s]);
        }
      }
    }
    c00 = n00; c01 = n01; c10 = n10; c11 = n11;
  }

  const int q = qt*16 + (l & 15);
  int* op = cand + ((size_t)(b*NN) + q)*32;
  #pragma unroll 1
  for (int r=0; r<32; ++r){
    float bd = dd[0]; int bi = ii[0];
    #pragma unroll
    for (int s=1;s<16;s++){
      if (dd[s] < bd){ bd = dd[s]; bi = ii[s]; }
    }
    const int mi0 = bi;
    float od; int oi;
    od = __shfl_xor(bd, 16); oi = __shfl_xor(bi, 16);
    if (od < bd){ bd = od; bi = oi; }
    od = __shfl_xor(bd, 32); oi = __shfl_xor(bi, 32);
    if (od < bd){ bd = od; bi = oi; }
    const bool win = (bi == mi0);
    #pragma unroll
    for (int s=0;s<16;s++){
      if (win && ii[s]==bi) dd[s] = 3.4e38f;
    }
    if (g == 0) op[r] = bi;
  }
}

// ---------------------------------------------------------------- exact f32 refine: top-16 set from 32 candidates
__global__ __launch_bounds__(256) void k_refine(const float* __restrict__ fpm,
                                                const float* __restrict__ sqn,
                                                const int* __restrict__ cand,
                                                int* __restrict__ idx_ws){
  const int t = threadIdx.x, w = t >> 6, l = t & 63;
  const int q = blockIdx.x*4 + w;
  const int b = q >> 12;
  const int c = l & 31, h = l >> 5;
  const int mi = cand[(size_t)q*32 + c];
  const float* qv = fpm + (size_t)q*DP + h*32;
  const float* cv = fpm + ((size_t)(b*NN) + mi)*DP + h*32;
  float dot = 0.f;
  #pragma unroll
  for (int d=0; d<32; d+=4){
    const float4 a = *reinterpret_cast<const float4*>(&qv[d]);
    const float4 x = *reinterpret_cast<const float4*>(&cv[d]);
    dot += a.x*x.x; dot += a.y*x.y; dot += a.z*x.z; dot += a.w*x.w;
  }
  dot += __shfl_xor(dot, 32);
  const float dist = sqn[q] + sqn[b*NN + mi] - 2.f*dot;
  int rank = 0;
  #pragma unroll
  for (int j=0; j<32; j++){
    const float dj = __shfl(dist, j);
    const int   ij = __shfl(mi,  j);
    rank += (dj < dist || (dj == dist && ij < mi)) ? 1 : 0;
  }
  if (h == 0 && rank < KK) idx_ws[(size_t)q*KK + rank] = mi;
}

// ---------------------------------------------------------------- x -> q,k,v (bf16 point-major), fully fused
__global__ __launch_bounds__(256) void k_xqkv(const float* __restrict__ feats,
                                              const float* __restrict__ W1,
                                              const float* __restrict__ bn1,
                                              const float* __restrict__ Wq,
                                              const float* __restrict__ Wk,
                                              const float* __restrict__ Wv,
                                              unsigned short* __restrict__ qbf,
                                              unsigned short* __restrict__ kbf,
                                              unsigned short* __restrict__ vbf){
  __shared__ float W1s[DM][DP+1];
  __shared__ float ft[DP][64];
  __shared__ float xt[64][DM+4];
  __shared__ float Ws[DM][DM+4];
  __shared__ float bS[DM], bT[DM];
  const int t = threadIdx.x;
  const int b = blockIdx.x >> 6;
  const int n0 = (blockIdx.x & 63) * 64;
  for (int i=t; i<DM*DP; i+=256){ W1s[i>>6][i&63] = W1[i]; }
  if (t < DM){
    float g = bn1[t], be = bn1[DM+t], mn = bn1[2*DM+t], vr = bn1[3*DM+t];
    float s = g*rsqrtf(vr+EPS); bS[t]=s; bT[t]=be-mn*s;
  }
  for (int i=t; i<DP*64; i+=256){
    const int c = i>>6, j = i&63;
    ft[c][j] = feats[(size_t)b*DP*NN + (size_t)c*NN + n0 + j];
  }
  __syncthreads();
  const int j = t >> 2, cq = t & 3;
  {
    float acc[32];
    #pragma unroll
    for (int i=0;i<32;i++) acc[i]=0.f;
    for (int c=0;c<DP;c++){
      const float fv = ft[c][j];
      #pragma unroll
      for (int i=0;i<32;i++) acc[i] += W1s[cq+4*i][c]*fv;
    }
    #pragma unroll
    for (int i=0;i<32;i++){
      const int ch = cq + 4*i;
      xt[j][ch] = lrelu(acc[i]*bS[ch] + bT[ch]);
    }
  }
  const float* Wp[3] = {Wq, Wk, Wv};
  unsigned short* Op[3] = {qbf, kbf, vbf};
  for (int wi=0; wi<3; wi++){
    __syncthreads();
    for (int i=t; i<DM*DM; i+=256){ Ws[i>>7][i&127] = Wp[wi][i]; }
    __syncthreads();
    float acc[32];
    #pragma unroll
    for (int i=0;i<32;i++) acc[i]=0.f;
    for (int c=0;c<DM;c+=4){
      const float4 xv = *reinterpret_cast<const float4*>(&xt[j][c]);
      #pragma unroll
      for (int i=0;i<32;i++){
        const float4 wv = *reinterpret_cast<const float4*>(&Ws[cq+4*i][c]);
        acc[i] += wv.x*xv.x + wv.y*xv.y + wv.z*xv.z + wv.w*xv.w;
      }
    }
    unsigned short* op = Op[wi] + ((size_t)(b*NN) + n0 + j)*DM;
    #pragma unroll
    for (int i=0;i<32;i++) op[cq+4*i] = f2bf(acc[i]);
  }
}

// ---------------------------------------------------------------- weight prep: 104 bf16 MFMA fragments, bn-scale folded
// 0..31 Wd2*s2 | 32..63 Wg1*s3 | 64..95 Wg2*s4 | 96..103 Wd1*s1
__global__ __launch_bounds__(256) void k_wprep(
    const float* __restrict__ Wd1, const float* __restrict__ bnd1,
    const float* __restrict__ Wd2, const float* __restrict__ bnd2,
    const float* __restrict__ Wg1, const float* __restrict__ bng1,
    const float* __restrict__ Wg2, const float* __restrict__ bng2,
    unsigned short* __restrict__ wfrag){
  const int i = blockIdx.x*256 + threadIdx.x;
  if (i >= 104*64) return;
  const int f = i >> 6, l = i & 63;
  const int r16 = l & 15, kg = (l >> 4) * 8;
  unsigned short o8[8];
  if (f < 96){
    const int mat = f >> 5, tt = (f >> 2) & 7, ks = f & 3;
    const float* W; const float* bn;
    if (mat == 0){ W = Wd2; bn = bnd2; }
    else if (mat == 1){ W = Wg1; bn = bng1; }
    else { W = Wg2; bn = bng2; }
    const int row = tt*16 + r16;
    const float s = bn[row] * rsqrtf(bn[3*DM+row] + EPS);
    const float* src = W + (size_t)row*DM + ks*32 + kg;
    #pragma unroll
    for (int j=0;j<8;j++) o8[j] = f2bf(s * src[j]);
  } else {
    const int tt = f - 96;
    const int row = tt*16 + r16;
    const float s = bnd1[row] * rsqrtf(bnd1[3*DM+row] + EPS);
    #pragma unroll
    for (int j=0;j<8;j++){
      const int k = kg + j;
      o8[j] = (k < 3) ? f2bf(s * Wd1[row*3 + k]) : (unsigned short)0;
    }
  }
  uint4 v;
  v.x = (uint32_t)o8[0] | ((uint32_t)o8[1]<<16);
  v.y = (uint32_t)o8[2] | ((uint32_t)o8[3]<<16);
  v.z = (uint32_t)o8[4] | ((uint32_t)o8[5]<<16);
  v.w = (uint32_t)o8[6] | ((uint32_t)o8[7]<<16);
  *reinterpret_cast<uint4*>(wfrag + (size_t)i*8) = v;
}

// ---------------------------------------------------------------- staged attention
// frag image: imgA[Gc*2048 + ks*512 + l*8] (ushort), per group 4 KB
// D image:    imgV[Gc*1024 + l*16 + tt*2]  (u32),    per group 4 KB
#define FRG(fi) (*reinterpret_cast<const bf16x8*>(&wfrag[(size_t)(fi)*512 + l*8]))

#define RD_B() \
  const bf16x8 b0 = *reinterpret_cast<const bf16x8*>(&hb[p*128 + ((0*4+g)^p)*8]); \
  const bf16x8 b1 = *reinterpret_cast<const bf16x8*>(&hb[p*128 + ((1*4+g)^p)*8]); \
  const bf16x8 b2 = *reinterpret_cast<const bf16x8*>(&hb[p*128 + ((2*4+g)^p)*8]); \
  const bf16x8 b3 = *reinterpret_cast<const bf16x8*>(&hb[p*128 + ((3*4+g)^p)*8]);

#define H1_STEP(tt) { \
  f32x4 acc = {0.f,0.f,0.f,0.f}; \
  acc = mfma16(FRG(96+(tt)), bv, acc); \
  const f32x4 sh = *reinterpret_cast<const f32x4*>(&bnT[0][(tt)*16 + g*4]); \
  uint2 hp; \
  hp.x = pk2(lrelu(acc[0]+sh[0]), lrelu(acc[1]+sh[1])); \
  hp.y = pk2(lrelu(acc[2]+sh[2]), lrelu(acc[3]+sh[3])); \
  *reinterpret_cast<uint2*>(&hb[hwb + (((tt)*2 + (g>>1))^p)*8]) = hp; }

#define PE_STEP(tt, PE) { \
  f32x4 acc = {0.f,0.f,0.f,0.f}; \
  acc = mfma16(FRG(0+(tt)*4+0), b0, acc); \
  acc = mfma16(FRG(0+(tt)*4+1), b1, acc); \
  acc = mfma16(FRG(0+(tt)*4+2), b2, acc); \
  acc = mfma16(FRG(0+(tt)*4+3), b3, acc); \
  const f32x4 sh = *reinterpret_cast<const f32x4*>(&bnT[1][(tt)*16 + g*4]); \
  PE[0]=lrelu(acc[0]+sh[0]); PE[1]=lrelu(acc[1]+sh[1]); \
  PE[2]=lrelu(acc[2]+sh[2]); PE[3]=lrelu(acc[3]+sh[3]); }

// reverse transpose read (frag data written to Hb) -> D layout, add pe, store vpe image
#define VPE_STEP(tt, PE) { \
  const uint2 du = *reinterpret_cast<const uint2*>(&hb[p*128 + (((tt)*2+(g>>1))^p)*8 + (g&1)*4]); \
  uint2 st; \
  st.x = pk2(bfl(du.x)+PE[0], bfh(du.x)+PE[1]); \
  st.y = pk2(bfl(du.y)+PE[2], bfh(du.y)+PE[3]); \
  *reinterpret_cast<uint2*>(&imgV[(size_t)Gc*1024 + l*16 + (tt)*2]) = st; }

// q+pe -> Hb (D-side write)
#define QPE_STEP(tt, PE) { \
  const uint2 qu = *reinterpret_cast<const uint2*>(&qbf[(size_t)gp*DM + (tt)*16 + g*4]); \
  uint2 hp; \
  hp.x = pk2(bfl(qu.x)+PE[0], bfh(qu.x)+PE[1]); \
  hp.y = pk2(bfl(qu.y)+PE[2], bfh(qu.y)+PE[3]); \
  *reinterpret_cast<uint2*>(&hb[hwb + (((tt)*2 + (g>>1))^p)*8]) = hp; }

__global__ __launch_bounds__(256) void k_pe5(
    const float* __restrict__ pos, const unsigned short* __restrict__ qbf,
    const unsigned short* __restrict__ kbf, const unsigned short* __restrict__ vbf,
    const int* __restrict__ idx_ws, const unsigned short* __restrict__ wfrag,
    const float* __restrict__ bnd1, const float* __restrict__ bnd2,
    const float* __restrict__ bng1, const float* __restrict__ bng2,
    unsigned short* __restrict__ imgA, uint32_t* __restrict__ imgV, int g0){
  __shared__ __align__(16) unsigned short Hb[4][2048];
  __shared__ float bnT[2][DM];

  const int t = threadIdx.x;
  if (t < DM){
    const float* bp[2] = {bnd1, bnd2};
    #pragma unroll
    for (int s4=0;s4<2;s4++){
      const float g = bp[s4][t], be = bp[s4][DM+t], mn = bp[s4][2*DM+t], vr = bp[s4][3*DM+t];
      const float sc = g * rsqrtf(vr + EPS);
      bnT[s4][t] = be - mn*sc;
    }
  }
  __syncthreads();

  const int w = t >> 6, l = t & 63;
  const int p = l & 15, g = l >> 4;
  unsigned short* hb = Hb[w];
  const int hwb = p*128 + ((g & 1) * 4);

  const int Gc = blockIdx.x*4 + w;
  const int gp = g0 + Gc;
  const int b = gp >> 12, n = gp & (NN-1);
  const int mi = idx_ws[gp*KK + p];

  // rel-pos B fragment
  uint32_t bw0 = 0u, bw1 = 0u;
  if (g == 0){
    const float* posb = pos + (size_t)b*3*NN;
    const float rx = posb[n]      - posb[mi];
    const float ry = posb[NN+n]   - posb[NN+mi];
    const float rz = posb[2*NN+n] - posb[2*NN+mi];
    bw0 = pk2(rx, ry);
    bw1 = pk2(rz, 0.f);
  }
  u32x4 bwv = {bw0, bw1, 0u, 0u};
  const bf16x8 bv = __builtin_bit_cast(bf16x8, bwv);

  // layer 1 -> Hb
  H1_STEP(0) H1_STEP(1) H1_STEP(2) H1_STEP(3)
  H1_STEP(4) H1_STEP(5) H1_STEP(6) H1_STEP(7)

  // layer 2: pe (D-layout regs)
  f32x4 pe0, pe1, pe2, pe3, pe4, pe5, pe6, pe7;
  {
    RD_B()
    PE_STEP(0, pe0) PE_STEP(1, pe1) PE_STEP(2, pe2) PE_STEP(3, pe3)
    PE_STEP(4, pe4) PE_STEP(5, pe5) PE_STEP(6, pe6) PE_STEP(7, pe7)
  }

  // gather v row as frags, reverse-transpose via Hb, vpe = v + pe -> D image
  {
    const unsigned short* vrow = vbf + ((size_t)(b*NN) + mi)*DM;
    const bf16x8 xv0 = *reinterpret_cast<const bf16x8*>(&vrow[ 0 + g*8]);
    const bf16x8 xv1 = *reinterpret_cast<const bf16x8*>(&vrow[32 + g*8]);
    const bf16x8 xv2 = *reinterpret_cast<const bf16x8*>(&vrow[64 + g*8]);
    const bf16x8 xv3 = *reinterpret_cast<const bf16x8*>(&vrow[96 + g*8]);
    *reinterpret_cast<bf16x8*>(&hb[p*128 + ((0*4+g)^p)*8]) = xv0;
    *reinterpret_cast<bf16x8*>(&hb[p*128 + ((1*4+g)^p)*8]) = xv1;
    *reinterpret_cast<bf16x8*>(&hb[p*128 + ((2*4+g)^p)*8]) = xv2;
    *reinterpret_cast<bf16x8*>(&hb[p*128 + ((3*4+g)^p)*8]) = xv3;
    VPE_STEP(0, pe0) VPE_STEP(1, pe1) VPE_STEP(2, pe2) VPE_STEP(3, pe3)
    VPE_STEP(4, pe4) VPE_STEP(5, pe5) VPE_STEP(6, pe6) VPE_STEP(7, pe7)
  }

  // q + pe -> Hb (D-write, fully overwrites), then frags, minus k-frags -> frag image
  QPE_STEP(0, pe0) QPE_STEP(1, pe1) QPE_STEP(2, pe2) QPE_STEP(3, pe3)
  QPE_STEP(4, pe4) QPE_STEP(5, pe5) QPE_STEP(6, pe6) QPE_STEP(7, pe7)
  {
    const unsigned short* krow = kbf + ((size_t)(b*NN) + mi)*DM;
    const bf16x8 xk0 = *reinterpret_cast<const bf16x8*>(&krow[ 0 + g*8]);
    const bf16x8 xk1 = *reinterpret_cast<const bf16x8*>(&krow[32 + g*8]);
    const bf16x8 xk2 = *reinterpret_cast<const bf16x8*>(&krow[64 + g*8]);
    const bf16x8 xk3 = *reinterpret_cast<const bf16x8*>(&krow[96 + g*8]);
    RD_B()
    const u32x4 f0 = sub8(__builtin_bit_cast(u32x4, b0), __builtin_bit_cast(u32x4, xk0));
    const u32x4 f1 = sub8(__builtin_bit_cast(u32x4, b1), __builtin_bit_cast(u32x4, xk1));
    const u32x4 f2 = sub8(__builtin_bit_cast(u32x4, b2), __builtin_bit_cast(u32x4, xk2));
    const u32x4 f3 = sub8(__builtin_bit_cast(u32x4, b3), __builtin_bit_cast(u32x4, xk3));
    *reinterpret_cast<u32x4*>(&imgA[(size_t)Gc*2048 + 0*512 + l*8]) = f0;
    *reinterpret_cast<u32x4*>(&imgA[(size_t)Gc*2048 + 1*512 + l*8]) = f1;
    *reinterpret_cast<u32x4*>(&imgA[(size_t)Gc*2048 + 2*512 + l*8]) = f2;
    *reinterpret_cast<u32x4*>(&imgA[(size_t)Gc*2048 + 3*512 + l*8]) = f3;
  }
}

#define G1_STEP(tt) { \
  f32x4 acc = {0.f,0.f,0.f,0.f}; \
  acc = mfma16(FRG(32+(tt)*4+0), b0, acc); \
  acc = mfma16(FRG(32+(tt)*4+1), b1, acc); \
  acc = mfma16(FRG(32+(tt)*4+2), b2, acc); \
  acc = mfma16(FRG(32+(tt)*4+3), b3, acc); \
  const f32x4 sh = *reinterpret_cast<const f32x4*>(&bnT[2][(tt)*16 + g*4]); \
  uint2 hp; \
  hp.x = pk2(lrelu(acc[0]+sh[0]), lrelu(acc[1]+sh[1])); \
  hp.y = pk2(lrelu(acc[2]+sh[2]), lrelu(acc[3]+sh[3])); \
  *reinterpret_cast<uint2*>(&hb[hwb + (((tt)*2 + (g>>1))^p)*8]) = hp; }

#define E_STEP(tt, E) { \
  f32x4 acc = {0.f,0.f,0.f,0.f}; \
  acc = mfma16(FRG(64+(tt)*4+0), b0, acc); \
  acc = mfma16(FRG(64+(tt)*4+1), b1, acc); \
  acc = mfma16(FRG(64+(tt)*4+2), b2, acc); \
  acc = mfma16(FRG(64+(tt)*4+3), b3, acc); \
  const f32x4 sh = *reinterpret_cast<const f32x4*>(&bnT[3][(tt)*16 + g*4]); \
  E[0]=lrelu(acc[0]+sh[0])*0.015625f; E[1]=lrelu(acc[1]+sh[1])*0.015625f; \
  E[2]=lrelu(acc[2]+sh[2])*0.015625f; E[3]=lrelu(acc[3]+sh[3])*0.015625f; }

#define EXP_STEP(E) { \
  E[0]=__expf(E[0]-m); E[1]=__expf(E[1]-m); E[2]=__expf(E[2]-m); E[3]=__expf(E[3]-m); }

#define RED5(tt, E) { \
  const uint2 vu = *reinterpret_cast<const uint2*>(&imgV[(size_t)Gc*1024 + l*16 + (tt)*2]); \
  float o0, o1, o2, o3; \
  { float num=E[0]*bfl(vu.x), den=E[0]; \
    num+=sx16(num,1); den+=sx16(den,1); num+=sx16(num,2); den+=sx16(den,2); \
    num+=sx16(num,4); den+=sx16(den,4); num+=sx16(num,8); den+=sx16(den,8); \
    o0 = num*__builtin_amdgcn_rcpf(den); } \
  { float num=E[1]*bfh(vu.x), den=E[1]; \
    num+=sx16(num,1); den+=sx16(den,1); num+=sx16(num,2); den+=sx16(den,2); \
    num+=sx16(num,4); den+=sx16(den,4); num+=sx16(num,8); den+=sx16(den,8); \
    o1 = num*__builtin_amdgcn_rcpf(den); } \
  { float num=E[2]*bfl(vu.y), den=E[2]; \
    num+=sx16(num,1); den+=sx16(den,1); num+=sx16(num,2); den+=sx16(den,2); \
    num+=sx16(num,4); den+=sx16(den,4); num+=sx16(num,8); den+=sx16(den,8); \
    o2 = num*__builtin_amdgcn_rcpf(den); } \
  { float num=E[3]*bfh(vu.y), den=E[3]; \
    num+=sx16(num,1); den+=sx16(den,1); num+=sx16(num,2); den+=sx16(den,2); \
    num+=sx16(num,4); den+=sx16(den,4); num+=sx16(num,8); den+=sx16(den,8); \
    o3 = num*__builtin_amdgcn_rcpf(den); } \
  if (p == 0){ \
    uint2 st; st.x = pk2(o0,o1); st.y = pk2(o2,o3); \
    *reinterpret_cast<uint2*>(&resbf[(size_t)gp*DM + (tt)*16 + g*4]) = st; } }

__global__ __launch_bounds__(256) void k_attn5(
    const unsigned short* __restrict__ imgA, const uint32_t* __restrict__ imgV,
    const unsigned short* __restrict__ wfrag,
    const float* __restrict__ bng1, const float* __restrict__ bng2,
    unsigned short* __restrict__ resbf, int g0){
  __shared__ __align__(16) unsigned short Hb[4][2048];
  __shared__ float bnT[4][DM];   // rows 2,3 used

  const int t = threadIdx.x;
  if (t < DM){
    const float* bp[2] = {bng1, bng2};
    #pragma unroll
    for (int s4=0;s4<2;s4++){
      const float g = bp[s4][t], be = bp[s4][DM+t], mn = bp[s4][2*DM+t], vr = bp[s4][3*DM+t];
      const float sc = g * rsqrtf(vr + EPS);
      bnT[2+s4][t] = be - mn*sc;
    }
  }
  __syncthreads();

  const int w = t >> 6, l = t & 63;
  const int p = l & 15, g = l >> 4;
  unsigned short* hb = Hb[w];
  const int hwb = p*128 + ((g & 1) * 4);

  const int Gc = blockIdx.x*4 + w;
  const int gp = g0 + Gc;

  // load aIn frags (coalesced)
  {
    const bf16x8 b0 = *reinterpret_cast<const bf16x8*>(&imgA[(size_t)Gc*2048 + 0*512 + l*8]);
    const bf16x8 b1 = *reinterpret_cast<const bf16x8*>(&imgA[(size_t)Gc*2048 + 1*512 + l*8]);
    const bf16x8 b2 = *reinterpret_cast<const bf16x8*>(&imgA[(size_t)Gc*2048 + 2*512 + l*8]);
    const bf16x8 b3 = *reinterpret_cast<const bf16x8*>(&imgA[(size_t)Gc*2048 + 3*512 + l*8]);
    G1_STEP(0) G1_STEP(1) G1_STEP(2) G1_STEP(3)
    G1_STEP(4) G1_STEP(5) G1_STEP(6) G1_STEP(7)
  }

  f32x4 e0, e1, e2, e3, e4, e5, e6, e7;
  {
    RD_B()
    E_STEP(0, e0) E_STEP(1, e1) E_STEP(2, e2) E_STEP(3, e3)
    E_STEP(4, e4) E_STEP(5, e5) E_STEP(6, e6) E_STEP(7, e7)
  }

  f32x4 mm = vmax4(vmax4(vmax4(e0,e1), vmax4(e2,e3)), vmax4(vmax4(e4,e5), vmax4(e6,e7)));
  float m = fmaxf(fmaxf(mm[0],mm[1]), fmaxf(mm[2],mm[3]));
  m = fmaxf(m, sx16(m,1)); m = fmaxf(m, sx16(m,2));
  m = fmaxf(m, sx16(m,4)); m = fmaxf(m, sx16(m,8));
  EXP_STEP(e0) EXP_STEP(e1) EXP_STEP(e2) EXP_STEP(e3)
  EXP_STEP(e4) EXP_STEP(e5) EXP_STEP(e6) EXP_STEP(e7)

  RED5(0, e0) RED5(1, e1) RED5(2, e2) RED5(3, e3)
  RED5(4, e4) RED5(5, e5) RED5(6, e6) RED5(7, e7)
}

// ---------------------------------------------------------------- out = lrelu(bn2(W2@res)) + feats  (res is bf16)
__global__ __launch_bounds__(256) void k_out(const unsigned short* __restrict__ resbf,
                                             const float* __restrict__ W2,
                                             const float* __restrict__ bn2,
                                             const float* __restrict__ feats,
                                             float* __restrict__ out){
  __shared__ float W2s[DP][DM+4];
  __shared__ float rt[128][DM+4];
  __shared__ float ob[DP][132];
  __shared__ float bS[DP], bT[DP];
  const int t = threadIdx.x;
  const int b = blockIdx.x >> 5;
  const int n0 = (blockIdx.x & 31) * 128;
  for (int i=t; i<DP*DM; i+=256){ W2s[i>>7][i&127] = W2[i]; }
  if (t < DP){
    float g=bn2[t], be=bn2[DP+t], mn=bn2[2*DP+t], vr=bn2[3*DP+t];
    float s = g*rsqrtf(vr+EPS); bS[t]=s; bT[t]=be-mn*s;
  }
  for (int i=t; i<128*(DM/4); i+=256){
    const int j=i>>5, c4=(i&31)*4;
    const ushort4 u = *reinterpret_cast<const ushort4*>(&resbf[((size_t)(b*NN)+n0+j)*DM + c4]);
    rt[j][c4+0] = bf2f(u.x); rt[j][c4+1] = bf2f(u.y);
    rt[j][c4+2] = bf2f(u.z); rt[j][c4+3] = bf2f(u.w);
  }
  __syncthreads();
  const int j = t>>1, cq = t&1;
  float acc[32];
  #pragma unroll
  for (int i=0;i<32;i++) acc[i]=0.f;
  for (int c=0;c<DM;c+=4){
    const float4 rv = *reinterpret_cast<const float4*>(&rt[j][c]);
    #pragma unroll
    for (int i=0;i<32;i++){
      const float4 wv = *reinterpret_cast<const float4*>(&W2s[cq+2*i][c]);
      acc[i] += wv.x*rv.x + wv.y*rv.y + wv.z*rv.z + wv.w*rv.w;
    }
  }
  #pragma unroll
  for (int i=0;i<32;i++) ob[cq+2*i][j] = acc[i];
  __syncthreads();
  for (int i=t; i<DP*128; i+=256){
    const int ch=i>>7, jj=i&127;
    const size_t o = (size_t)b*DP*NN + (size_t)ch*NN + n0 + jj;
    out[o] = lrelu(ob[ch][jj]*bS[ch] + bT[ch]) + feats[o];
  }
}

// ----------------------------------------------------------------
extern "C" void kernel_launch(void* const* d_in, const int* in_sizes, int n_in,
                              void* d_out, int out_size, void* d_ws, size_t ws_size,
                              hipStream_t stream) {
  const float* feats = (const float*)d_in[0];
  const float* pos   = (const float*)d_in[1];
  const float* W1    = (const float*)d_in[2];
  const float* bn1   = (const float*)d_in[3];
  const float* W2    = (const float*)d_in[4];
  const float* bn2   = (const float*)d_in[5];
  const float* Wq    = (const float*)d_in[6];
  const float* Wk    = (const float*)d_in[7];
  const float* Wv    = (const float*)d_in[8];
  const float* Wd1   = (const float*)d_in[9];
  const float* bnd1  = (const float*)d_in[10];
  const float* Wd2   = (const float*)d_in[11];
  const float* bnd2  = (const float*)d_in[12];
  const float* Wg1   = (const float*)d_in[13];
  const float* bng1  = (const float*)d_in[14];
  const float* Wg2   = (const float*)d_in[15];
  const float* bng2  = (const float*)d_in[16];
  float* out = (float*)d_out;

  // ws layout (~33 MiB total, matches proven R1 footprint)
  unsigned short* qbf = (unsigned short*)d_ws;              // 4 MiB
  unsigned short* kbf = qbf + 2097152;                      // 4 MiB
  unsigned short* vbf = kbf + 2097152;                      // 4 MiB
  float* sqn = (float*)(vbf + 2097152);                     // 64 KiB
  int*   idx = (int*)(sqn + 16384);                         // 1 MiB
  unsigned short* wfrag = (unsigned short*)(idx + 262144);  // 104 KiB
  unsigned short* poolu = wfrag + 53248;                    // 20 MiB pool
  // knn phase overlays
  float* fpm = (float*)poolu;                               // 4 MiB
  unsigned short* cfrag = (unsigned short*)(fpm + 1048576); // 4 MiB
  unsigned short* qfrag = cfrag + 2097152;                  // 4 MiB
  int* cand = (int*)(qfrag + 2097152);                      // 2 MiB
  // attn phase overlays
  unsigned short* resbf = poolu;                            // 4 MiB
  unsigned short* imgA  = poolu + 2097152;                  // 8 MiB
  uint32_t* imgV = (uint32_t*)(imgA + 4194304);             // 8 MiB

  k_sqnorm<<<(NB*NN)/256, 256, 0, stream>>>(feats, sqn);
  k_fprep <<<NB*(NN/64), 256, 0, stream>>>(feats, cfrag, qfrag, fpm);
  k_knn2  <<<NB*(NN/64), 256, 0, stream>>>(cfrag, qfrag, sqn, cand);
  k_refine<<<(NB*NN)/4, 256, 0, stream>>>(fpm, sqn, cand, idx);
  k_wprep <<<26, 256, 0, stream>>>(Wd1, bnd1, Wd2, bnd2, Wg1, bng1, Wg2, bng2, wfrag);
  k_xqkv  <<<NB*(NN/64), 256, 0, stream>>>(feats, W1, bn1, Wq, Wk, Wv, qbf, kbf, vbf);

  for (int c = 0; c < NCHUNK; ++c){
    const int g0 = c * CHPTS;
    k_pe5  <<<CHPTS/4, 256, 0, stream>>>(pos, qbf, kbf, vbf, idx, wfrag,
                                         bnd1, bnd2, bng1, bng2, imgA, imgV, g0);
    k_attn5<<<CHPTS/4, 256, 0, stream>>>(imgA, imgV, wfrag, bng1, bng2, resbf, g0);
  }

  k_out   <<<NB*(NN/128), 256, 0, stream>>>(resbf, W2, bn2, feats, out);
}

// Round 11
// 768.718 us; speedup vs baseline: 3.3892x; 1.1317x over previous
//
#include <hip/hip_runtime.h>
#include <cstdint>
#include <cstddef>

#define NB 4
#define NN 4096
#define KK 16
#define DP 64
#define DM 128
#define EPS 1e-5f
#define NCHUNK 8
#define CHPTS (NN*NB/NCHUNK)   // 2048 points per chunk

typedef __attribute__((ext_vector_type(8))) short bf16x8;
typedef __attribute__((ext_vector_type(4))) float f32x4;
typedef __attribute__((ext_vector_type(4))) unsigned int u32x4;

__device__ __forceinline__ float lrelu(float x){ return x >= 0.f ? x : 0.2f*x; }

__device__ __forceinline__ unsigned short f2bf(float x){
  union { float f; uint32_t u; } a; a.f = x;
  return (unsigned short)((a.u + 0x7fffu + ((a.u >> 16) & 1u)) >> 16);
}
__device__ __forceinline__ float bf2f(unsigned short h){
  union { uint32_t u; float f; } a; a.u = ((uint32_t)h) << 16; return a.f;
}
__device__ __forceinline__ uint32_t pk2(float a, float b){
  return (uint32_t)f2bf(a) | ((uint32_t)f2bf(b) << 16);
}
__device__ __forceinline__ float bfl(uint32_t w){ return __uint_as_float(w << 16); }
__device__ __forceinline__ float bfh(uint32_t w){ return __uint_as_float(w & 0xffff0000u); }

__device__ __forceinline__ f32x4 mfma16(bf16x8 a, bf16x8 b, f32x4 c){
  return __builtin_amdgcn_mfma_f32_16x16x32_bf16(a, b, c, 0, 0, 0);
}
__device__ __forceinline__ float sx16(float v, int m){ return __shfl_xor(v, m, 16); }
__device__ __forceinline__ f32x4 vmax4(f32x4 a, f32x4 b){
  f32x4 r; r[0]=fmaxf(a[0],b[0]); r[1]=fmaxf(a[1],b[1]); r[2]=fmaxf(a[2],b[2]); r[3]=fmaxf(a[3],b[3]); return r;
}
__device__ __forceinline__ u32x4 sub8(u32x4 a, u32x4 k){
  u32x4 r;
  r[0] = pk2(bfl(a[0])-bfl(k[0]), bfh(a[0])-bfh(k[0]));
  r[1] = pk2(bfl(a[1])-bfl(k[1]), bfh(a[1])-bfh(k[1]));
  r[2] = pk2(bfl(a[2])-bfl(k[2]), bfh(a[2])-bfh(k[2]));
  r[3] = pk2(bfl(a[3])-bfl(k[3]), bfh(a[3])-bfh(k[3]));
  return r;
}

// ---------------------------------------------------------------- sq norms
__global__ __launch_bounds__(256) void k_sqnorm(const float* __restrict__ feats,
                                                float* __restrict__ sqn){
  const int i = blockIdx.x*256 + threadIdx.x;
  const int b = i >> 12, n = i & (NN-1);
  const float* f = feats + (size_t)b*DP*NN + n;
  float s = 0.f;
  #pragma unroll
  for (int c=0;c<DP;c++){ const float v = f[(size_t)c*NN]; s += v*v; }
  sqn[i] = s;
}

// ---------------------------------------------------------------- feats -> bf16 hi/lo MFMA fragments + point-major f32 copy
__global__ __launch_bounds__(256) void k_fprep(const float* __restrict__ feats,
                                               unsigned short* __restrict__ cfrag,
                                               unsigned short* __restrict__ qfrag,
                                               float* __restrict__ fpm){
  __shared__ float ft[DP][65];
  const int t = threadIdx.x;
  const int b = blockIdx.x >> 6;
  const int n0 = (blockIdx.x & 63) * 64;
  for (int i=t; i<DP*64; i+=256){
    const int dim = i >> 6, pt = i & 63;
    ft[dim][pt] = feats[(size_t)b*DP*NN + (size_t)dim*NN + n0 + pt];
  }
  __syncthreads();
  for (int i=t; i<64*DP; i+=256){
    const int pt = i >> 6, dim = i & 63;
    fpm[((size_t)(b*NN) + n0 + pt)*DP + dim] = ft[dim][pt];
  }
  #pragma unroll
  for (int v = t; v < 1024; v += 256){
    const int l = v & 63, hl = (v>>6)&1, ks = (v>>7)&1, ntl = v>>8;
    const int ptl = ntl*16 + (l&15);
    const int d0 = ks*32 + (l>>4)*8;
    unsigned short qo[8], co[8];
    #pragma unroll
    for (int j=0;j<8;j++){
      const float x = ft[d0+j][ptl];
      const unsigned short qh = f2bf(x);
      const float y = -2.f*x;
      const unsigned short ch = f2bf(y);
      qo[j] = hl ? f2bf(x - bf2f(qh)) : qh;
      co[j] = hl ? f2bf(y - bf2f(ch)) : ch;
    }
    const int nt = (n0 >> 4) + ntl;
    const size_t off = ((size_t)((b*256 + nt)*4 + ks*2 + hl))*512 + l*8;
    uint4 qv, cv;
    qv.x = (uint32_t)qo[0] | ((uint32_t)qo[1]<<16);
    qv.y = (uint32_t)qo[2] | ((uint32_t)qo[3]<<16);
    qv.z = (uint32_t)qo[4] | ((uint32_t)qo[5]<<16);
    qv.w = (uint32_t)qo[6] | ((uint32_t)qo[7]<<16);
    cv.x = (uint32_t)co[0] | ((uint32_t)co[1]<<16);
    cv.y = (uint32_t)co[2] | ((uint32_t)co[3]<<16);
    cv.z = (uint32_t)co[4] | ((uint32_t)co[5]<<16);
    cv.w = (uint32_t)co[6] | ((uint32_t)co[7]<<16);
    *reinterpret_cast<uint4*>(qfrag + off) = qv;
    *reinterpret_cast<uint4*>(cfrag + off) = cv;
  }
}

// ---------------------------------------------------------------- MFMA kNN v3: (query-tile, stream-half) per wave
// grid NB*128 blocks x 4 waves; wave covers 128 candidate tiles; emits top-32 per query per half.
__global__ __launch_bounds__(256, 2) void k_knn3(const unsigned short* __restrict__ cfrag,
                                                 const unsigned short* __restrict__ qfrag,
                                                 const float* __restrict__ sqn,
                                                 int* __restrict__ cand){
  const int t = threadIdx.x, w = t >> 6, l = t & 63, g = l >> 4;
  const int b = blockIdx.x >> 7;
  const int combo = (blockIdx.x & 127)*4 + w;   // 512 combos per batch
  const int qt = combo >> 1, h = combo & 1;
  const int ct0 = h * 128;

  bf16x8 qf00, qf01, qf10, qf11;
  {
    const unsigned short* qb = qfrag + ((size_t)(b*256 + qt))*2048 + l*8;
    qf00 = *reinterpret_cast<const bf16x8*>(qb);
    qf01 = *reinterpret_cast<const bf16x8*>(qb + 512);
    qf10 = *reinterpret_cast<const bf16x8*>(qb + 1024);
    qf11 = *reinterpret_cast<const bf16x8*>(qb + 1536);
  }
  const unsigned short* cb = cfrag + ((size_t)(b*256))*2048 + l*8;

  float dd[16]; int ii[16];
  #pragma unroll
  for (int s=0;s<16;s++){ dd[s]=3.4e38f; ii[s]=0; }
  float dmax = 3.4e38f;

  bf16x8 c00 = *reinterpret_cast<const bf16x8*>(cb + (size_t)ct0*2048);
  bf16x8 c01 = *reinterpret_cast<const bf16x8*>(cb + (size_t)ct0*2048 + 512);
  bf16x8 c10 = *reinterpret_cast<const bf16x8*>(cb + (size_t)ct0*2048 + 1024);
  bf16x8 c11 = *reinterpret_cast<const bf16x8*>(cb + (size_t)ct0*2048 + 1536);

  const float* sqb = sqn + b*NN + g*4;

  #pragma unroll 1
  for (int it=0; it<128; ++it){
    const int ct = ct0 + it;
    bf16x8 n00, n01, n10, n11;
    if (it < 127){
      const unsigned short* nb_ = cb + (size_t)(ct+1)*2048;
      n00 = *reinterpret_cast<const bf16x8*>(nb_);
      n01 = *reinterpret_cast<const bf16x8*>(nb_ + 512);
      n10 = *reinterpret_cast<const bf16x8*>(nb_ + 1024);
      n11 = *reinterpret_cast<const bf16x8*>(nb_ + 1536);
    }
    f32x4 acc = {0.f,0.f,0.f,0.f};
    acc = mfma16(c00, qf00, acc);
    acc = mfma16(c10, qf10, acc);
    acc = mfma16(c00, qf01, acc);
    acc = mfma16(c01, qf00, acc);
    acc = mfma16(c10, qf11, acc);
    acc = mfma16(c11, qf10, acc);
    const float4 sq4 = *reinterpret_cast<const float4*>(&sqb[ct*16]);
    const float d0 = acc[0] + sq4.x;
    const float d1 = acc[1] + sq4.y;
    const float d2 = acc[2] + sq4.z;
    const float d3 = acc[3] + sq4.w;
    const float mn = fminf(fminf(d0,d1), fminf(d2,d3));
    if (mn < dmax){
      const int cbase = ct*16 + g*4;
      float dv[4] = {d0,d1,d2,d3};
      #pragma unroll
      for (int u=0;u<4;u++){
        if (dv[u] < dmax){
          bool done=false;
          #pragma unroll
          for (int s=0;s<16;s++){
            if (!done && dd[s]==dmax){ dd[s]=dv[u]; ii[s]=cbase+u; done=true; }
          }
          dmax = dd[0];
          #pragma unroll
          for (int s=1;s<16;s++) dmax = fmaxf(dmax, dd[s]);
        }
      }
    }
    c00 = n00; c01 = n01; c10 = n10; c11 = n11;
  }

  // merge across the 4 g-lanes per query: 32 extraction rounds -> cand[q][h*32 + r]
  const int q = qt*16 + (l & 15);
  int* op = cand + ((size_t)(b*NN) + q)*64 + h*32;
  #pragma unroll 1
  for (int r=0; r<32; ++r){
    float bd = dd[0]; int bi = ii[0];
    #pragma unroll
    for (int s=1;s<16;s++){
      if (dd[s] < bd){ bd = dd[s]; bi = ii[s]; }
    }
    const int mi0 = bi;
    float od; int oi;
    od = __shfl_xor(bd, 16); oi = __shfl_xor(bi, 16);
    if (od < bd){ bd = od; bi = oi; }
    od = __shfl_xor(bd, 32); oi = __shfl_xor(bi, 32);
    if (od < bd){ bd = od; bi = oi; }
    const bool win = (bi == mi0);
    #pragma unroll
    for (int s=0;s<16;s++){
      if (win && ii[s]==bi) dd[s] = 3.4e38f;
    }
    if (g == 0) op[r] = bi;
  }
}

// ---------------------------------------------------------------- exact f32 refine: wave per query, lane per candidate (64)
__global__ __launch_bounds__(256) void k_refine(const float* __restrict__ fpm,
                                                const float* __restrict__ sqn,
                                                const int* __restrict__ cand,
                                                int* __restrict__ idx_ws){
  const int t = threadIdx.x, w = t >> 6, l = t & 63;
  const int q = blockIdx.x*4 + w;           // global point id
  const int b = q >> 12;
  const int mi = cand[(size_t)q*64 + l];
  const float* qv = fpm + (size_t)q*DP;
  const float* cv = fpm + ((size_t)(b*NN) + mi)*DP;
  float dot = 0.f;
  #pragma unroll
  for (int d=0; d<DP; d+=4){
    const float4 a = *reinterpret_cast<const float4*>(&qv[d]);
    const float4 x = *reinterpret_cast<const float4*>(&cv[d]);
    dot += a.x*x.x; dot += a.y*x.y; dot += a.z*x.z; dot += a.w*x.w;
  }
  // sqn[q] is query-constant -> rank-invariant, dropped
  const float dist = sqn[b*NN + mi] - 2.f*dot;
  int rank = 0;
  #pragma unroll 4
  for (int j=0; j<64; j++){
    const float dj = __shfl(dist, j);
    const int   ij = __shfl(mi,  j);
    rank += (dj < dist || (dj == dist && ij < mi)) ? 1 : 0;
  }
  if (rank < KK) idx_ws[(size_t)q*KK + rank] = mi;
}

// ---------------------------------------------------------------- x -> q,k,v (bf16 point-major), fully fused
__global__ __launch_bounds__(256, 1) void k_xqkv(const float* __restrict__ feats,
                                              const float* __restrict__ W1,
                                              const float* __restrict__ bn1,
                                              const float* __restrict__ Wq,
                                              const float* __restrict__ Wk,
                                              const float* __restrict__ Wv,
                                              unsigned short* __restrict__ qbf,
                                              unsigned short* __restrict__ kbf,
                                              unsigned short* __restrict__ vbf){
  __shared__ float W1s[DM][DP+1];
  __shared__ float ft[DP][64];
  __shared__ float xt[64][DM+4];
  __shared__ float Ws[DM][DM+4];
  __shared__ float bS[DM], bT[DM];
  const int t = threadIdx.x;
  const int b = blockIdx.x >> 6;
  const int n0 = (blockIdx.x & 63) * 64;
  for (int i=t; i<DM*DP; i+=256){ W1s[i>>6][i&63] = W1[i]; }
  if (t < DM){
    float g = bn1[t], be = bn1[DM+t], mn = bn1[2*DM+t], vr = bn1[3*DM+t];
    float s = g*rsqrtf(vr+EPS); bS[t]=s; bT[t]=be-mn*s;
  }
  for (int i=t; i<DP*64; i+=256){
    const int c = i>>6, j = i&63;
    ft[c][j] = feats[(size_t)b*DP*NN + (size_t)c*NN + n0 + j];
  }
  __syncthreads();
  const int j = t >> 2, cq = t & 3;
  {
    float acc[32];
    #pragma unroll
    for (int i=0;i<32;i++) acc[i]=0.f;
    for (int c=0;c<DP;c++){
      const float fv = ft[c][j];
      #pragma unroll
      for (int i=0;i<32;i++) acc[i] += W1s[cq+4*i][c]*fv;
    }
    #pragma unroll
    for (int i=0;i<32;i++){
      const int ch = cq + 4*i;
      xt[j][ch] = lrelu(acc[i]*bS[ch] + bT[ch]);
    }
  }
  const float* Wp[3] = {Wq, Wk, Wv};
  unsigned short* Op[3] = {qbf, kbf, vbf};
  for (int wi=0; wi<3; wi++){
    __syncthreads();
    for (int i=t; i<DM*DM; i+=256){ Ws[i>>7][i&127] = Wp[wi][i]; }
    __syncthreads();
    float acc[32];
    #pragma unroll
    for (int i=0;i<32;i++) acc[i]=0.f;
    for (int c=0;c<DM;c+=4){
      const float4 xv = *reinterpret_cast<const float4*>(&xt[j][c]);
      #pragma unroll
      for (int i=0;i<32;i++){
        const float4 wv = *reinterpret_cast<const float4*>(&Ws[cq+4*i][c]);
        acc[i] += wv.x*xv.x + wv.y*xv.y + wv.z*xv.z + wv.w*xv.w;
      }
    }
    unsigned short* op = Op[wi] + ((size_t)(b*NN) + n0 + j)*DM;
    #pragma unroll
    for (int i=0;i<32;i++) op[cq+4*i] = f2bf(acc[i]);
  }
}

// ---------------------------------------------------------------- weight prep: 104 bf16 MFMA fragments, bn-scale folded
__global__ __launch_bounds__(256) void k_wprep(
    const float* __restrict__ Wd1, const float* __restrict__ bnd1,
    const float* __restrict__ Wd2, const float* __restrict__ bnd2,
    const float* __restrict__ Wg1, const float* __restrict__ bng1,
    const float* __restrict__ Wg2, const float* __restrict__ bng2,
    unsigned short* __restrict__ wfrag){
  const int i = blockIdx.x*256 + threadIdx.x;
  if (i >= 104*64) return;
  const int f = i >> 6, l = i & 63;
  const int r16 = l & 15, kg = (l >> 4) * 8;
  unsigned short o8[8];
  if (f < 96){
    const int mat = f >> 5, tt = (f >> 2) & 7, ks = f & 3;
    const float* W; const float* bn;
    if (mat == 0){ W = Wd2; bn = bnd2; }
    else if (mat == 1){ W = Wg1; bn = bng1; }
    else { W = Wg2; bn = bng2; }
    const int row = tt*16 + r16;
    const float s = bn[row] * rsqrtf(bn[3*DM+row] + EPS);
    const float* src = W + (size_t)row*DM + ks*32 + kg;
    #pragma unroll
    for (int j=0;j<8;j++) o8[j] = f2bf(s * src[j]);
  } else {
    const int tt = f - 96;
    const int row = tt*16 + r16;
    const float s = bnd1[row] * rsqrtf(bnd1[3*DM+row] + EPS);
    #pragma unroll
    for (int j=0;j<8;j++){
      const int k = kg + j;
      o8[j] = (k < 3) ? f2bf(s * Wd1[row*3 + k]) : (unsigned short)0;
    }
  }
  uint4 v;
  v.x = (uint32_t)o8[0] | ((uint32_t)o8[1]<<16);
  v.y = (uint32_t)o8[2] | ((uint32_t)o8[3]<<16);
  v.z = (uint32_t)o8[4] | ((uint32_t)o8[5]<<16);
  v.w = (uint32_t)o8[6] | ((uint32_t)o8[7]<<16);
  *reinterpret_cast<uint4*>(wfrag + (size_t)i*8) = v;
}

// ---------------------------------------------------------------- staged attention
#define FRG(fi) (*reinterpret_cast<const bf16x8*>(&wfrag[(size_t)(fi)*512 + l*8]))

#define RD_B() \
  const bf16x8 b0 = *reinterpret_cast<const bf16x8*>(&hb[p*128 + ((0*4+g)^p)*8]); \
  const bf16x8 b1 = *reinterpret_cast<const bf16x8*>(&hb[p*128 + ((1*4+g)^p)*8]); \
  const bf16x8 b2 = *reinterpret_cast<const bf16x8*>(&hb[p*128 + ((2*4+g)^p)*8]); \
  const bf16x8 b3 = *reinterpret_cast<const bf16x8*>(&hb[p*128 + ((3*4+g)^p)*8]);

#define H1_STEP(tt) { \
  f32x4 acc = {0.f,0.f,0.f,0.f}; \
  acc = mfma16(FRG(96+(tt)), bv, acc); \
  const f32x4 sh = *reinterpret_cast<const f32x4*>(&bnT[0][(tt)*16 + g*4]); \
  uint2 hp; \
  hp.x = pk2(lrelu(acc[0]+sh[0]), lrelu(acc[1]+sh[1])); \
  hp.y = pk2(lrelu(acc[2]+sh[2]), lrelu(acc[3]+sh[3])); \
  *reinterpret_cast<uint2*>(&hb[hwb + (((tt)*2 + (g>>1))^p)*8]) = hp; }

#define PE_STEP(tt, PE) { \
  f32x4 acc = {0.f,0.f,0.f,0.f}; \
  acc = mfma16(FRG(0+(tt)*4+0), b0, acc); \
  acc = mfma16(FRG(0+(tt)*4+1), b1, acc); \
  acc = mfma16(FRG(0+(tt)*4+2), b2, acc); \
  acc = mfma16(FRG(0+(tt)*4+3), b3, acc); \
  const f32x4 sh = *reinterpret_cast<const f32x4*>(&bnT[1][(tt)*16 + g*4]); \
  PE[0]=lrelu(acc[0]+sh[0]); PE[1]=lrelu(acc[1]+sh[1]); \
  PE[2]=lrelu(acc[2]+sh[2]); PE[3]=lrelu(acc[3]+sh[3]); }

#define VPE_STEP(tt, PE) { \
  const uint2 du = *reinterpret_cast<const uint2*>(&hb[p*128 + (((tt)*2+(g>>1))^p)*8 + (g&1)*4]); \
  uint2 st; \
  st.x = pk2(bfl(du.x)+PE[0], bfh(du.x)+PE[1]); \
  st.y = pk2(bfl(du.y)+PE[2], bfh(du.y)+PE[3]); \
  *reinterpret_cast<uint2*>(&imgV[(size_t)Gc*1024 + l*16 + (tt)*2]) = st; }

#define QPE_STEP(tt, PE) { \
  const uint2 qu = *reinterpret_cast<const uint2*>(&qbf[(size_t)gp*DM + (tt)*16 + g*4]); \
  uint2 hp; \
  hp.x = pk2(bfl(qu.x)+PE[0], bfh(qu.x)+PE[1]); \
  hp.y = pk2(bfl(qu.y)+PE[2], bfh(qu.y)+PE[3]); \
  *reinterpret_cast<uint2*>(&hb[hwb + (((tt)*2 + (g>>1))^p)*8]) = hp; }

__global__ __launch_bounds__(256, 2) void k_pe5(
    const float* __restrict__ pos, const unsigned short* __restrict__ qbf,
    const unsigned short* __restrict__ kbf, const unsigned short* __restrict__ vbf,
    const int* __restrict__ idx_ws, const unsigned short* __restrict__ wfrag,
    const float* __restrict__ bnd1, const float* __restrict__ bnd2,
    const float* __restrict__ bng1, const float* __restrict__ bng2,
    unsigned short* __restrict__ imgA, uint32_t* __restrict__ imgV, int g0){
  __shared__ __align__(16) unsigned short Hb[4][2048];
  __shared__ float bnT[2][DM];

  const int t = threadIdx.x;
  if (t < DM){
    const float* bp[2] = {bnd1, bnd2};
    #pragma unroll
    for (int s4=0;s4<2;s4++){
      const float g = bp[s4][t], be = bp[s4][DM+t], mn = bp[s4][2*DM+t], vr = bp[s4][3*DM+t];
      const float sc = g * rsqrtf(vr + EPS);
      bnT[s4][t] = be - mn*sc;
    }
  }
  __syncthreads();

  const int w = t >> 6, l = t & 63;
  const int p = l & 15, g = l >> 4;
  unsigned short* hb = Hb[w];
  const int hwb = p*128 + ((g & 1) * 4);

  const int Gc = blockIdx.x*4 + w;
  const int gp = g0 + Gc;
  const int b = gp >> 12, n = gp & (NN-1);
  const int mi = idx_ws[gp*KK + p];

  uint32_t bw0 = 0u, bw1 = 0u;
  if (g == 0){
    const float* posb = pos + (size_t)b*3*NN;
    const float rx = posb[n]      - posb[mi];
    const float ry = posb[NN+n]   - posb[NN+mi];
    const float rz = posb[2*NN+n] - posb[2*NN+mi];
    bw0 = pk2(rx, ry);
    bw1 = pk2(rz, 0.f);
  }
  u32x4 bwv = {bw0, bw1, 0u, 0u};
  const bf16x8 bv = __builtin_bit_cast(bf16x8, bwv);

  H1_STEP(0) H1_STEP(1) H1_STEP(2) H1_STEP(3)
  H1_STEP(4) H1_STEP(5) H1_STEP(6) H1_STEP(7)

  f32x4 pe0, pe1, pe2, pe3, pe4, pe5, pe6, pe7;
  {
    RD_B()
    PE_STEP(0, pe0) PE_STEP(1, pe1) PE_STEP(2, pe2) PE_STEP(3, pe3)
    PE_STEP(4, pe4) PE_STEP(5, pe5) PE_STEP(6, pe6) PE_STEP(7, pe7)
  }

  {
    const unsigned short* vrow = vbf + ((size_t)(b*NN) + mi)*DM;
    const bf16x8 xv0 = *reinterpret_cast<const bf16x8*>(&vrow[ 0 + g*8]);
    const bf16x8 xv1 = *reinterpret_cast<const bf16x8*>(&vrow[32 + g*8]);
    const bf16x8 xv2 = *reinterpret_cast<const bf16x8*>(&vrow[64 + g*8]);
    const bf16x8 xv3 = *reinterpret_cast<const bf16x8*>(&vrow[96 + g*8]);
    *reinterpret_cast<bf16x8*>(&hb[p*128 + ((0*4+g)^p)*8]) = xv0;
    *reinterpret_cast<bf16x8*>(&hb[p*128 + ((1*4+g)^p)*8]) = xv1;
    *reinterpret_cast<bf16x8*>(&hb[p*128 + ((2*4+g)^p)*8]) = xv2;
    *reinterpret_cast<bf16x8*>(&hb[p*128 + ((3*4+g)^p)*8]) = xv3;
    VPE_STEP(0, pe0) VPE_STEP(1, pe1) VPE_STEP(2, pe2) VPE_STEP(3, pe3)
    VPE_STEP(4, pe4) VPE_STEP(5, pe5) VPE_STEP(6, pe6) VPE_STEP(7, pe7)
  }

  QPE_STEP(0, pe0) QPE_STEP(1, pe1) QPE_STEP(2, pe2) QPE_STEP(3, pe3)
  QPE_STEP(4, pe4) QPE_STEP(5, pe5) QPE_STEP(6, pe6) QPE_STEP(7, pe7)
  {
    const unsigned short* krow = kbf + ((size_t)(b*NN) + mi)*DM;
    const bf16x8 xk0 = *reinterpret_cast<const bf16x8*>(&krow[ 0 + g*8]);
    const bf16x8 xk1 = *reinterpret_cast<const bf16x8*>(&krow[32 + g*8]);
    const bf16x8 xk2 = *reinterpret_cast<const bf16x8*>(&krow[64 + g*8]);
    const bf16x8 xk3 = *reinterpret_cast<const bf16x8*>(&krow[96 + g*8]);
    RD_B()
    const u32x4 f0 = sub8(__builtin_bit_cast(u32x4, b0), __builtin_bit_cast(u32x4, xk0));
    const u32x4 f1 = sub8(__builtin_bit_cast(u32x4, b1), __builtin_bit_cast(u32x4, xk1));
    const u32x4 f2 = sub8(__builtin_bit_cast(u32x4, b2), __builtin_bit_cast(u32x4, xk2));
    const u32x4 f3 = sub8(__builtin_bit_cast(u32x4, b3), __builtin_bit_cast(u32x4, xk3));
    *reinterpret_cast<u32x4*>(&imgA[(size_t)Gc*2048 + 0*512 + l*8]) = f0;
    *reinterpret_cast<u32x4*>(&imgA[(size_t)Gc*2048 + 1*512 + l*8]) = f1;
    *reinterpret_cast<u32x4*>(&imgA[(size_t)Gc*2048 + 2*512 + l*8]) = f2;
    *reinterpret_cast<u32x4*>(&imgA[(size_t)Gc*2048 + 3*512 + l*8]) = f3;
  }
}

#define G1_STEP(tt) { \
  f32x4 acc = {0.f,0.f,0.f,0.f}; \
  acc = mfma16(FRG(32+(tt)*4+0), b0, acc); \
  acc = mfma16(FRG(32+(tt)*4+1), b1, acc); \
  acc = mfma16(FRG(32+(tt)*4+2), b2, acc); \
  acc = mfma16(FRG(32+(tt)*4+3), b3, acc); \
  const f32x4 sh = *reinterpret_cast<const f32x4*>(&bnT[2][(tt)*16 + g*4]); \
  uint2 hp; \
  hp.x = pk2(lrelu(acc[0]+sh[0]), lrelu(acc[1]+sh[1])); \
  hp.y = pk2(lrelu(acc[2]+sh[2]), lrelu(acc[3]+sh[3])); \
  *reinterpret_cast<uint2*>(&hb[hwb + (((tt)*2 + (g>>1))^p)*8]) = hp; }

#define E_STEP(tt, E) { \
  f32x4 acc = {0.f,0.f,0.f,0.f}; \
  acc = mfma16(FRG(64+(tt)*4+0), b0, acc); \
  acc = mfma16(FRG(64+(tt)*4+1), b1, acc); \
  acc = mfma16(FRG(64+(tt)*4+2), b2, acc); \
  acc = mfma16(FRG(64+(tt)*4+3), b3, acc); \
  const f32x4 sh = *reinterpret_cast<const f32x4*>(&bnT[3][(tt)*16 + g*4]); \
  E[0]=lrelu(acc[0]+sh[0])*0.015625f; E[1]=lrelu(acc[1]+sh[1])*0.015625f; \
  E[2]=lrelu(acc[2]+sh[2])*0.015625f; E[3]=lrelu(acc[3]+sh[3])*0.015625f; }

#define EXP_STEP(E) { \
  E[0]=__expf(E[0]-m); E[1]=__expf(E[1]-m); E[2]=__expf(E[2]-m); E[3]=__expf(E[3]-m); }

#define RED5(tt, E) { \
  const uint2 vu = *reinterpret_cast<const uint2*>(&imgV[(size_t)Gc*1024 + l*16 + (tt)*2]); \
  float o0, o1, o2, o3; \
  { float num=E[0]*bfl(vu.x), den=E[0]; \
    num+=sx16(num,1); den+=sx16(den,1); num+=sx16(num,2); den+=sx16(den,2); \
    num+=sx16(num,4); den+=sx16(den,4); num+=sx16(num,8); den+=sx16(den,8); \
    o0 = num*__builtin_amdgcn_rcpf(den); } \
  { float num=E[1]*bfh(vu.x), den=E[1]; \
    num+=sx16(num,1); den+=sx16(den,1); num+=sx16(num,2); den+=sx16(den,2); \
    num+=sx16(num,4); den+=sx16(den,4); num+=sx16(num,8); den+=sx16(den,8); \
    o1 = num*__builtin_amdgcn_rcpf(den); } \
  { float num=E[2]*bfl(vu.y), den=E[2]; \
    num+=sx16(num,1); den+=sx16(den,1); num+=sx16(num,2); den+=sx16(den,2); \
    num+=sx16(num,4); den+=sx16(den,4); num+=sx16(num,8); den+=sx16(den,8); \
    o2 = num*__builtin_amdgcn_rcpf(den); } \
  { float num=E[3]*bfh(vu.y), den=E[3]; \
    num+=sx16(num,1); den+=sx16(den,1); num+=sx16(num,2); den+=sx16(den,2); \
    num+=sx16(num,4); den+=sx16(den,4); num+=sx16(num,8); den+=sx16(den,8); \
    o3 = num*__builtin_amdgcn_rcpf(den); } \
  if (p == 0){ \
    uint2 st; st.x = pk2(o0,o1); st.y = pk2(o2,o3); \
    *reinterpret_cast<uint2*>(&resbf[(size_t)gp*DM + (tt)*16 + g*4]) = st; } }

__global__ __launch_bounds__(256, 2) void k_attn5(
    const unsigned short* __restrict__ imgA, const uint32_t* __restrict__ imgV,
    const unsigned short* __restrict__ wfrag,
    const float* __restrict__ bng1, const float* __restrict__ bng2,
    unsigned short* __restrict__ resbf, int g0){
  __shared__ __align__(16) unsigned short Hb[4][2048];
  __shared__ float bnT[4][DM];   // rows 2,3 used

  const int t = threadIdx.x;
  if (t < DM){
    const float* bp[2] = {bng1, bng2};
    #pragma unroll
    for (int s4=0;s4<2;s4++){
      const float g = bp[s4][t], be = bp[s4][DM+t], mn = bp[s4][2*DM+t], vr = bp[s4][3*DM+t];
      const float sc = g * rsqrtf(vr + EPS);
      bnT[2+s4][t] = be - mn*sc;
    }
  }
  __syncthreads();

  const int w = t >> 6, l = t & 63;
  const int p = l & 15, g = l >> 4;
  unsigned short* hb = Hb[w];
  const int hwb = p*128 + ((g & 1) * 4);

  const int Gc = blockIdx.x*4 + w;
  const int gp = g0 + Gc;

  {
    const bf16x8 b0 = *reinterpret_cast<const bf16x8*>(&imgA[(size_t)Gc*2048 + 0*512 + l*8]);
    const bf16x8 b1 = *reinterpret_cast<const bf16x8*>(&imgA[(size_t)Gc*2048 + 1*512 + l*8]);
    const bf16x8 b2 = *reinterpret_cast<const bf16x8*>(&imgA[(size_t)Gc*2048 + 2*512 + l*8]);
    const bf16x8 b3 = *reinterpret_cast<const bf16x8*>(&imgA[(size_t)Gc*2048 + 3*512 + l*8]);
    G1_STEP(0) G1_STEP(1) G1_STEP(2) G1_STEP(3)
    G1_STEP(4) G1_STEP(5) G1_STEP(6) G1_STEP(7)
  }

  f32x4 e0, e1, e2, e3, e4, e5, e6, e7;
  {
    RD_B()
    E_STEP(0, e0) E_STEP(1, e1) E_STEP(2, e2) E_STEP(3, e3)
    E_STEP(4, e4) E_STEP(5, e5) E_STEP(6, e6) E_STEP(7, e7)
  }

  f32x4 mm = vmax4(vmax4(vmax4(e0,e1), vmax4(e2,e3)), vmax4(vmax4(e4,e5), vmax4(e6,e7)));
  float m = fmaxf(fmaxf(mm[0],mm[1]), fmaxf(mm[2],mm[3]));
  m = fmaxf(m, sx16(m,1)); m = fmaxf(m, sx16(m,2));
  m = fmaxf(m, sx16(m,4)); m = fmaxf(m, sx16(m,8));
  EXP_STEP(e0) EXP_STEP(e1) EXP_STEP(e2) EXP_STEP(e3)
  EXP_STEP(e4) EXP_STEP(e5) EXP_STEP(e6) EXP_STEP(e7)

  RED5(0, e0) RED5(1, e1) RED5(2, e2) RED5(3, e3)
  RED5(4, e4) RED5(5, e5) RED5(6, e6) RED5(7, e7)
}

// ---------------------------------------------------------------- out = lrelu(bn2(W2@res)) + feats  (res is bf16)
__global__ __launch_bounds__(256, 1) void k_out(const unsigned short* __restrict__ resbf,
                                             const float* __restrict__ W2,
                                             const float* __restrict__ bn2,
                                             const float* __restrict__ feats,
                                             float* __restrict__ out){
  __shared__ float W2s[DP][DM+4];
  __shared__ float rt[128][DM+4];
  __shared__ float ob[DP][132];
  __shared__ float bS[DP], bT[DP];
  const int t = threadIdx.x;
  const int b = blockIdx.x >> 5;
  const int n0 = (blockIdx.x & 31) * 128;
  for (int i=t; i<DP*DM; i+=256){ W2s[i>>7][i&127] = W2[i]; }
  if (t < DP){
    float g=bn2[t], be=bn2[DP+t], mn=bn2[2*DP+t], vr=bn2[3*DP+t];
    float s = g*rsqrtf(vr+EPS); bS[t]=s; bT[t]=be-mn*s;
  }
  for (int i=t; i<128*(DM/4); i+=256){
    const int j=i>>5, c4=(i&31)*4;
    const ushort4 u = *reinterpret_cast<const ushort4*>(&resbf[((size_t)(b*NN)+n0+j)*DM + c4]);
    rt[j][c4+0] = bf2f(u.x); rt[j][c4+1] = bf2f(u.y);
    rt[j][c4+2] = bf2f(u.z); rt[j][c4+3] = bf2f(u.w);
  }
  __syncthreads();
  const int j = t>>1, cq = t&1;
  float acc[32];
  #pragma unroll
  for (int i=0;i<32;i++) acc[i]=0.f;
  for (int c=0;c<DM;c+=4){
    const float4 rv = *reinterpret_cast<const float4*>(&rt[j][c]);
    #pragma unroll
    for (int i=0;i<32;i++){
      const float4 wv = *reinterpret_cast<const float4*>(&W2s[cq+2*i][c]);
      acc[i] += wv.x*rv.x + wv.y*rv.y + wv.z*rv.z + wv.w*rv.w;
    }
  }
  #pragma unroll
  for (int i=0;i<32;i++) ob[cq+2*i][j] = acc[i];
  __syncthreads();
  for (int i=t; i<DP*128; i+=256){
    const int ch=i>>7, jj=i&127;
    const size_t o = (size_t)b*DP*NN + (size_t)ch*NN + n0 + jj;
    out[o] = lrelu(ob[ch][jj]*bS[ch] + bT[ch]) + feats[o];
  }
}

// ----------------------------------------------------------------
extern "C" void kernel_launch(void* const* d_in, const int* in_sizes, int n_in,
                              void* d_out, int out_size, void* d_ws, size_t ws_size,
                              hipStream_t stream) {
  const float* feats = (const float*)d_in[0];
  const float* pos   = (const float*)d_in[1];
  const float* W1    = (const float*)d_in[2];
  const float* bn1   = (const float*)d_in[3];
  const float* W2    = (const float*)d_in[4];
  const float* bn2   = (const float*)d_in[5];
  const float* Wq    = (const float*)d_in[6];
  const float* Wk    = (const float*)d_in[7];
  const float* Wv    = (const float*)d_in[8];
  const float* Wd1   = (const float*)d_in[9];
  const float* bnd1  = (const float*)d_in[10];
  const float* Wd2   = (const float*)d_in[11];
  const float* bnd2  = (const float*)d_in[12];
  const float* Wg1   = (const float*)d_in[13];
  const float* bng1  = (const float*)d_in[14];
  const float* Wg2   = (const float*)d_in[15];
  const float* bng2  = (const float*)d_in[16];
  float* out = (float*)d_out;

  unsigned short* qbf = (unsigned short*)d_ws;              // 4 MiB
  unsigned short* kbf = qbf + 2097152;                      // 4 MiB
  unsigned short* vbf = kbf + 2097152;                      // 4 MiB
  float* sqn = (float*)(vbf + 2097152);                     // 64 KiB
  int*   idx = (int*)(sqn + 16384);                         // 1 MiB
  unsigned short* wfrag = (unsigned short*)(idx + 262144);  // 104 KiB
  unsigned short* poolu = wfrag + 53248;                    // 20 MiB pool
  // knn phase overlays
  float* fpm = (float*)poolu;                               // 4 MiB
  unsigned short* cfrag = (unsigned short*)(fpm + 1048576); // 4 MiB
  unsigned short* qfrag = cfrag + 2097152;                  // 4 MiB
  int* cand = (int*)(qfrag + 2097152);                      // 4 MiB (64/query)
  // attn phase overlays
  unsigned short* resbf = poolu;                            // 4 MiB
  unsigned short* imgA  = poolu + 2097152;                  // 8 MiB
  uint32_t* imgV = (uint32_t*)(imgA + 4194304);             // 8 MiB

  k_sqnorm<<<(NB*NN)/256, 256, 0, stream>>>(feats, sqn);
  k_fprep <<<NB*(NN/64), 256, 0, stream>>>(feats, cfrag, qfrag, fpm);
  k_knn3  <<<NB*128, 256, 0, stream>>>(cfrag, qfrag, sqn, cand);
  k_refine<<<(NB*NN)/4, 256, 0, stream>>>(fpm, sqn, cand, idx);
  k_wprep <<<26, 256, 0, stream>>>(Wd1, bnd1, Wd2, bnd2, Wg1, bng1, Wg2, bng2, wfrag);
  k_xqkv  <<<NB*(NN/64), 256, 0, stream>>>(feats, W1, bn1, Wq, Wk, Wv, qbf, kbf, vbf);

  for (int c = 0; c < NCHUNK; ++c){
    const int g0 = c * CHPTS;
    k_pe5  <<<CHPTS/4, 256, 0, stream>>>(pos, qbf, kbf, vbf, idx, wfrag,
                                         bnd1, bnd2, bng1, bng2, imgA, imgV, g0);
    k_attn5<<<CHPTS/4, 256, 0, stream>>>(imgA, imgV, wfrag, bng1, bng2, resbf, g0);
  }

  k_out   <<<NB*(NN/128), 256, 0, stream>>>(resbf, W2, bn2, feats, out);
}

// Round 12
// 703.608 us; speedup vs baseline: 3.7028x; 1.0925x over previous
//
#include <hip/hip_runtime.h>
#include <cstdint>
#include <cstddef>

#define NB 4
#define NN 4096
#define KK 16
#define DP 64
#define DM 128
#define EPS 1e-5f
#define NCHUNK 8
#define CHPTS (NN*NB/NCHUNK)   // 2048 points per chunk

typedef __attribute__((ext_vector_type(8))) short bf16x8;
typedef __attribute__((ext_vector_type(4))) float f32x4;
typedef __attribute__((ext_vector_type(4))) unsigned int u32x4;

__device__ __forceinline__ float lrelu(float x){ return x >= 0.f ? x : 0.2f*x; }

__device__ __forceinline__ unsigned short f2bf(float x){
  union { float f; uint32_t u; } a; a.f = x;
  return (unsigned short)((a.u + 0x7fffu + ((a.u >> 16) & 1u)) >> 16);
}
__device__ __forceinline__ float bf2f(unsigned short h){
  union { uint32_t u; float f; } a; a.u = ((uint32_t)h) << 16; return a.f;
}
__device__ __forceinline__ uint32_t pk2(float a, float b){
  return (uint32_t)f2bf(a) | ((uint32_t)f2bf(b) << 16);
}
__device__ __forceinline__ float bfl(uint32_t w){ return __uint_as_float(w << 16); }
__device__ __forceinline__ float bfh(uint32_t w){ return __uint_as_float(w & 0xffff0000u); }

__device__ __forceinline__ f32x4 mfma16(bf16x8 a, bf16x8 b, f32x4 c){
  return __builtin_amdgcn_mfma_f32_16x16x32_bf16(a, b, c, 0, 0, 0);
}
__device__ __forceinline__ float sx16(float v, int m){ return __shfl_xor(v, m, 16); }
__device__ __forceinline__ f32x4 vmax4(f32x4 a, f32x4 b){
  f32x4 r; r[0]=fmaxf(a[0],b[0]); r[1]=fmaxf(a[1],b[1]); r[2]=fmaxf(a[2],b[2]); r[3]=fmaxf(a[3],b[3]); return r;
}
__device__ __forceinline__ u32x4 sub8(u32x4 a, u32x4 k){
  u32x4 r;
  r[0] = pk2(bfl(a[0])-bfl(k[0]), bfh(a[0])-bfh(k[0]));
  r[1] = pk2(bfl(a[1])-bfl(k[1]), bfh(a[1])-bfh(k[1]));
  r[2] = pk2(bfl(a[2])-bfl(k[2]), bfh(a[2])-bfh(k[2]));
  r[3] = pk2(bfl(a[3])-bfl(k[3]), bfh(a[3])-bfh(k[3]));
  return r;
}

// ---------------------------------------------------------------- sq norms
__global__ __launch_bounds__(256) void k_sqnorm(const float* __restrict__ feats,
                                                float* __restrict__ sqn){
  const int i = blockIdx.x*256 + threadIdx.x;
  const int b = i >> 12, n = i & (NN-1);
  const float* f = feats + (size_t)b*DP*NN + n;
  float s = 0.f;
  #pragma unroll
  for (int c=0;c<DP;c++){ const float v = f[(size_t)c*NN]; s += v*v; }
  sqn[i] = s;
}

// ---------------------------------------------------------------- feats -> bf16 hi/lo MFMA fragments + point-major f32 copy
__global__ __launch_bounds__(256) void k_fprep(const float* __restrict__ feats,
                                               unsigned short* __restrict__ cfrag,
                                               unsigned short* __restrict__ qfrag,
                                               float* __restrict__ fpm){
  __shared__ float ft[DP][65];
  const int t = threadIdx.x;
  const int b = blockIdx.x >> 6;
  const int n0 = (blockIdx.x & 63) * 64;
  for (int i=t; i<DP*64; i+=256){
    const int dim = i >> 6, pt = i & 63;
    ft[dim][pt] = feats[(size_t)b*DP*NN + (size_t)dim*NN + n0 + pt];
  }
  __syncthreads();
  for (int i=t; i<64*DP; i+=256){
    const int pt = i >> 6, dim = i & 63;
    fpm[((size_t)(b*NN) + n0 + pt)*DP + dim] = ft[dim][pt];
  }
  #pragma unroll
  for (int v = t; v < 1024; v += 256){
    const int l = v & 63, hl = (v>>6)&1, ks = (v>>7)&1, ntl = v>>8;
    const int ptl = ntl*16 + (l&15);
    const int d0 = ks*32 + (l>>4)*8;
    unsigned short qo[8], co[8];
    #pragma unroll
    for (int j=0;j<8;j++){
      const float x = ft[d0+j][ptl];
      const unsigned short qh = f2bf(x);
      const float y = -2.f*x;
      const unsigned short ch = f2bf(y);
      qo[j] = hl ? f2bf(x - bf2f(qh)) : qh;
      co[j] = hl ? f2bf(y - bf2f(ch)) : ch;
    }
    const int nt = (n0 >> 4) + ntl;
    const size_t off = ((size_t)((b*256 + nt)*4 + ks*2 + hl))*512 + l*8;
    uint4 qv, cv;
    qv.x = (uint32_t)qo[0] | ((uint32_t)qo[1]<<16);
    qv.y = (uint32_t)qo[2] | ((uint32_t)qo[3]<<16);
    qv.z = (uint32_t)qo[4] | ((uint32_t)qo[5]<<16);
    qv.w = (uint32_t)qo[6] | ((uint32_t)qo[7]<<16);
    cv.x = (uint32_t)co[0] | ((uint32_t)co[1]<<16);
    cv.y = (uint32_t)co[2] | ((uint32_t)co[3]<<16);
    cv.z = (uint32_t)co[4] | ((uint32_t)co[5]<<16);
    cv.w = (uint32_t)co[6] | ((uint32_t)co[7]<<16);
    *reinterpret_cast<uint4*>(qfrag + off) = qv;
    *reinterpret_cast<uint4*>(cfrag + off) = cv;
  }
}

// ---------------------------------------------------------------- MFMA kNN v4: (query-tile, quarter) per wave, packed u32 top-16
// grid NB*256 blocks x 4 waves; wave streams 64 candidate tiles; exact top-16 per quarter.
__global__ __launch_bounds__(256, 4) void k_knn4(const unsigned short* __restrict__ cfrag,
                                                 const unsigned short* __restrict__ qfrag,
                                                 const float* __restrict__ sqn,
                                                 int* __restrict__ cand){
  const int t = threadIdx.x, w = t >> 6, l = t & 63, g = l >> 4;
  const int b = blockIdx.x >> 8;
  const int combo = (blockIdx.x & 255)*4 + w;   // 1024 combos per batch
  const int qt = combo >> 2, quarter = combo & 3;
  const int ct0 = quarter * 64;

  bf16x8 qf00, qf01, qf10, qf11;
  {
    const unsigned short* qb = qfrag + ((size_t)(b*256 + qt))*2048 + l*8;
    qf00 = *reinterpret_cast<const bf16x8*>(qb);
    qf01 = *reinterpret_cast<const bf16x8*>(qb + 512);
    qf10 = *reinterpret_cast<const bf16x8*>(qb + 1024);
    qf11 = *reinterpret_cast<const bf16x8*>(qb + 1536);
  }
  const unsigned short* cb = cfrag + ((size_t)(b*256))*2048 + l*8;
  const float sqq = sqn[b*NN + qt*16 + (l & 15)];

  uint32_t kk[16];
  #pragma unroll
  for (int s=0;s<16;s++) kk[s] = 0xFFFFFFFFu;
  uint32_t umax = 0xFFFFFFFFu;

  bf16x8 c00 = *reinterpret_cast<const bf16x8*>(cb + (size_t)ct0*2048);
  bf16x8 c01 = *reinterpret_cast<const bf16x8*>(cb + (size_t)ct0*2048 + 512);
  bf16x8 c10 = *reinterpret_cast<const bf16x8*>(cb + (size_t)ct0*2048 + 1024);
  bf16x8 c11 = *reinterpret_cast<const bf16x8*>(cb + (size_t)ct0*2048 + 1536);

  const float* sqb = sqn + b*NN + g*4;

  #pragma unroll 1
  for (int it=0; it<64; ++it){
    const int ct = ct0 + it;
    bf16x8 n00, n01, n10, n11;
    if (it < 63){
      const unsigned short* nb_ = cb + (size_t)(ct+1)*2048;
      n00 = *reinterpret_cast<const bf16x8*>(nb_);
      n01 = *reinterpret_cast<const bf16x8*>(nb_ + 512);
      n10 = *reinterpret_cast<const bf16x8*>(nb_ + 1024);
      n11 = *reinterpret_cast<const bf16x8*>(nb_ + 1536);
    }
    f32x4 acc = {0.f,0.f,0.f,0.f};
    acc = mfma16(c00, qf00, acc);
    acc = mfma16(c10, qf10, acc);
    acc = mfma16(c00, qf01, acc);
    acc = mfma16(c01, qf00, acc);
    acc = mfma16(c10, qf11, acc);
    acc = mfma16(c11, qf10, acc);
    const float4 sq4 = *reinterpret_cast<const float4*>(&sqb[ct*16]);
    const int cbase = ct*16 + g*4;
    const uint32_t p0 = (__float_as_uint(fmaxf(acc[0]+sq4.x+sqq, 0.f)) & 0xFFFFF000u) | (cbase+0);
    const uint32_t p1 = (__float_as_uint(fmaxf(acc[1]+sq4.y+sqq, 0.f)) & 0xFFFFF000u) | (cbase+1);
    const uint32_t p2 = (__float_as_uint(fmaxf(acc[2]+sq4.z+sqq, 0.f)) & 0xFFFFF000u) | (cbase+2);
    const uint32_t p3 = (__float_as_uint(fmaxf(acc[3]+sq4.w+sqq, 0.f)) & 0xFFFFF000u) | (cbase+3);
    const uint32_t mn = min(min(p0,p1), min(p2,p3));
    if (mn < umax){
      uint32_t pv[4] = {p0,p1,p2,p3};
      #pragma unroll
      for (int u=0;u<4;u++){
        if (pv[u] < umax){
          bool done=false;
          #pragma unroll
          for (int s=0;s<16;s++){
            if (!done && kk[s]==umax){ kk[s]=pv[u]; done=true; }
          }
          umax = kk[0];
          #pragma unroll
          for (int s=1;s<16;s++) umax = max(umax, kk[s]);
        }
      }
    }
    c00 = n00; c01 = n01; c10 = n10; c11 = n11;
  }

  // merge across the 4 g-lanes per query: exact quarter top-16 -> cand[q][quarter*16 + r]
  const int q = qt*16 + (l & 15);
  int* op = cand + ((size_t)(b*NN) + q)*64 + quarter*16;
  #pragma unroll 1
  for (int r=0; r<KK; ++r){
    uint32_t bm = kk[0];
    #pragma unroll
    for (int s=1;s<16;s++) bm = min(bm, kk[s]);
    uint32_t om;
    om = __shfl_xor((int)bm, 16); bm = min(bm, om);
    om = __shfl_xor((int)bm, 32); bm = min(bm, om);
    #pragma unroll
    for (int s=0;s<16;s++){
      if (kk[s]==bm) kk[s] = 0xFFFFFFFFu;
    }
    if (g == 0) op[r] = (int)(bm & 0xFFFu);
  }
}

// ---------------------------------------------------------------- exact f32 refine: wave per query, lane per candidate (64)
__global__ __launch_bounds__(256) void k_refine(const float* __restrict__ fpm,
                                                const float* __restrict__ sqn,
                                                const int* __restrict__ cand,
                                                int* __restrict__ idx_ws){
  const int t = threadIdx.x, w = t >> 6, l = t & 63;
  const int q = blockIdx.x*4 + w;           // global point id
  const int b = q >> 12;
  const int mi = cand[(size_t)q*64 + l];
  const float* qv = fpm + (size_t)q*DP;
  const float* cv = fpm + ((size_t)(b*NN) + mi)*DP;
  float dot = 0.f;
  #pragma unroll
  for (int d=0; d<DP; d+=4){
    const float4 a = *reinterpret_cast<const float4*>(&qv[d]);
    const float4 x = *reinterpret_cast<const float4*>(&cv[d]);
    dot += a.x*x.x; dot += a.y*x.y; dot += a.z*x.z; dot += a.w*x.w;
  }
  // sqn[q] is query-constant -> rank-invariant, dropped
  const float dist = sqn[b*NN + mi] - 2.f*dot;
  int rank = 0;
  #pragma unroll 4
  for (int j=0; j<64; j++){
    const float dj = __shfl(dist, j);
    const int   ij = __shfl(mi,  j);
    rank += (dj < dist || (dj == dist && ij < mi)) ? 1 : 0;
  }
  if (rank < KK) idx_ws[(size_t)q*KK + rank] = mi;
}

// ---------------------------------------------------------------- x -> q,k,v (bf16 point-major), fully fused
__global__ __launch_bounds__(256, 1) void k_xqkv(const float* __restrict__ feats,
                                              const float* __restrict__ W1,
                                              const float* __restrict__ bn1,
                                              const float* __restrict__ Wq,
                                              const float* __restrict__ Wk,
                                              const float* __restrict__ Wv,
                                              unsigned short* __restrict__ qbf,
                                              unsigned short* __restrict__ kbf,
                                              unsigned short* __restrict__ vbf){
  __shared__ float W1s[DM][DP+1];
  __shared__ float ft[DP][64];
  __shared__ float xt[64][DM+4];
  __shared__ float Ws[DM][DM+4];
  __shared__ float bS[DM], bT[DM];
  const int t = threadIdx.x;
  const int b = blockIdx.x >> 6;
  const int n0 = (blockIdx.x & 63) * 64;
  for (int i=t; i<DM*DP; i+=256){ W1s[i>>6][i&63] = W1[i]; }
  if (t < DM){
    float g = bn1[t], be = bn1[DM+t], mn = bn1[2*DM+t], vr = bn1[3*DM+t];
    float s = g*rsqrtf(vr+EPS); bS[t]=s; bT[t]=be-mn*s;
  }
  for (int i=t; i<DP*64; i+=256){
    const int c = i>>6, j = i&63;
    ft[c][j] = feats[(size_t)b*DP*NN + (size_t)c*NN + n0 + j];
  }
  __syncthreads();
  const int j = t >> 2, cq = t & 3;
  {
    float acc[32];
    #pragma unroll
    for (int i=0;i<32;i++) acc[i]=0.f;
    for (int c=0;c<DP;c++){
      const float fv = ft[c][j];
      #pragma unroll
      for (int i=0;i<32;i++) acc[i] += W1s[cq+4*i][c]*fv;
    }
    #pragma unroll
    for (int i=0;i<32;i++){
      const int ch = cq + 4*i;
      xt[j][ch] = lrelu(acc[i]*bS[ch] + bT[ch]);
    }
  }
  const float* Wp[3] = {Wq, Wk, Wv};
  unsigned short* Op[3] = {qbf, kbf, vbf};
  for (int wi=0; wi<3; wi++){
    __syncthreads();
    for (int i=t; i<DM*DM; i+=256){ Ws[i>>7][i&127] = Wp[wi][i]; }
    __syncthreads();
    float acc[32];
    #pragma unroll
    for (int i=0;i<32;i++) acc[i]=0.f;
    for (int c=0;c<DM;c+=4){
      const float4 xv = *reinterpret_cast<const float4*>(&xt[j][c]);
      #pragma unroll
      for (int i=0;i<32;i++){
        const float4 wv = *reinterpret_cast<const float4*>(&Ws[cq+4*i][c]);
        acc[i] += wv.x*xv.x + wv.y*xv.y + wv.z*xv.z + wv.w*xv.w;
      }
    }
    unsigned short* op = Op[wi] + ((size_t)(b*NN) + n0 + j)*DM;
    #pragma unroll
    for (int i=0;i<32;i++) op[cq+4*i] = f2bf(acc[i]);
  }
}

// ---------------------------------------------------------------- weight prep: 104 bf16 MFMA fragments, bn-scale folded
__global__ __launch_bounds__(256) void k_wprep(
    const float* __restrict__ Wd1, const float* __restrict__ bnd1,
    const float* __restrict__ Wd2, const float* __restrict__ bnd2,
    const float* __restrict__ Wg1, const float* __restrict__ bng1,
    const float* __restrict__ Wg2, const float* __restrict__ bng2,
    unsigned short* __restrict__ wfrag){
  const int i = blockIdx.x*256 + threadIdx.x;
  if (i >= 104*64) return;
  const int f = i >> 6, l = i & 63;
  const int r16 = l & 15, kg = (l >> 4) * 8;
  unsigned short o8[8];
  if (f < 96){
    const int mat = f >> 5, tt = (f >> 2) & 7, ks = f & 3;
    const float* W; const float* bn;
    if (mat == 0){ W = Wd2; bn = bnd2; }
    else if (mat == 1){ W = Wg1; bn = bng1; }
    else { W = Wg2; bn = bng2; }
    const int row = tt*16 + r16;
    const float s = bn[row] * rsqrtf(bn[3*DM+row] + EPS);
    const float* src = W + (size_t)row*DM + ks*32 + kg;
    #pragma unroll
    for (int j=0;j<8;j++) o8[j] = f2bf(s * src[j]);
  } else {
    const int tt = f - 96;
    const int row = tt*16 + r16;
    const float s = bnd1[row] * rsqrtf(bnd1[3*DM+row] + EPS);
    #pragma unroll
    for (int j=0;j<8;j++){
      const int k = kg + j;
      o8[j] = (k < 3) ? f2bf(s * Wd1[row*3 + k]) : (unsigned short)0;
    }
  }
  uint4 v;
  v.x = (uint32_t)o8[0] | ((uint32_t)o8[1]<<16);
  v.y = (uint32_t)o8[2] | ((uint32_t)o8[3]<<16);
  v.z = (uint32_t)o8[4] | ((uint32_t)o8[5]<<16);
  v.w = (uint32_t)o8[6] | ((uint32_t)o8[7]<<16);
  *reinterpret_cast<uint4*>(wfrag + (size_t)i*8) = v;
}

// ---------------------------------------------------------------- staged attention
#define FRG(fi) (*reinterpret_cast<const bf16x8*>(&wfrag[(size_t)(fi)*512 + l*8]))

#define RD_B() \
  const bf16x8 b0 = *reinterpret_cast<const bf16x8*>(&hb[p*128 + ((0*4+g)^p)*8]); \
  const bf16x8 b1 = *reinterpret_cast<const bf16x8*>(&hb[p*128 + ((1*4+g)^p)*8]); \
  const bf16x8 b2 = *reinterpret_cast<const bf16x8*>(&hb[p*128 + ((2*4+g)^p)*8]); \
  const bf16x8 b3 = *reinterpret_cast<const bf16x8*>(&hb[p*128 + ((3*4+g)^p)*8]);

#define H1_STEP(tt) { \
  f32x4 acc = {0.f,0.f,0.f,0.f}; \
  acc = mfma16(FRG(96+(tt)), bv, acc); \
  const f32x4 sh = *reinterpret_cast<const f32x4*>(&bnT[0][(tt)*16 + g*4]); \
  uint2 hp; \
  hp.x = pk2(lrelu(acc[0]+sh[0]), lrelu(acc[1]+sh[1])); \
  hp.y = pk2(lrelu(acc[2]+sh[2]), lrelu(acc[3]+sh[3])); \
  *reinterpret_cast<uint2*>(&hb[hwb + (((tt)*2 + (g>>1))^p)*8]) = hp; }

#define PE_STEP(tt, PE) { \
  f32x4 acc = {0.f,0.f,0.f,0.f}; \
  acc = mfma16(FRG(0+(tt)*4+0), b0, acc); \
  acc = mfma16(FRG(0+(tt)*4+1), b1, acc); \
  acc = mfma16(FRG(0+(tt)*4+2), b2, acc); \
  acc = mfma16(FRG(0+(tt)*4+3), b3, acc); \
  const f32x4 sh = *reinterpret_cast<const f32x4*>(&bnT[1][(tt)*16 + g*4]); \
  PE[0]=lrelu(acc[0]+sh[0]); PE[1]=lrelu(acc[1]+sh[1]); \
  PE[2]=lrelu(acc[2]+sh[2]); PE[3]=lrelu(acc[3]+sh[3]); }

#define VPE_STEP(tt, PE) { \
  const uint2 du = *reinterpret_cast<const uint2*>(&hb[p*128 + (((tt)*2+(g>>1))^p)*8 + (g&1)*4]); \
  uint2 st; \
  st.x = pk2(bfl(du.x)+PE[0], bfh(du.x)+PE[1]); \
  st.y = pk2(bfl(du.y)+PE[2], bfh(du.y)+PE[3]); \
  *reinterpret_cast<uint2*>(&imgV[(size_t)Gc*1024 + l*16 + (tt)*2]) = st; }

#define QPE_STEP(tt, PE) { \
  const uint2 qu = *reinterpret_cast<const uint2*>(&qbf[(size_t)gp*DM + (tt)*16 + g*4]); \
  uint2 hp; \
  hp.x = pk2(bfl(qu.x)+PE[0], bfh(qu.x)+PE[1]); \
  hp.y = pk2(bfl(qu.y)+PE[2], bfh(qu.y)+PE[3]); \
  *reinterpret_cast<uint2*>(&hb[hwb + (((tt)*2 + (g>>1))^p)*8]) = hp; }

__global__ __launch_bounds__(256, 2) void k_pe5(
    const float* __restrict__ pos, const unsigned short* __restrict__ qbf,
    const unsigned short* __restrict__ kbf, const unsigned short* __restrict__ vbf,
    const int* __restrict__ idx_ws, const unsigned short* __restrict__ wfrag,
    const float* __restrict__ bnd1, const float* __restrict__ bnd2,
    const float* __restrict__ bng1, const float* __restrict__ bng2,
    unsigned short* __restrict__ imgA, uint32_t* __restrict__ imgV, int g0){
  __shared__ __align__(16) unsigned short Hb[4][2048];
  __shared__ float bnT[2][DM];

  const int t = threadIdx.x;
  if (t < DM){
    const float* bp[2] = {bnd1, bnd2};
    #pragma unroll
    for (int s4=0;s4<2;s4++){
      const float g = bp[s4][t], be = bp[s4][DM+t], mn = bp[s4][2*DM+t], vr = bp[s4][3*DM+t];
      const float sc = g * rsqrtf(vr + EPS);
      bnT[s4][t] = be - mn*sc;
    }
  }
  __syncthreads();

  const int w = t >> 6, l = t & 63;
  const int p = l & 15, g = l >> 4;
  unsigned short* hb = Hb[w];
  const int hwb = p*128 + ((g & 1) * 4);

  const int Gc = blockIdx.x*4 + w;
  const int gp = g0 + Gc;
  const int b = gp >> 12, n = gp & (NN-1);
  const int mi = idx_ws[gp*KK + p];

  uint32_t bw0 = 0u, bw1 = 0u;
  if (g == 0){
    const float* posb = pos + (size_t)b*3*NN;
    const float rx = posb[n]      - posb[mi];
    const float ry = posb[NN+n]   - posb[NN+mi];
    const float rz = posb[2*NN+n] - posb[2*NN+mi];
    bw0 = pk2(rx, ry);
    bw1 = pk2(rz, 0.f);
  }
  u32x4 bwv = {bw0, bw1, 0u, 0u};
  const bf16x8 bv = __builtin_bit_cast(bf16x8, bwv);

  H1_STEP(0) H1_STEP(1) H1_STEP(2) H1_STEP(3)
  H1_STEP(4) H1_STEP(5) H1_STEP(6) H1_STEP(7)

  f32x4 pe0, pe1, pe2, pe3, pe4, pe5, pe6, pe7;
  {
    RD_B()
    PE_STEP(0, pe0) PE_STEP(1, pe1) PE_STEP(2, pe2) PE_STEP(3, pe3)
    PE_STEP(4, pe4) PE_STEP(5, pe5) PE_STEP(6, pe6) PE_STEP(7, pe7)
  }

  {
    const unsigned short* vrow = vbf + ((size_t)(b*NN) + mi)*DM;
    const bf16x8 xv0 = *reinterpret_cast<const bf16x8*>(&vrow[ 0 + g*8]);
    const bf16x8 xv1 = *reinterpret_cast<const bf16x8*>(&vrow[32 + g*8]);
    const bf16x8 xv2 = *reinterpret_cast<const bf16x8*>(&vrow[64 + g*8]);
    const bf16x8 xv3 = *reinterpret_cast<const bf16x8*>(&vrow[96 + g*8]);
    *reinterpret_cast<bf16x8*>(&hb[p*128 + ((0*4+g)^p)*8]) = xv0;
    *reinterpret_cast<bf16x8*>(&hb[p*128 + ((1*4+g)^p)*8]) = xv1;
    *reinterpret_cast<bf16x8*>(&hb[p*128 + ((2*4+g)^p)*8]) = xv2;
    *reinterpret_cast<bf16x8*>(&hb[p*128 + ((3*4+g)^p)*8]) = xv3;
    VPE_STEP(0, pe0) VPE_STEP(1, pe1) VPE_STEP(2, pe2) VPE_STEP(3, pe3)
    VPE_STEP(4, pe4) VPE_STEP(5, pe5) VPE_STEP(6, pe6) VPE_STEP(7, pe7)
  }

  QPE_STEP(0, pe0) QPE_STEP(1, pe1) QPE_STEP(2, pe2) QPE_STEP(3, pe3)
  QPE_STEP(4, pe4) QPE_STEP(5, pe5) QPE_STEP(6, pe6) QPE_STEP(7, pe7)
  {
    const unsigned short* krow = kbf + ((size_t)(b*NN) + mi)*DM;
    const bf16x8 xk0 = *reinterpret_cast<const bf16x8*>(&krow[ 0 + g*8]);
    const bf16x8 xk1 = *reinterpret_cast<const bf16x8*>(&krow[32 + g*8]);
    const bf16x8 xk2 = *reinterpret_cast<const bf16x8*>(&krow[64 + g*8]);
    const bf16x8 xk3 = *reinterpret_cast<const bf16x8*>(&krow[96 + g*8]);
    RD_B()
    const u32x4 f0 = sub8(__builtin_bit_cast(u32x4, b0), __builtin_bit_cast(u32x4, xk0));
    const u32x4 f1 = sub8(__builtin_bit_cast(u32x4, b1), __builtin_bit_cast(u32x4, xk1));
    const u32x4 f2 = sub8(__builtin_bit_cast(u32x4, b2), __builtin_bit_cast(u32x4, xk2));
    const u32x4 f3 = sub8(__builtin_bit_cast(u32x4, b3), __builtin_bit_cast(u32x4, xk3));
    *reinterpret_cast<u32x4*>(&imgA[(size_t)Gc*2048 + 0*512 + l*8]) = f0;
    *reinterpret_cast<u32x4*>(&imgA[(size_t)Gc*2048 + 1*512 + l*8]) = f1;
    *reinterpret_cast<u32x4*>(&imgA[(size_t)Gc*2048 + 2*512 + l*8]) = f2;
    *reinterpret_cast<u32x4*>(&imgA[(size_t)Gc*2048 + 3*512 + l*8]) = f3;
  }
}

#define G1_STEP(tt) { \
  f32x4 acc = {0.f,0.f,0.f,0.f}; \
  acc = mfma16(FRG(32+(tt)*4+0), b0, acc); \
  acc = mfma16(FRG(32+(tt)*4+1), b1, acc); \
  acc = mfma16(FRG(32+(tt)*4+2), b2, acc); \
  acc = mfma16(FRG(32+(tt)*4+3), b3, acc); \
  const f32x4 sh = *reinterpret_cast<const f32x4*>(&bnT[2][(tt)*16 + g*4]); \
  uint2 hp; \
  hp.x = pk2(lrelu(acc[0]+sh[0]), lrelu(acc[1]+sh[1])); \
  hp.y = pk2(lrelu(acc[2]+sh[2]), lrelu(acc[3]+sh[3])); \
  *reinterpret_cast<uint2*>(&hb[hwb + (((tt)*2 + (g>>1))^p)*8]) = hp; }

#define E_STEP(tt, E) { \
  f32x4 acc = {0.f,0.f,0.f,0.f}; \
  acc = mfma16(FRG(64+(tt)*4+0), b0, acc); \
  acc = mfma16(FRG(64+(tt)*4+1), b1, acc); \
  acc = mfma16(FRG(64+(tt)*4+2), b2, acc); \
  acc = mfma16(FRG(64+(tt)*4+3), b3, acc); \
  const f32x4 sh = *reinterpret_cast<const f32x4*>(&bnT[3][(tt)*16 + g*4]); \
  E[0]=lrelu(acc[0]+sh[0])*0.015625f; E[1]=lrelu(acc[1]+sh[1])*0.015625f; \
  E[2]=lrelu(acc[2]+sh[2])*0.015625f; E[3]=lrelu(acc[3]+sh[3])*0.015625f; }

#define EXP_STEP(E) { \
  E[0]=__expf(E[0]-m); E[1]=__expf(E[1]-m); E[2]=__expf(E[2]-m); E[3]=__expf(E[3]-m); }

#define RED5(tt, E) { \
  const uint2 vu = *reinterpret_cast<const uint2*>(&imgV[(size_t)Gc*1024 + l*16 + (tt)*2]); \
  float o0, o1, o2, o3; \
  { float num=E[0]*bfl(vu.x), den=E[0]; \
    num+=sx16(num,1); den+=sx16(den,1); num+=sx16(num,2); den+=sx16(den,2); \
    num+=sx16(num,4); den+=sx16(den,4); num+=sx16(num,8); den+=sx16(den,8); \
    o0 = num*__builtin_amdgcn_rcpf(den); } \
  { float num=E[1]*bfh(vu.x), den=E[1]; \
    num+=sx16(num,1); den+=sx16(den,1); num+=sx16(num,2); den+=sx16(den,2); \
    num+=sx16(num,4); den+=sx16(den,4); num+=sx16(num,8); den+=sx16(den,8); \
    o1 = num*__builtin_amdgcn_rcpf(den); } \
  { float num=E[2]*bfl(vu.y), den=E[2]; \
    num+=sx16(num,1); den+=sx16(den,1); num+=sx16(num,2); den+=sx16(den,2); \
    num+=sx16(num,4); den+=sx16(den,4); num+=sx16(num,8); den+=sx16(den,8); \
    o2 = num*__builtin_amdgcn_rcpf(den); } \
  { float num=E[3]*bfh(vu.y), den=E[3]; \
    num+=sx16(num,1); den+=sx16(den,1); num+=sx16(num,2); den+=sx16(den,2); \
    num+=sx16(num,4); den+=sx16(den,4); num+=sx16(num,8); den+=sx16(den,8); \
    o3 = num*__builtin_amdgcn_rcpf(den); } \
  if (p == 0){ \
    uint2 st; st.x = pk2(o0,o1); st.y = pk2(o2,o3); \
    *reinterpret_cast<uint2*>(&resbf[(size_t)gp*DM + (tt)*16 + g*4]) = st; } }

__global__ __launch_bounds__(256, 2) void k_attn5(
    const unsigned short* __restrict__ imgA, const uint32_t* __restrict__ imgV,
    const unsigned short* __restrict__ wfrag,
    const float* __restrict__ bng1, const float* __restrict__ bng2,
    unsigned short* __restrict__ resbf, int g0){
  __shared__ __align__(16) unsigned short Hb[4][2048];
  __shared__ float bnT[4][DM];   // rows 2,3 used

  const int t = threadIdx.x;
  if (t < DM){
    const float* bp[2] = {bng1, bng2};
    #pragma unroll
    for (int s4=0;s4<2;s4++){
      const float g = bp[s4][t], be = bp[s4][DM+t], mn = bp[s4][2*DM+t], vr = bp[s4][3*DM+t];
      const float sc = g * rsqrtf(vr + EPS);
      bnT[2+s4][t] = be - mn*sc;
    }
  }
  __syncthreads();

  const int w = t >> 6, l = t & 63;
  const int p = l & 15, g = l >> 4;
  unsigned short* hb = Hb[w];
  const int hwb = p*128 + ((g & 1) * 4);

  const int Gc = blockIdx.x*4 + w;
  const int gp = g0 + Gc;

  {
    const bf16x8 b0 = *reinterpret_cast<const bf16x8*>(&imgA[(size_t)Gc*2048 + 0*512 + l*8]);
    const bf16x8 b1 = *reinterpret_cast<const bf16x8*>(&imgA[(size_t)Gc*2048 + 1*512 + l*8]);
    const bf16x8 b2 = *reinterpret_cast<const bf16x8*>(&imgA[(size_t)Gc*2048 + 2*512 + l*8]);
    const bf16x8 b3 = *reinterpret_cast<const bf16x8*>(&imgA[(size_t)Gc*2048 + 3*512 + l*8]);
    G1_STEP(0) G1_STEP(1) G1_STEP(2) G1_STEP(3)
    G1_STEP(4) G1_STEP(5) G1_STEP(6) G1_STEP(7)
  }

  f32x4 e0, e1, e2, e3, e4, e5, e6, e7;
  {
    RD_B()
    E_STEP(0, e0) E_STEP(1, e1) E_STEP(2, e2) E_STEP(3, e3)
    E_STEP(4, e4) E_STEP(5, e5) E_STEP(6, e6) E_STEP(7, e7)
  }

  f32x4 mm = vmax4(vmax4(vmax4(e0,e1), vmax4(e2,e3)), vmax4(vmax4(e4,e5), vmax4(e6,e7)));
  float m = fmaxf(fmaxf(mm[0],mm[1]), fmaxf(mm[2],mm[3]));
  m = fmaxf(m, sx16(m,1)); m = fmaxf(m, sx16(m,2));
  m = fmaxf(m, sx16(m,4)); m = fmaxf(m, sx16(m,8));
  EXP_STEP(e0) EXP_STEP(e1) EXP_STEP(e2) EXP_STEP(e3)
  EXP_STEP(e4) EXP_STEP(e5) EXP_STEP(e6) EXP_STEP(e7)

  RED5(0, e0) RED5(1, e1) RED5(2, e2) RED5(3, e3)
  RED5(4, e4) RED5(5, e5) RED5(6, e6) RED5(7, e7)
}

// ---------------------------------------------------------------- out = lrelu(bn2(W2@res)) + feats  (res is bf16)
__global__ __launch_bounds__(256, 1) void k_out(const unsigned short* __restrict__ resbf,
                                             const float* __restrict__ W2,
                                             const float* __restrict__ bn2,
                                             const float* __restrict__ feats,
                                             float* __restrict__ out){
  __shared__ float W2s[DP][DM+4];
  __shared__ float rt[128][DM+4];
  __shared__ float ob[DP][132];
  __shared__ float bS[DP], bT[DP];
  const int t = threadIdx.x;
  const int b = blockIdx.x >> 5;
  const int n0 = (blockIdx.x & 31) * 128;
  for (int i=t; i<DP*DM; i+=256){ W2s[i>>7][i&127] = W2[i]; }
  if (t < DP){
    float g=bn2[t], be=bn2[DP+t], mn=bn2[2*DP+t], vr=bn2[3*DP+t];
    float s = g*rsqrtf(vr+EPS); bS[t]=s; bT[t]=be-mn*s;
  }
  for (int i=t; i<128*(DM/4); i+=256){
    const int j=i>>5, c4=(i&31)*4;
    const ushort4 u = *reinterpret_cast<const ushort4*>(&resbf[((size_t)(b*NN)+n0+j)*DM + c4]);
    rt[j][c4+0] = bf2f(u.x); rt[j][c4+1] = bf2f(u.y);
    rt[j][c4+2] = bf2f(u.z); rt[j][c4+3] = bf2f(u.w);
  }
  __syncthreads();
  const int j = t>>1, cq = t&1;
  float acc[32];
  #pragma unroll
  for (int i=0;i<32;i++) acc[i]=0.f;
  for (int c=0;c<DM;c+=4){
    const float4 rv = *reinterpret_cast<const float4*>(&rt[j][c]);
    #pragma unroll
    for (int i=0;i<32;i++){
      const float4 wv = *reinterpret_cast<const float4*>(&W2s[cq+2*i][c]);
      acc[i] += wv.x*rv.x + wv.y*rv.y + wv.z*rv.z + wv.w*rv.w;
    }
  }
  #pragma unroll
  for (int i=0;i<32;i++) ob[cq+2*i][j] = acc[i];
  __syncthreads();
  for (int i=t; i<DP*128; i+=256){
    const int ch=i>>7, jj=i&127;
    const size_t o = (size_t)b*DP*NN + (size_t)ch*NN + n0 + jj;
    out[o] = lrelu(ob[ch][jj]*bS[ch] + bT[ch]) + feats[o];
  }
}

// ----------------------------------------------------------------
extern "C" void kernel_launch(void* const* d_in, const int* in_sizes, int n_in,
                              void* d_out, int out_size, void* d_ws, size_t ws_size,
                              hipStream_t stream) {
  const float* feats = (const float*)d_in[0];
  const float* pos   = (const float*)d_in[1];
  const float* W1    = (const float*)d_in[2];
  const float* bn1   = (const float*)d_in[3];
  const float* W2    = (const float*)d_in[4];
  const float* bn2   = (const float*)d_in[5];
  const float* Wq    = (const float*)d_in[6];
  const float* Wk    = (const float*)d_in[7];
  const float* Wv    = (const float*)d_in[8];
  const float* Wd1   = (const float*)d_in[9];
  const float* bnd1  = (const float*)d_in[10];
  const float* Wd2   = (const float*)d_in[11];
  const float* bnd2  = (const float*)d_in[12];
  const float* Wg1   = (const float*)d_in[13];
  const float* bng1  = (const float*)d_in[14];
  const float* Wg2   = (const float*)d_in[15];
  const float* bng2  = (const float*)d_in[16];
  float* out = (float*)d_out;

  unsigned short* qbf = (unsigned short*)d_ws;              // 4 MiB
  unsigned short* kbf = qbf + 2097152;                      // 4 MiB
  unsigned short* vbf = kbf + 2097152;                      // 4 MiB
  float* sqn = (float*)(vbf + 2097152);                     // 64 KiB
  int*   idx = (int*)(sqn + 16384);                         // 1 MiB
  unsigned short* wfrag = (unsigned short*)(idx + 262144);  // 104 KiB
  unsigned short* poolu = wfrag + 53248;                    // 20 MiB pool
  // knn phase overlays
  float* fpm = (float*)poolu;                               // 4 MiB
  unsigned short* cfrag = (unsigned short*)(fpm + 1048576); // 4 MiB
  unsigned short* qfrag = cfrag + 2097152;                  // 4 MiB
  int* cand = (int*)(qfrag + 2097152);                      // 4 MiB (64/query)
  // attn phase overlays
  unsigned short* resbf = poolu;                            // 4 MiB
  unsigned short* imgA  = poolu + 2097152;                  // 8 MiB
  uint32_t* imgV = (uint32_t*)(imgA + 4194304);             // 8 MiB

  k_sqnorm<<<(NB*NN)/256, 256, 0, stream>>>(feats, sqn);
  k_fprep <<<NB*(NN/64), 256, 0, stream>>>(feats, cfrag, qfrag, fpm);
  k_knn4  <<<NB*256, 256, 0, stream>>>(cfrag, qfrag, sqn, cand);
  k_refine<<<(NB*NN)/4, 256, 0, stream>>>(fpm, sqn, cand, idx);
  k_wprep <<<26, 256, 0, stream>>>(Wd1, bnd1, Wd2, bnd2, Wg1, bng1, Wg2, bng2, wfrag);
  k_xqkv  <<<NB*(NN/64), 256, 0, stream>>>(feats, W1, bn1, Wq, Wk, Wv, qbf, kbf, vbf);

  for (int c = 0; c < NCHUNK; ++c){
    const int g0 = c * CHPTS;
    k_pe5  <<<CHPTS/4, 256, 0, stream>>>(pos, qbf, kbf, vbf, idx, wfrag,
                                         bnd1, bnd2, bng1, bng2, imgA, imgV, g0);
    k_attn5<<<CHPTS/4, 256, 0, stream>>>(imgA, imgV, wfrag, bng1, bng2, resbf, g0);
  }

  k_out   <<<NB*(NN/128), 256, 0, stream>>>(resbf, W2, bn2, feats, out);
}

// Round 13
// 571.910 us; speedup vs baseline: 4.5555x; 1.2303x over previous
//
#include <hip/hip_runtime.h>
#include <cstdint>
#include <cstddef>

#define NB 4
#define NN 4096
#define KK 16
#define DP 64
#define DM 128
#define EPS 1e-5f
#define NCHUNK 8
#define CHPTS (NN*NB/NCHUNK)   // 2048 points per chunk

typedef __attribute__((ext_vector_type(8))) short bf16x8;
typedef __attribute__((ext_vector_type(4))) float f32x4;
typedef __attribute__((ext_vector_type(4))) unsigned int u32x4;

__device__ __forceinline__ float lrelu(float x){ return x >= 0.f ? x : 0.2f*x; }

__device__ __forceinline__ unsigned short f2bf(float x){
  union { float f; uint32_t u; } a; a.f = x;
  return (unsigned short)((a.u + 0x7fffu + ((a.u >> 16) & 1u)) >> 16);
}
__device__ __forceinline__ float bf2f(unsigned short h){
  union { uint32_t u; float f; } a; a.u = ((uint32_t)h) << 16; return a.f;
}
__device__ __forceinline__ uint32_t pk2(float a, float b){
  return (uint32_t)f2bf(a) | ((uint32_t)f2bf(b) << 16);
}
__device__ __forceinline__ float bfl(uint32_t w){ return __uint_as_float(w << 16); }
__device__ __forceinline__ float bfh(uint32_t w){ return __uint_as_float(w & 0xffff0000u); }

__device__ __forceinline__ f32x4 mfma16(bf16x8 a, bf16x8 b, f32x4 c){
  return __builtin_amdgcn_mfma_f32_16x16x32_bf16(a, b, c, 0, 0, 0);
}
__device__ __forceinline__ float sx16(float v, int m){ return __shfl_xor(v, m, 16); }
__device__ __forceinline__ f32x4 vmax4(f32x4 a, f32x4 b){
  f32x4 r; r[0]=fmaxf(a[0],b[0]); r[1]=fmaxf(a[1],b[1]); r[2]=fmaxf(a[2],b[2]); r[3]=fmaxf(a[3],b[3]); return r;
}
__device__ __forceinline__ u32x4 sub8(u32x4 a, u32x4 k){
  u32x4 r;
  r[0] = pk2(bfl(a[0])-bfl(k[0]), bfh(a[0])-bfh(k[0]));
  r[1] = pk2(bfl(a[1])-bfl(k[1]), bfh(a[1])-bfh(k[1]));
  r[2] = pk2(bfl(a[2])-bfl(k[2]), bfh(a[2])-bfh(k[2]));
  r[3] = pk2(bfl(a[3])-bfl(k[3]), bfh(a[3])-bfh(k[3]));
  return r;
}

// ---------------------------------------------------------------- sq norms
__global__ __launch_bounds__(256) void k_sqnorm(const float* __restrict__ feats,
                                                float* __restrict__ sqn){
  const int i = blockIdx.x*256 + threadIdx.x;
  const int b = i >> 12, n = i & (NN-1);
  const float* f = feats + (size_t)b*DP*NN + n;
  float s = 0.f;
  #pragma unroll
  for (int c=0;c<DP;c++){ const float v = f[(size_t)c*NN]; s += v*v; }
  sqn[i] = s;
}

// ---------------------------------------------------------------- feats -> bf16 hi/lo MFMA fragments + point-major f32 copy
__global__ __launch_bounds__(256) void k_fprep(const float* __restrict__ feats,
                                               unsigned short* __restrict__ cfrag,
                                               unsigned short* __restrict__ qfrag,
                                               float* __restrict__ fpm){
  __shared__ float ft[DP][65];
  const int t = threadIdx.x;
  const int b = blockIdx.x >> 6;
  const int n0 = (blockIdx.x & 63) * 64;
  for (int i=t; i<DP*64; i+=256){
    const int dim = i >> 6, pt = i & 63;
    ft[dim][pt] = feats[(size_t)b*DP*NN + (size_t)dim*NN + n0 + pt];
  }
  __syncthreads();
  for (int i=t; i<64*DP; i+=256){
    const int pt = i >> 6, dim = i & 63;
    fpm[((size_t)(b*NN) + n0 + pt)*DP + dim] = ft[dim][pt];
  }
  #pragma unroll
  for (int v = t; v < 1024; v += 256){
    const int l = v & 63, hl = (v>>6)&1, ks = (v>>7)&1, ntl = v>>8;
    const int ptl = ntl*16 + (l&15);
    const int d0 = ks*32 + (l>>4)*8;
    unsigned short qo[8], co[8];
    #pragma unroll
    for (int j=0;j<8;j++){
      const float x = ft[d0+j][ptl];
      const unsigned short qh = f2bf(x);
      const float y = -2.f*x;
      const unsigned short ch = f2bf(y);
      qo[j] = hl ? f2bf(x - bf2f(qh)) : qh;
      co[j] = hl ? f2bf(y - bf2f(ch)) : ch;
    }
    const int nt = (n0 >> 4) + ntl;
    const size_t off = ((size_t)((b*256 + nt)*4 + ks*2 + hl))*512 + l*8;
    uint4 qv, cv;
    qv.x = (uint32_t)qo[0] | ((uint32_t)qo[1]<<16);
    qv.y = (uint32_t)qo[2] | ((uint32_t)qo[3]<<16);
    qv.z = (uint32_t)qo[4] | ((uint32_t)qo[5]<<16);
    qv.w = (uint32_t)qo[6] | ((uint32_t)qo[7]<<16);
    cv.x = (uint32_t)co[0] | ((uint32_t)co[1]<<16);
    cv.y = (uint32_t)co[2] | ((uint32_t)co[3]<<16);
    cv.z = (uint32_t)co[4] | ((uint32_t)co[5]<<16);
    cv.w = (uint32_t)co[6] | ((uint32_t)co[7]<<16);
    *reinterpret_cast<uint4*>(qfrag + off) = qv;
    *reinterpret_cast<uint4*>(cfrag + off) = cv;
  }
}

// ---------------------------------------------------------------- MFMA kNN v5: (query-tile, eighth) per wave
// 8 waves/SIMD; sorted-list insert (branch-free bubble); exact top-16 per eighth -> 128 cands/query.
__global__ __launch_bounds__(256, 4) void k_knn5(const unsigned short* __restrict__ cfrag,
                                                 const unsigned short* __restrict__ qfrag,
                                                 const float* __restrict__ sqn,
                                                 int* __restrict__ cand){
  const int t = threadIdx.x, w = t >> 6, l = t & 63, g = l >> 4;
  const int b = blockIdx.x >> 9;
  const int combo = (blockIdx.x & 511)*4 + w;   // 2048 combos per batch
  const int qt = combo >> 3, eighth = combo & 7;
  const int ct0 = eighth * 32;

  bf16x8 qf00, qf01, qf10, qf11;
  {
    const unsigned short* qb = qfrag + ((size_t)(b*256 + qt))*2048 + l*8;
    qf00 = *reinterpret_cast<const bf16x8*>(qb);
    qf01 = *reinterpret_cast<const bf16x8*>(qb + 512);
    qf10 = *reinterpret_cast<const bf16x8*>(qb + 1024);
    qf11 = *reinterpret_cast<const bf16x8*>(qb + 1536);
  }
  const unsigned short* cb = cfrag + ((size_t)(b*256))*2048 + l*8;
  const float sqq = sqn[b*NN + qt*16 + (l & 15)];

  // sorted ascending; kk[15] = current max
  uint32_t kk[16];
  #pragma unroll
  for (int s=0;s<16;s++) kk[s] = 0xFFFFFFFFu;

  bf16x8 c00 = *reinterpret_cast<const bf16x8*>(cb + (size_t)ct0*2048);
  bf16x8 c01 = *reinterpret_cast<const bf16x8*>(cb + (size_t)ct0*2048 + 512);
  bf16x8 c10 = *reinterpret_cast<const bf16x8*>(cb + (size_t)ct0*2048 + 1024);
  bf16x8 c11 = *reinterpret_cast<const bf16x8*>(cb + (size_t)ct0*2048 + 1536);

  const float* sqb = sqn + b*NN + g*4;

  #pragma unroll 1
  for (int it=0; it<32; ++it){
    const int ct = ct0 + it;
    bf16x8 n00, n01, n10, n11;
    if (it < 31){
      const unsigned short* nb_ = cb + (size_t)(ct+1)*2048;
      n00 = *reinterpret_cast<const bf16x8*>(nb_);
      n01 = *reinterpret_cast<const bf16x8*>(nb_ + 512);
      n10 = *reinterpret_cast<const bf16x8*>(nb_ + 1024);
      n11 = *reinterpret_cast<const bf16x8*>(nb_ + 1536);
    }
    f32x4 acc = {0.f,0.f,0.f,0.f};
    acc = mfma16(c00, qf00, acc);
    acc = mfma16(c10, qf10, acc);
    acc = mfma16(c00, qf01, acc);
    acc = mfma16(c01, qf00, acc);
    acc = mfma16(c10, qf11, acc);
    acc = mfma16(c11, qf10, acc);
    const float4 sq4 = *reinterpret_cast<const float4*>(&sqb[ct*16]);
    const int cbase = ct*16 + g*4;
    uint32_t pv[4];
    pv[0] = (__float_as_uint(fmaxf(acc[0]+sq4.x+sqq, 0.f)) & 0xFFFFF000u) | (cbase+0);
    pv[1] = (__float_as_uint(fmaxf(acc[1]+sq4.y+sqq, 0.f)) & 0xFFFFF000u) | (cbase+1);
    pv[2] = (__float_as_uint(fmaxf(acc[2]+sq4.z+sqq, 0.f)) & 0xFFFFF000u) | (cbase+2);
    pv[3] = (__float_as_uint(fmaxf(acc[3]+sq4.w+sqq, 0.f)) & 0xFFFFF000u) | (cbase+3);
    const uint32_t mn = min(min(pv[0],pv[1]), min(pv[2],pv[3]));
    if (mn < kk[15]){
      #pragma unroll
      for (int u=0;u<4;u++){
        uint32_t v = pv[u];
        if (v < kk[15]){
          // branch-free sorted bubble insert (drops old max)
          #pragma unroll
          for (int s=0;s<16;s++){
            const uint32_t hi = max(kk[s], v);
            kk[s] = min(kk[s], v);
            v = hi;
          }
        }
      }
    }
    c00 = n00; c01 = n01; c10 = n10; c11 = n11;
  }

  // merge across the 4 g-lanes per query: lists sorted -> head-compare + shift
  const int q = qt*16 + (l & 15);
  int* op = cand + ((size_t)(b*NN) + q)*128 + eighth*16;
  #pragma unroll 1
  for (int r=0; r<KK; ++r){
    uint32_t bm = kk[0];
    uint32_t om;
    om = __shfl_xor((int)bm, 16); bm = min(bm, om);
    om = __shfl_xor((int)bm, 32); bm = min(bm, om);
    if (kk[0] == bm){
      #pragma unroll
      for (int s=0;s<15;s++) kk[s] = kk[s+1];
      kk[15] = 0xFFFFFFFFu;
    }
    if (g == 0) op[r] = (int)(bm & 0xFFFu);
  }
}

// ---------------------------------------------------------------- exact f32 refine: wave per query, 2 candidates per lane (128)
__global__ __launch_bounds__(256) void k_refine(const float* __restrict__ fpm,
                                                const float* __restrict__ sqn,
                                                const int* __restrict__ cand,
                                                int* __restrict__ idx_ws){
  const int t = threadIdx.x, w = t >> 6, l = t & 63;
  const int q = blockIdx.x*4 + w;           // global point id
  const int b = q >> 12;
  const int mi0 = cand[(size_t)q*128 + l];
  const int mi1 = cand[(size_t)q*128 + 64 + l];
  const float* qv = fpm + (size_t)q*DP;
  const float* cv0 = fpm + ((size_t)(b*NN) + mi0)*DP;
  const float* cv1 = fpm + ((size_t)(b*NN) + mi1)*DP;
  float dot0 = 0.f, dot1 = 0.f;
  #pragma unroll
  for (int d=0; d<DP; d+=4){
    const float4 a  = *reinterpret_cast<const float4*>(&qv[d]);
    const float4 x0 = *reinterpret_cast<const float4*>(&cv0[d]);
    const float4 x1 = *reinterpret_cast<const float4*>(&cv1[d]);
    dot0 += a.x*x0.x + a.y*x0.y + a.z*x0.z + a.w*x0.w;
    dot1 += a.x*x1.x + a.y*x1.y + a.z*x1.z + a.w*x1.w;
  }
  const float dist0 = sqn[b*NN + mi0] - 2.f*dot0;   // sqn[q] dropped (rank-invariant)
  const float dist1 = sqn[b*NN + mi1] - 2.f*dot1;
  int rank0 = 0, rank1 = 0;
  #pragma unroll 4
  for (int j=0; j<64; j++){
    const float dj0 = __shfl(dist0, j);
    const int   ij0 = __shfl(mi0,  j);
    const float dj1 = __shfl(dist1, j);
    const int   ij1 = __shfl(mi1,  j);
    rank0 += (dj0 < dist0 || (dj0 == dist0 && ij0 < mi0)) ? 1 : 0;
    rank0 += (dj1 < dist0 || (dj1 == dist0 && ij1 < mi0)) ? 1 : 0;
    rank1 += (dj0 < dist1 || (dj0 == dist1 && ij0 < mi1)) ? 1 : 0;
    rank1 += (dj1 < dist1 || (dj1 == dist1 && ij1 < mi1)) ? 1 : 0;
  }
  if (rank0 < KK) idx_ws[(size_t)q*KK + rank0] = mi0;
  if (rank1 < KK) idx_ws[(size_t)q*KK + rank1] = mi1;
}

// ---------------------------------------------------------------- x -> q,k,v (bf16 point-major), fully fused
__global__ __launch_bounds__(256, 1) void k_xqkv(const float* __restrict__ feats,
                                              const float* __restrict__ W1,
                                              const float* __restrict__ bn1,
                                              const float* __restrict__ Wq,
                                              const float* __restrict__ Wk,
                                              const float* __restrict__ Wv,
                                              unsigned short* __restrict__ qbf,
                                              unsigned short* __restrict__ kbf,
                                              unsigned short* __restrict__ vbf){
  __shared__ float W1s[DM][DP+1];
  __shared__ float ft[DP][64];
  __shared__ float xt[64][DM+4];
  __shared__ float Ws[DM][DM+4];
  __shared__ float bS[DM], bT[DM];
  const int t = threadIdx.x;
  const int b = blockIdx.x >> 6;
  const int n0 = (blockIdx.x & 63) * 64;
  for (int i=t; i<DM*DP; i+=256){ W1s[i>>6][i&63] = W1[i]; }
  if (t < DM){
    float g = bn1[t], be = bn1[DM+t], mn = bn1[2*DM+t], vr = bn1[3*DM+t];
    float s = g*rsqrtf(vr+EPS); bS[t]=s; bT[t]=be-mn*s;
  }
  for (int i=t; i<DP*64; i+=256){
    const int c = i>>6, j = i&63;
    ft[c][j] = feats[(size_t)b*DP*NN + (size_t)c*NN + n0 + j];
  }
  __syncthreads();
  const int j = t >> 2, cq = t & 3;
  {
    float acc[32];
    #pragma unroll
    for (int i=0;i<32;i++) acc[i]=0.f;
    for (int c=0;c<DP;c++){
      const float fv = ft[c][j];
      #pragma unroll
      for (int i=0;i<32;i++) acc[i] += W1s[cq+4*i][c]*fv;
    }
    #pragma unroll
    for (int i=0;i<32;i++){
      const int ch = cq + 4*i;
      xt[j][ch] = lrelu(acc[i]*bS[ch] + bT[ch]);
    }
  }
  const float* Wp[3] = {Wq, Wk, Wv};
  unsigned short* Op[3] = {qbf, kbf, vbf};
  for (int wi=0; wi<3; wi++){
    __syncthreads();
    for (int i=t; i<DM*DM; i+=256){ Ws[i>>7][i&127] = Wp[wi][i]; }
    __syncthreads();
    float acc[32];
    #pragma unroll
    for (int i=0;i<32;i++) acc[i]=0.f;
    for (int c=0;c<DM;c+=4){
      const float4 xv = *reinterpret_cast<const float4*>(&xt[j][c]);
      #pragma unroll
      for (int i=0;i<32;i++){
        const float4 wv = *reinterpret_cast<const float4*>(&Ws[cq+4*i][c]);
        acc[i] += wv.x*xv.x + wv.y*xv.y + wv.z*xv.z + wv.w*xv.w;
      }
    }
    unsigned short* op = Op[wi] + ((size_t)(b*NN) + n0 + j)*DM;
    #pragma unroll
    for (int i=0;i<32;i++) op[cq+4*i] = f2bf(acc[i]);
  }
}

// ---------------------------------------------------------------- weight prep: 104 bf16 MFMA fragments, bn-scale folded
__global__ __launch_bounds__(256) void k_wprep(
    const float* __restrict__ Wd1, const float* __restrict__ bnd1,
    const float* __restrict__ Wd2, const float* __restrict__ bnd2,
    const float* __restrict__ Wg1, const float* __restrict__ bng1,
    const float* __restrict__ Wg2, const float* __restrict__ bng2,
    unsigned short* __restrict__ wfrag){
  const int i = blockIdx.x*256 + threadIdx.x;
  if (i >= 104*64) return;
  const int f = i >> 6, l = i & 63;
  const int r16 = l & 15, kg = (l >> 4) * 8;
  unsigned short o8[8];
  if (f < 96){
    const int mat = f >> 5, tt = (f >> 2) & 7, ks = f & 3;
    const float* W; const float* bn;
    if (mat == 0){ W = Wd2; bn = bnd2; }
    else if (mat == 1){ W = Wg1; bn = bng1; }
    else { W = Wg2; bn = bng2; }
    const int row = tt*16 + r16;
    const float s = bn[row] * rsqrtf(bn[3*DM+row] + EPS);
    const float* src = W + (size_t)row*DM + ks*32 + kg;
    #pragma unroll
    for (int j=0;j<8;j++) o8[j] = f2bf(s * src[j]);
  } else {
    const int tt = f - 96;
    const int row = tt*16 + r16;
    const float s = bnd1[row] * rsqrtf(bnd1[3*DM+row] + EPS);
    #pragma unroll
    for (int j=0;j<8;j++){
      const int k = kg + j;
      o8[j] = (k < 3) ? f2bf(s * Wd1[row*3 + k]) : (unsigned short)0;
    }
  }
  uint4 v;
  v.x = (uint32_t)o8[0] | ((uint32_t)o8[1]<<16);
  v.y = (uint32_t)o8[2] | ((uint32_t)o8[3]<<16);
  v.z = (uint32_t)o8[4] | ((uint32_t)o8[5]<<16);
  v.w = (uint32_t)o8[6] | ((uint32_t)o8[7]<<16);
  *reinterpret_cast<uint4*>(wfrag + (size_t)i*8) = v;
}

// ---------------------------------------------------------------- staged attention
#define FRG(fi) (*reinterpret_cast<const bf16x8*>(&wfrag[(size_t)(fi)*512 + l*8]))

#define RD_B() \
  const bf16x8 b0 = *reinterpret_cast<const bf16x8*>(&hb[p*128 + ((0*4+g)^p)*8]); \
  const bf16x8 b1 = *reinterpret_cast<const bf16x8*>(&hb[p*128 + ((1*4+g)^p)*8]); \
  const bf16x8 b2 = *reinterpret_cast<const bf16x8*>(&hb[p*128 + ((2*4+g)^p)*8]); \
  const bf16x8 b3 = *reinterpret_cast<const bf16x8*>(&hb[p*128 + ((3*4+g)^p)*8]);

#define H1_STEP(tt) { \
  f32x4 acc = {0.f,0.f,0.f,0.f}; \
  acc = mfma16(FRG(96+(tt)), bv, acc); \
  const f32x4 sh = *reinterpret_cast<const f32x4*>(&bnT[0][(tt)*16 + g*4]); \
  uint2 hp; \
  hp.x = pk2(lrelu(acc[0]+sh[0]), lrelu(acc[1]+sh[1])); \
  hp.y = pk2(lrelu(acc[2]+sh[2]), lrelu(acc[3]+sh[3])); \
  *reinterpret_cast<uint2*>(&hb[hwb + (((tt)*2 + (g>>1))^p)*8]) = hp; }

#define PE_STEP(tt, PE) { \
  f32x4 acc = {0.f,0.f,0.f,0.f}; \
  acc = mfma16(FRG(0+(tt)*4+0), b0, acc); \
  acc = mfma16(FRG(0+(tt)*4+1), b1, acc); \
  acc = mfma16(FRG(0+(tt)*4+2), b2, acc); \
  acc = mfma16(FRG(0+(tt)*4+3), b3, acc); \
  const f32x4 sh = *reinterpret_cast<const f32x4*>(&bnT[1][(tt)*16 + g*4]); \
  PE[0]=lrelu(acc[0]+sh[0]); PE[1]=lrelu(acc[1]+sh[1]); \
  PE[2]=lrelu(acc[2]+sh[2]); PE[3]=lrelu(acc[3]+sh[3]); }

#define VPE_STEP(tt, PE) { \
  const uint2 du = *reinterpret_cast<const uint2*>(&hb[p*128 + (((tt)*2+(g>>1))^p)*8 + (g&1)*4]); \
  uint2 st; \
  st.x = pk2(bfl(du.x)+PE[0], bfh(du.x)+PE[1]); \
  st.y = pk2(bfl(du.y)+PE[2], bfh(du.y)+PE[3]); \
  *reinterpret_cast<uint2*>(&imgV[(size_t)Gc*1024 + l*16 + (tt)*2]) = st; }

#define QPE_STEP(tt, PE) { \
  const uint2 qu = *reinterpret_cast<const uint2*>(&qbf[(size_t)gp*DM + (tt)*16 + g*4]); \
  uint2 hp; \
  hp.x = pk2(bfl(qu.x)+PE[0], bfh(qu.x)+PE[1]); \
  hp.y = pk2(bfl(qu.y)+PE[2], bfh(qu.y)+PE[3]); \
  *reinterpret_cast<uint2*>(&hb[hwb + (((tt)*2 + (g>>1))^p)*8]) = hp; }

__global__ __launch_bounds__(256, 2) void k_pe5(
    const float* __restrict__ pos, const unsigned short* __restrict__ qbf,
    const unsigned short* __restrict__ kbf, const unsigned short* __restrict__ vbf,
    const int* __restrict__ idx_ws, const unsigned short* __restrict__ wfrag,
    const float* __restrict__ bnd1, const float* __restrict__ bnd2,
    const float* __restrict__ bng1, const float* __restrict__ bng2,
    unsigned short* __restrict__ imgA, uint32_t* __restrict__ imgV, int g0){
  __shared__ __align__(16) unsigned short Hb[4][2048];
  __shared__ float bnT[2][DM];

  const int t = threadIdx.x;
  if (t < DM){
    const float* bp[2] = {bnd1, bnd2};
    #pragma unroll
    for (int s4=0;s4<2;s4++){
      const float g = bp[s4][t], be = bp[s4][DM+t], mn = bp[s4][2*DM+t], vr = bp[s4][3*DM+t];
      const float sc = g * rsqrtf(vr + EPS);
      bnT[s4][t] = be - mn*sc;
    }
  }
  __syncthreads();

  const int w = t >> 6, l = t & 63;
  const int p = l & 15, g = l >> 4;
  unsigned short* hb = Hb[w];
  const int hwb = p*128 + ((g & 1) * 4);

  const int Gc = blockIdx.x*4 + w;
  const int gp = g0 + Gc;
  const int b = gp >> 12, n = gp & (NN-1);
  const int mi = idx_ws[gp*KK + p];

  uint32_t bw0 = 0u, bw1 = 0u;
  if (g == 0){
    const float* posb = pos + (size_t)b*3*NN;
    const float rx = posb[n]      - posb[mi];
    const float ry = posb[NN+n]   - posb[NN+mi];
    const float rz = posb[2*NN+n] - posb[2*NN+mi];
    bw0 = pk2(rx, ry);
    bw1 = pk2(rz, 0.f);
  }
  u32x4 bwv = {bw0, bw1, 0u, 0u};
  const bf16x8 bv = __builtin_bit_cast(bf16x8, bwv);

  H1_STEP(0) H1_STEP(1) H1_STEP(2) H1_STEP(3)
  H1_STEP(4) H1_STEP(5) H1_STEP(6) H1_STEP(7)

  f32x4 pe0, pe1, pe2, pe3, pe4, pe5, pe6, pe7;
  {
    RD_B()
    PE_STEP(0, pe0) PE_STEP(1, pe1) PE_STEP(2, pe2) PE_STEP(3, pe3)
    PE_STEP(4, pe4) PE_STEP(5, pe5) PE_STEP(6, pe6) PE_STEP(7, pe7)
  }

  {
    const unsigned short* vrow = vbf + ((size_t)(b*NN) + mi)*DM;
    const bf16x8 xv0 = *reinterpret_cast<const bf16x8*>(&vrow[ 0 + g*8]);
    const bf16x8 xv1 = *reinterpret_cast<const bf16x8*>(&vrow[32 + g*8]);
    const bf16x8 xv2 = *reinterpret_cast<const bf16x8*>(&vrow[64 + g*8]);
    const bf16x8 xv3 = *reinterpret_cast<const bf16x8*>(&vrow[96 + g*8]);
    *reinterpret_cast<bf16x8*>(&hb[p*128 + ((0*4+g)^p)*8]) = xv0;
    *reinterpret_cast<bf16x8*>(&hb[p*128 + ((1*4+g)^p)*8]) = xv1;
    *reinterpret_cast<bf16x8*>(&hb[p*128 + ((2*4+g)^p)*8]) = xv2;
    *reinterpret_cast<bf16x8*>(&hb[p*128 + ((3*4+g)^p)*8]) = xv3;
    VPE_STEP(0, pe0) VPE_STEP(1, pe1) VPE_STEP(2, pe2) VPE_STEP(3, pe3)
    VPE_STEP(4, pe4) VPE_STEP(5, pe5) VPE_STEP(6, pe6) VPE_STEP(7, pe7)
  }

  QPE_STEP(0, pe0) QPE_STEP(1, pe1) QPE_STEP(2, pe2) QPE_STEP(3, pe3)
  QPE_STEP(4, pe4) QPE_STEP(5, pe5) QPE_STEP(6, pe6) QPE_STEP(7, pe7)
  {
    const unsigned short* krow = kbf + ((size_t)(b*NN) + mi)*DM;
    const bf16x8 xk0 = *reinterpret_cast<const bf16x8*>(&krow[ 0 + g*8]);
    const bf16x8 xk1 = *reinterpret_cast<const bf16x8*>(&krow[32 + g*8]);
    const bf16x8 xk2 = *reinterpret_cast<const bf16x8*>(&krow[64 + g*8]);
    const bf16x8 xk3 = *reinterpret_cast<const bf16x8*>(&krow[96 + g*8]);
    RD_B()
    const u32x4 f0 = sub8(__builtin_bit_cast(u32x4, b0), __builtin_bit_cast(u32x4, xk0));
    const u32x4 f1 = sub8(__builtin_bit_cast(u32x4, b1), __builtin_bit_cast(u32x4, xk1));
    const u32x4 f2 = sub8(__builtin_bit_cast(u32x4, b2), __builtin_bit_cast(u32x4, xk2));
    const u32x4 f3 = sub8(__builtin_bit_cast(u32x4, b3), __builtin_bit_cast(u32x4, xk3));
    *reinterpret_cast<u32x4*>(&imgA[(size_t)Gc*2048 + 0*512 + l*8]) = f0;
    *reinterpret_cast<u32x4*>(&imgA[(size_t)Gc*2048 + 1*512 + l*8]) = f1;
    *reinterpret_cast<u32x4*>(&imgA[(size_t)Gc*2048 + 2*512 + l*8]) = f2;
    *reinterpret_cast<u32x4*>(&imgA[(size_t)Gc*2048 + 3*512 + l*8]) = f3;
  }
}

#define G1_STEP(tt) { \
  f32x4 acc = {0.f,0.f,0.f,0.f}; \
  acc = mfma16(FRG(32+(tt)*4+0), b0, acc); \
  acc = mfma16(FRG(32+(tt)*4+1), b1, acc); \
  acc = mfma16(FRG(32+(tt)*4+2), b2, acc); \
  acc = mfma16(FRG(32+(tt)*4+3), b3, acc); \
  const f32x4 sh = *reinterpret_cast<const f32x4*>(&bnT[2][(tt)*16 + g*4]); \
  uint2 hp; \
  hp.x = pk2(lrelu(acc[0]+sh[0]), lrelu(acc[1]+sh[1])); \
  hp.y = pk2(lrelu(acc[2]+sh[2]), lrelu(acc[3]+sh[3])); \
  *reinterpret_cast<uint2*>(&hb[hwb + (((tt)*2 + (g>>1))^p)*8]) = hp; }

#define E_STEP(tt, E) { \
  f32x4 acc = {0.f,0.f,0.f,0.f}; \
  acc = mfma16(FRG(64+(tt)*4+0), b0, acc); \
  acc = mfma16(FRG(64+(tt)*4+1), b1, acc); \
  acc = mfma16(FRG(64+(tt)*4+2), b2, acc); \
  acc = mfma16(FRG(64+(tt)*4+3), b3, acc); \
  const f32x4 sh = *reinterpret_cast<const f32x4*>(&bnT[3][(tt)*16 + g*4]); \
  E[0]=lrelu(acc[0]+sh[0])*0.015625f; E[1]=lrelu(acc[1]+sh[1])*0.015625f; \
  E[2]=lrelu(acc[2]+sh[2])*0.015625f; E[3]=lrelu(acc[3]+sh[3])*0.015625f; }

#define EXP_STEP(E) { \
  E[0]=__expf(E[0]-m); E[1]=__expf(E[1]-m); E[2]=__expf(E[2]-m); E[3]=__expf(E[3]-m); }

#define RED5(tt, E) { \
  const uint2 vu = *reinterpret_cast<const uint2*>(&imgV[(size_t)Gc*1024 + l*16 + (tt)*2]); \
  float o0, o1, o2, o3; \
  { float num=E[0]*bfl(vu.x), den=E[0]; \
    num+=sx16(num,1); den+=sx16(den,1); num+=sx16(num,2); den+=sx16(den,2); \
    num+=sx16(num,4); den+=sx16(den,4); num+=sx16(num,8); den+=sx16(den,8); \
    o0 = num*__builtin_amdgcn_rcpf(den); } \
  { float num=E[1]*bfh(vu.x), den=E[1]; \
    num+=sx16(num,1); den+=sx16(den,1); num+=sx16(num,2); den+=sx16(den,2); \
    num+=sx16(num,4); den+=sx16(den,4); num+=sx16(num,8); den+=sx16(den,8); \
    o1 = num*__builtin_amdgcn_rcpf(den); } \
  { float num=E[2]*bfl(vu.y), den=E[2]; \
    num+=sx16(num,1); den+=sx16(den,1); num+=sx16(num,2); den+=sx16(den,2); \
    num+=sx16(num,4); den+=sx16(den,4); num+=sx16(num,8); den+=sx16(den,8); \
    o2 = num*__builtin_amdgcn_rcpf(den); } \
  { float num=E[3]*bfh(vu.y), den=E[3]; \
    num+=sx16(num,1); den+=sx16(den,1); num+=sx16(num,2); den+=sx16(den,2); \
    num+=sx16(num,4); den+=sx16(den,4); num+=sx16(num,8); den+=sx16(den,8); \
    o3 = num*__builtin_amdgcn_rcpf(den); } \
  if (p == 0){ \
    uint2 st; st.x = pk2(o0,o1); st.y = pk2(o2,o3); \
    *reinterpret_cast<uint2*>(&resbf[(size_t)gp*DM + (tt)*16 + g*4]) = st; } }

__global__ __launch_bounds__(256, 2) void k_attn5(
    const unsigned short* __restrict__ imgA, const uint32_t* __restrict__ imgV,
    const unsigned short* __restrict__ wfrag,
    const float* __restrict__ bng1, const float* __restrict__ bng2,
    unsigned short* __restrict__ resbf, int g0){
  __shared__ __align__(16) unsigned short Hb[4][2048];
  __shared__ float bnT[4][DM];   // rows 2,3 used

  const int t = threadIdx.x;
  if (t < DM){
    const float* bp[2] = {bng1, bng2};
    #pragma unroll
    for (int s4=0;s4<2;s4++){
      const float g = bp[s4][t], be = bp[s4][DM+t], mn = bp[s4][2*DM+t], vr = bp[s4][3*DM+t];
      const float sc = g * rsqrtf(vr + EPS);
      bnT[2+s4][t] = be - mn*sc;
    }
  }
  __syncthreads();

  const int w = t >> 6, l = t & 63;
  const int p = l & 15, g = l >> 4;
  unsigned short* hb = Hb[w];
  const int hwb = p*128 + ((g & 1) * 4);

  const int Gc = blockIdx.x*4 + w;
  const int gp = g0 + Gc;

  {
    const bf16x8 b0 = *reinterpret_cast<const bf16x8*>(&imgA[(size_t)Gc*2048 + 0*512 + l*8]);
    const bf16x8 b1 = *reinterpret_cast<const bf16x8*>(&imgA[(size_t)Gc*2048 + 1*512 + l*8]);
    const bf16x8 b2 = *reinterpret_cast<const bf16x8*>(&imgA[(size_t)Gc*2048 + 2*512 + l*8]);
    const bf16x8 b3 = *reinterpret_cast<const bf16x8*>(&imgA[(size_t)Gc*2048 + 3*512 + l*8]);
    G1_STEP(0) G1_STEP(1) G1_STEP(2) G1_STEP(3)
    G1_STEP(4) G1_STEP(5) G1_STEP(6) G1_STEP(7)
  }

  f32x4 e0, e1, e2, e3, e4, e5, e6, e7;
  {
    RD_B()
    E_STEP(0, e0) E_STEP(1, e1) E_STEP(2, e2) E_STEP(3, e3)
    E_STEP(4, e4) E_STEP(5, e5) E_STEP(6, e6) E_STEP(7, e7)
  }

  f32x4 mm = vmax4(vmax4(vmax4(e0,e1), vmax4(e2,e3)), vmax4(vmax4(e4,e5), vmax4(e6,e7)));
  float m = fmaxf(fmaxf(mm[0],mm[1]), fmaxf(mm[2],mm[3]));
  m = fmaxf(m, sx16(m,1)); m = fmaxf(m, sx16(m,2));
  m = fmaxf(m, sx16(m,4)); m = fmaxf(m, sx16(m,8));
  EXP_STEP(e0) EXP_STEP(e1) EXP_STEP(e2) EXP_STEP(e3)
  EXP_STEP(e4) EXP_STEP(e5) EXP_STEP(e6) EXP_STEP(e7)

  RED5(0, e0) RED5(1, e1) RED5(2, e2) RED5(3, e3)
  RED5(4, e4) RED5(5, e5) RED5(6, e6) RED5(7, e7)
}

// ---------------------------------------------------------------- out = lrelu(bn2(W2@res)) + feats  (res is bf16)
__global__ __launch_bounds__(256, 1) void k_out(const unsigned short* __restrict__ resbf,
                                             const float* __restrict__ W2,
                                             const float* __restrict__ bn2,
                                             const float* __restrict__ feats,
                                             float* __restrict__ out){
  __shared__ float W2s[DP][DM+4];
  __shared__ float rt[128][DM+4];
  __shared__ float ob[DP][132];
  __shared__ float bS[DP], bT[DP];
  const int t = threadIdx.x;
  const int b = blockIdx.x >> 5;
  const int n0 = (blockIdx.x & 31) * 128;
  for (int i=t; i<DP*DM; i+=256){ W2s[i>>7][i&127] = W2[i]; }
  if (t < DP){
    float g=bn2[t], be=bn2[DP+t], mn=bn2[2*DP+t], vr=bn2[3*DP+t];
    float s = g*rsqrtf(vr+EPS); bS[t]=s; bT[t]=be-mn*s;
  }
  for (int i=t; i<128*(DM/4); i+=256){
    const int j=i>>5, c4=(i&31)*4;
    const ushort4 u = *reinterpret_cast<const ushort4*>(&resbf[((size_t)(b*NN)+n0+j)*DM + c4]);
    rt[j][c4+0] = bf2f(u.x); rt[j][c4+1] = bf2f(u.y);
    rt[j][c4+2] = bf2f(u.z); rt[j][c4+3] = bf2f(u.w);
  }
  __syncthreads();
  const int j = t>>1, cq = t&1;
  float acc[32];
  #pragma unroll
  for (int i=0;i<32;i++) acc[i]=0.f;
  for (int c=0;c<DM;c+=4){
    const float4 rv = *reinterpret_cast<const float4*>(&rt[j][c]);
    #pragma unroll
    for (int i=0;i<32;i++){
      const float4 wv = *reinterpret_cast<const float4*>(&W2s[cq+2*i][c]);
      acc[i] += wv.x*rv.x + wv.y*rv.y + wv.z*rv.z + wv.w*rv.w;
    }
  }
  #pragma unroll
  for (int i=0;i<32;i++) ob[cq+2*i][j] = acc[i];
  __syncthreads();
  for (int i=t; i<DP*128; i+=256){
    const int ch=i>>7, jj=i&127;
    const size_t o = (size_t)b*DP*NN + (size_t)ch*NN + n0 + jj;
    out[o] = lrelu(ob[ch][jj]*bS[ch] + bT[ch]) + feats[o];
  }
}

// ----------------------------------------------------------------
extern "C" void kernel_launch(void* const* d_in, const int* in_sizes, int n_in,
                              void* d_out, int out_size, void* d_ws, size_t ws_size,
                              hipStream_t stream) {
  const float* feats = (const float*)d_in[0];
  const float* pos   = (const float*)d_in[1];
  const float* W1    = (const float*)d_in[2];
  const float* bn1   = (const float*)d_in[3];
  const float* W2    = (const float*)d_in[4];
  const float* bn2   = (const float*)d_in[5];
  const float* Wq    = (const float*)d_in[6];
  const float* Wk    = (const float*)d_in[7];
  const float* Wv    = (const float*)d_in[8];
  const float* Wd1   = (const float*)d_in[9];
  const float* bnd1  = (const float*)d_in[10];
  const float* Wd2   = (const float*)d_in[11];
  const float* bnd2  = (const float*)d_in[12];
  const float* Wg1   = (const float*)d_in[13];
  const float* bng1  = (const float*)d_in[14];
  const float* Wg2   = (const float*)d_in[15];
  const float* bng2  = (const float*)d_in[16];
  float* out = (float*)d_out;

  unsigned short* qbf = (unsigned short*)d_ws;              // 4 MiB
  unsigned short* kbf = qbf + 2097152;                      // 4 MiB
  unsigned short* vbf = kbf + 2097152;                      // 4 MiB
  float* sqn = (float*)(vbf + 2097152);                     // 64 KiB
  int*   idx = (int*)(sqn + 16384);                         // 1 MiB
  unsigned short* wfrag = (unsigned short*)(idx + 262144);  // 104 KiB
  unsigned short* poolu = wfrag + 53248;                    // 20 MiB pool
  // knn phase overlays
  float* fpm = (float*)poolu;                               // 4 MiB
  unsigned short* cfrag = (unsigned short*)(fpm + 1048576); // 4 MiB
  unsigned short* qfrag = cfrag + 2097152;                  // 4 MiB
  int* cand = (int*)(qfrag + 2097152);                      // 8 MiB (128/query)
  // attn phase overlays
  unsigned short* resbf = poolu;                            // 4 MiB
  unsigned short* imgA  = poolu + 2097152;                  // 8 MiB (over cfrag+qfrag)
  uint32_t* imgV = (uint32_t*)(imgA + 4194304);             // 8 MiB (over cand)

  k_sqnorm<<<(NB*NN)/256, 256, 0, stream>>>(feats, sqn);
  k_fprep <<<NB*(NN/64), 256, 0, stream>>>(feats, cfrag, qfrag, fpm);
  k_knn5  <<<NB*512, 256, 0, stream>>>(cfrag, qfrag, sqn, cand);
  k_refine<<<(NB*NN)/4, 256, 0, stream>>>(fpm, sqn, cand, idx);
  k_wprep <<<26, 256, 0, stream>>>(Wd1, bnd1, Wd2, bnd2, Wg1, bng1, Wg2, bng2, wfrag);
  k_xqkv  <<<NB*(NN/64), 256, 0, stream>>>(feats, W1, bn1, Wq, Wk, Wv, qbf, kbf, vbf);

  for (int c = 0; c < NCHUNK; ++c){
    const int g0 = c * CHPTS;
    k_pe5  <<<CHPTS/4, 256, 0, stream>>>(pos, qbf, kbf, vbf, idx, wfrag,
                                         bnd1, bnd2, bng1, bng2, imgA, imgV, g0);
    k_attn5<<<CHPTS/4, 256, 0, stream>>>(imgA, imgV, wfrag, bng1, bng2, resbf, g0);
  }

  k_out   <<<NB*(NN/128), 256, 0, stream>>>(resbf, W2, bn2, feats, out);
}

// Round 14
// 466.727 us; speedup vs baseline: 5.5822x; 1.2254x over previous
//
#include <hip/hip_runtime.h>
#include <cstdint>
#include <cstddef>

#define NB 4
#define NN 4096
#define KK 16
#define DP 64
#define DM 128
#define EPS 1e-5f
#define NCHUNK 8
#define CHPTS (NN*NB/NCHUNK)   // 2048 points per chunk

typedef __attribute__((ext_vector_type(8))) short bf16x8;
typedef __attribute__((ext_vector_type(4))) float f32x4;
typedef __attribute__((ext_vector_type(4))) unsigned int u32x4;

__device__ __forceinline__ float lrelu(float x){ return x >= 0.f ? x : 0.2f*x; }

__device__ __forceinline__ unsigned short f2bf(float x){
  union { float f; uint32_t u; } a; a.f = x;
  return (unsigned short)((a.u + 0x7fffu + ((a.u >> 16) & 1u)) >> 16);
}
__device__ __forceinline__ float bf2f(unsigned short h){
  union { uint32_t u; float f; } a; a.u = ((uint32_t)h) << 16; return a.f;
}
__device__ __forceinline__ uint32_t pk2(float a, float b){
  return (uint32_t)f2bf(a) | ((uint32_t)f2bf(b) << 16);
}
__device__ __forceinline__ float bfl(uint32_t w){ return __uint_as_float(w << 16); }
__device__ __forceinline__ float bfh(uint32_t w){ return __uint_as_float(w & 0xffff0000u); }

__device__ __forceinline__ f32x4 mfma16(bf16x8 a, bf16x8 b, f32x4 c){
  return __builtin_amdgcn_mfma_f32_16x16x32_bf16(a, b, c, 0, 0, 0);
}
__device__ __forceinline__ float sx16(float v, int m){ return __shfl_xor(v, m, 16); }
__device__ __forceinline__ f32x4 vmax4(f32x4 a, f32x4 b){
  f32x4 r; r[0]=fmaxf(a[0],b[0]); r[1]=fmaxf(a[1],b[1]); r[2]=fmaxf(a[2],b[2]); r[3]=fmaxf(a[3],b[3]); return r;
}
__device__ __forceinline__ u32x4 sub8(u32x4 a, u32x4 k){
  u32x4 r;
  r[0] = pk2(bfl(a[0])-bfl(k[0]), bfh(a[0])-bfh(k[0]));
  r[1] = pk2(bfl(a[1])-bfl(k[1]), bfh(a[1])-bfh(k[1]));
  r[2] = pk2(bfl(a[2])-bfl(k[2]), bfh(a[2])-bfh(k[2]));
  r[3] = pk2(bfl(a[3])-bfl(k[3]), bfh(a[3])-bfh(k[3]));
  return r;
}

// ---------------------------------------------------------------- sq norms
__global__ __launch_bounds__(256) void k_sqnorm(const float* __restrict__ feats,
                                                float* __restrict__ sqn){
  const int i = blockIdx.x*256 + threadIdx.x;
  const int b = i >> 12, n = i & (NN-1);
  const float* f = feats + (size_t)b*DP*NN + n;
  float s = 0.f;
  #pragma unroll
  for (int c=0;c<DP;c++){ const float v = f[(size_t)c*NN]; s += v*v; }
  sqn[i] = s;
}

// ---------------------------------------------------------------- feats -> bf16 hi/lo MFMA fragments + point-major f32 copy
__global__ __launch_bounds__(256) void k_fprep(const float* __restrict__ feats,
                                               unsigned short* __restrict__ cfrag,
                                               unsigned short* __restrict__ qfrag,
                                               float* __restrict__ fpm){
  __shared__ float ft[DP][65];
  const int t = threadIdx.x;
  const int b = blockIdx.x >> 6;
  const int n0 = (blockIdx.x & 63) * 64;
  for (int i=t; i<DP*64; i+=256){
    const int dim = i >> 6, pt = i & 63;
    ft[dim][pt] = feats[(size_t)b*DP*NN + (size_t)dim*NN + n0 + pt];
  }
  __syncthreads();
  for (int i=t; i<64*DP; i+=256){
    const int pt = i >> 6, dim = i & 63;
    fpm[((size_t)(b*NN) + n0 + pt)*DP + dim] = ft[dim][pt];
  }
  #pragma unroll
  for (int v = t; v < 1024; v += 256){
    const int l = v & 63, hl = (v>>6)&1, ks = (v>>7)&1, ntl = v>>8;
    const int ptl = ntl*16 + (l&15);
    const int d0 = ks*32 + (l>>4)*8;
    unsigned short qo[8], co[8];
    #pragma unroll
    for (int j=0;j<8;j++){
      const float x = ft[d0+j][ptl];
      const unsigned short qh = f2bf(x);
      const float y = -2.f*x;
      const unsigned short ch = f2bf(y);
      qo[j] = hl ? f2bf(x - bf2f(qh)) : qh;
      co[j] = hl ? f2bf(y - bf2f(ch)) : ch;
    }
    const int nt = (n0 >> 4) + ntl;
    const size_t off = ((size_t)((b*256 + nt)*4 + ks*2 + hl))*512 + l*8;
    uint4 qv, cv;
    qv.x = (uint32_t)qo[0] | ((uint32_t)qo[1]<<16);
    qv.y = (uint32_t)qo[2] | ((uint32_t)qo[3]<<16);
    qv.z = (uint32_t)qo[4] | ((uint32_t)qo[5]<<16);
    qv.w = (uint32_t)qo[6] | ((uint32_t)qo[7]<<16);
    cv.x = (uint32_t)co[0] | ((uint32_t)co[1]<<16);
    cv.y = (uint32_t)co[2] | ((uint32_t)co[3]<<16);
    cv.z = (uint32_t)co[4] | ((uint32_t)co[5]<<16);
    cv.w = (uint32_t)co[6] | ((uint32_t)co[7]<<16);
    *reinterpret_cast<uint4*>(qfrag + off) = qv;
    *reinterpret_cast<uint4*>(cfrag + off) = cv;
  }
}

// ---------------------------------------------------------------- MFMA kNN v5: (query-tile, eighth) per wave
__global__ __launch_bounds__(256, 4) void k_knn5(const unsigned short* __restrict__ cfrag,
                                                 const unsigned short* __restrict__ qfrag,
                                                 const float* __restrict__ sqn,
                                                 int* __restrict__ cand){
  const int t = threadIdx.x, w = t >> 6, l = t & 63, g = l >> 4;
  const int b = blockIdx.x >> 9;
  const int combo = (blockIdx.x & 511)*4 + w;
  const int qt = combo >> 3, eighth = combo & 7;
  const int ct0 = eighth * 32;

  bf16x8 qf00, qf01, qf10, qf11;
  {
    const unsigned short* qb = qfrag + ((size_t)(b*256 + qt))*2048 + l*8;
    qf00 = *reinterpret_cast<const bf16x8*>(qb);
    qf01 = *reinterpret_cast<const bf16x8*>(qb + 512);
    qf10 = *reinterpret_cast<const bf16x8*>(qb + 1024);
    qf11 = *reinterpret_cast<const bf16x8*>(qb + 1536);
  }
  const unsigned short* cb = cfrag + ((size_t)(b*256))*2048 + l*8;
  const float sqq = sqn[b*NN + qt*16 + (l & 15)];

  uint32_t kk[16];
  #pragma unroll
  for (int s=0;s<16;s++) kk[s] = 0xFFFFFFFFu;

  bf16x8 c00 = *reinterpret_cast<const bf16x8*>(cb + (size_t)ct0*2048);
  bf16x8 c01 = *reinterpret_cast<const bf16x8*>(cb + (size_t)ct0*2048 + 512);
  bf16x8 c10 = *reinterpret_cast<const bf16x8*>(cb + (size_t)ct0*2048 + 1024);
  bf16x8 c11 = *reinterpret_cast<const bf16x8*>(cb + (size_t)ct0*2048 + 1536);

  const float* sqb = sqn + b*NN + g*4;

  #pragma unroll 1
  for (int it=0; it<32; ++it){
    const int ct = ct0 + it;
    bf16x8 n00, n01, n10, n11;
    if (it < 31){
      const unsigned short* nb_ = cb + (size_t)(ct+1)*2048;
      n00 = *reinterpret_cast<const bf16x8*>(nb_);
      n01 = *reinterpret_cast<const bf16x8*>(nb_ + 512);
      n10 = *reinterpret_cast<const bf16x8*>(nb_ + 1024);
      n11 = *reinterpret_cast<const bf16x8*>(nb_ + 1536);
    }
    f32x4 acc = {0.f,0.f,0.f,0.f};
    acc = mfma16(c00, qf00, acc);
    acc = mfma16(c10, qf10, acc);
    acc = mfma16(c00, qf01, acc);
    acc = mfma16(c01, qf00, acc);
    acc = mfma16(c10, qf11, acc);
    acc = mfma16(c11, qf10, acc);
    const float4 sq4 = *reinterpret_cast<const float4*>(&sqb[ct*16]);
    const int cbase = ct*16 + g*4;
    uint32_t pv[4];
    pv[0] = (__float_as_uint(fmaxf(acc[0]+sq4.x+sqq, 0.f)) & 0xFFFFF000u) | (cbase+0);
    pv[1] = (__float_as_uint(fmaxf(acc[1]+sq4.y+sqq, 0.f)) & 0xFFFFF000u) | (cbase+1);
    pv[2] = (__float_as_uint(fmaxf(acc[2]+sq4.z+sqq, 0.f)) & 0xFFFFF000u) | (cbase+2);
    pv[3] = (__float_as_uint(fmaxf(acc[3]+sq4.w+sqq, 0.f)) & 0xFFFFF000u) | (cbase+3);
    const uint32_t mn = min(min(pv[0],pv[1]), min(pv[2],pv[3]));
    if (mn < kk[15]){
      #pragma unroll
      for (int u=0;u<4;u++){
        uint32_t v = pv[u];
        if (v < kk[15]){
          #pragma unroll
          for (int s=0;s<16;s++){
            const uint32_t hi = max(kk[s], v);
            kk[s] = min(kk[s], v);
            v = hi;
          }
        }
      }
    }
    c00 = n00; c01 = n01; c10 = n10; c11 = n11;
  }

  const int q = qt*16 + (l & 15);
  int* op = cand + ((size_t)(b*NN) + q)*128 + eighth*16;
  #pragma unroll 1
  for (int r=0; r<KK; ++r){
    uint32_t bm = kk[0];
    uint32_t om;
    om = __shfl_xor((int)bm, 16); bm = min(bm, om);
    om = __shfl_xor((int)bm, 32); bm = min(bm, om);
    if (kk[0] == bm){
      #pragma unroll
      for (int s=0;s<15;s++) kk[s] = kk[s+1];
      kk[15] = 0xFFFFFFFFu;
    }
    if (g == 0) op[r] = (int)(bm & 0xFFFu);
  }
}

// ---------------------------------------------------------------- exact f32 refine: wave per query, 2 candidates per lane (128)
__global__ __launch_bounds__(256) void k_refine(const float* __restrict__ fpm,
                                                const float* __restrict__ sqn,
                                                const int* __restrict__ cand,
                                                int* __restrict__ idx_ws){
  const int t = threadIdx.x, w = t >> 6, l = t & 63;
  const int q = blockIdx.x*4 + w;
  const int b = q >> 12;
  const int mi0 = cand[(size_t)q*128 + l];
  const int mi1 = cand[(size_t)q*128 + 64 + l];
  const float* qv = fpm + (size_t)q*DP;
  const float* cv0 = fpm + ((size_t)(b*NN) + mi0)*DP;
  const float* cv1 = fpm + ((size_t)(b*NN) + mi1)*DP;
  float dot0 = 0.f, dot1 = 0.f;
  #pragma unroll
  for (int d=0; d<DP; d+=4){
    const float4 a  = *reinterpret_cast<const float4*>(&qv[d]);
    const float4 x0 = *reinterpret_cast<const float4*>(&cv0[d]);
    const float4 x1 = *reinterpret_cast<const float4*>(&cv1[d]);
    dot0 += a.x*x0.x + a.y*x0.y + a.z*x0.z + a.w*x0.w;
    dot1 += a.x*x1.x + a.y*x1.y + a.z*x1.z + a.w*x1.w;
  }
  const float dist0 = sqn[b*NN + mi0] - 2.f*dot0;
  const float dist1 = sqn[b*NN + mi1] - 2.f*dot1;
  int rank0 = 0, rank1 = 0;
  #pragma unroll 4
  for (int j=0; j<64; j++){
    const float dj0 = __shfl(dist0, j);
    const int   ij0 = __shfl(mi0,  j);
    const float dj1 = __shfl(dist1, j);
    const int   ij1 = __shfl(mi1,  j);
    rank0 += (dj0 < dist0 || (dj0 == dist0 && ij0 < mi0)) ? 1 : 0;
    rank0 += (dj1 < dist0 || (dj1 == dist0 && ij1 < mi0)) ? 1 : 0;
    rank1 += (dj0 < dist1 || (dj0 == dist1 && ij0 < mi1)) ? 1 : 0;
    rank1 += (dj1 < dist1 || (dj1 == dist1 && ij1 < mi1)) ? 1 : 0;
  }
  if (rank0 < KK) idx_ws[(size_t)q*KK + rank0] = mi0;
  if (rank1 < KK) idx_ws[(size_t)q*KK + rank1] = mi1;
}

// ---------------------------------------------------------------- weight prep v2: 216 bf16 MFMA fragments
// 0..31 Wd2*s2 | 32..63 Wg1*s3 | 64..95 Wg2*s4 | 96..103 Wd1*s1d |
// 104..119 W1*s1 (8 tt x 2 ks) | 120..151 Wq | 152..183 Wk | 184..215 Wv
__global__ __launch_bounds__(256) void k_wprep2(
    const float* __restrict__ Wd1, const float* __restrict__ bnd1,
    const float* __restrict__ Wd2, const float* __restrict__ bnd2,
    const float* __restrict__ Wg1, const float* __restrict__ bng1,
    const float* __restrict__ Wg2, const float* __restrict__ bng2,
    const float* __restrict__ W1, const float* __restrict__ bn1,
    const float* __restrict__ Wq, const float* __restrict__ Wk,
    const float* __restrict__ Wv,
    unsigned short* __restrict__ wfrag){
  const int i = blockIdx.x*256 + threadIdx.x;
  if (i >= 216*64) return;
  const int f = i >> 6, l = i & 63;
  const int r16 = l & 15, kg = (l >> 4) * 8;
  unsigned short o8[8];
  if (f < 96){
    const int mat = f >> 5, tt = (f >> 2) & 7, ks = f & 3;
    const float* W; const float* bn;
    if (mat == 0){ W = Wd2; bn = bnd2; }
    else if (mat == 1){ W = Wg1; bn = bng1; }
    else { W = Wg2; bn = bng2; }
    const int row = tt*16 + r16;
    const float s = bn[row] * rsqrtf(bn[3*DM+row] + EPS);
    const float* src = W + (size_t)row*DM + ks*32 + kg;
    #pragma unroll
    for (int j=0;j<8;j++) o8[j] = f2bf(s * src[j]);
  } else if (f < 104){
    const int tt = f - 96;
    const int row = tt*16 + r16;
    const float s = bnd1[row] * rsqrtf(bnd1[3*DM+row] + EPS);
    #pragma unroll
    for (int j=0;j<8;j++){
      const int k = kg + j;
      o8[j] = (k < 3) ? f2bf(s * Wd1[row*3 + k]) : (unsigned short)0;
    }
  } else if (f < 120){
    const int fp = f - 104;
    const int tt = fp >> 1, ks = fp & 1;
    const int row = tt*16 + r16;
    const float s = bn1[row] * rsqrtf(bn1[3*DM+row] + EPS);
    const float* src = W1 + (size_t)row*DP + ks*32 + kg;
    #pragma unroll
    for (int j=0;j<8;j++) o8[j] = f2bf(s * src[j]);
  } else {
    const int fp = f - 120;
    const float* W = (fp < 32) ? Wq : (fp < 64 ? Wk : Wv);
    const int r = fp & 31, tt = r >> 2, ks = r & 3;
    const int row = tt*16 + r16;
    const float* src = W + (size_t)row*DM + ks*32 + kg;
    #pragma unroll
    for (int j=0;j<8;j++) o8[j] = f2bf(src[j]);
  }
  uint4 v;
  v.x = (uint32_t)o8[0] | ((uint32_t)o8[1]<<16);
  v.y = (uint32_t)o8[2] | ((uint32_t)o8[3]<<16);
  v.z = (uint32_t)o8[4] | ((uint32_t)o8[5]<<16);
  v.w = (uint32_t)o8[6] | ((uint32_t)o8[7]<<16);
  *reinterpret_cast<uint4*>(wfrag + (size_t)i*8) = v;
}

// ---------------------------------------------------------------- common frag/LDS macros
#define FRG(fi) (*reinterpret_cast<const bf16x8*>(&wfrag[(size_t)(fi)*512 + l*8]))

#define RD_B() \
  const bf16x8 b0 = *reinterpret_cast<const bf16x8*>(&hb[p*128 + ((0*4+g)^p)*8]); \
  const bf16x8 b1 = *reinterpret_cast<const bf16x8*>(&hb[p*128 + ((1*4+g)^p)*8]); \
  const bf16x8 b2 = *reinterpret_cast<const bf16x8*>(&hb[p*128 + ((2*4+g)^p)*8]); \
  const bf16x8 b3 = *reinterpret_cast<const bf16x8*>(&hb[p*128 + ((3*4+g)^p)*8]);

// ---------------------------------------------------------------- x -> q,k,v via MFMA (wave = 16 points)
#define X_STEP(tt) { \
  f32x4 acc = {0.f,0.f,0.f,0.f}; \
  acc = mfma16(FRG(104+(tt)*2+0), f00, acc); \
  acc = mfma16(FRG(104+(tt)*2+1), f10, acc); \
  acc = mfma16(FRG(104+(tt)*2+0), f01, acc); \
  acc = mfma16(FRG(104+(tt)*2+1), f11, acc); \
  const f32x4 sh = *reinterpret_cast<const f32x4*>(&bnT1[(tt)*16 + g*4]); \
  uint2 hp; \
  hp.x = pk2(lrelu(acc[0]+sh[0]), lrelu(acc[1]+sh[1])); \
  hp.y = pk2(lrelu(acc[2]+sh[2]), lrelu(acc[3]+sh[3])); \
  *reinterpret_cast<uint2*>(&hb[hwb + (((tt)*2 + (g>>1))^p)*8]) = hp; }

#define QKV_STEP(tt, base, OUT) { \
  f32x4 acc = {0.f,0.f,0.f,0.f}; \
  acc = mfma16(FRG((base)+(tt)*4+0), b0, acc); \
  acc = mfma16(FRG((base)+(tt)*4+1), b1, acc); \
  acc = mfma16(FRG((base)+(tt)*4+2), b2, acc); \
  acc = mfma16(FRG((base)+(tt)*4+3), b3, acc); \
  uint2 st; \
  st.x = pk2(acc[0], acc[1]); \
  st.y = pk2(acc[2], acc[3]); \
  *reinterpret_cast<uint2*>(&OUT[(size_t)(pt)*DM + (tt)*16 + g*4]) = st; }

__global__ __launch_bounds__(256) void k_xqkv2(const unsigned short* __restrict__ qfrag,
                                               const unsigned short* __restrict__ wfrag,
                                               const float* __restrict__ bn1,
                                               unsigned short* __restrict__ qbf,
                                               unsigned short* __restrict__ kbf,
                                               unsigned short* __restrict__ vbf){
  __shared__ __align__(16) unsigned short Hb[4][2048];
  __shared__ float bnT1[DM];
  const int t = threadIdx.x;
  if (t < DM){
    const float s = bn1[t] * rsqrtf(bn1[3*DM+t] + EPS);
    bnT1[t] = bn1[DM+t] - bn1[2*DM+t]*s;
  }
  __syncthreads();

  const int w = t >> 6, l = t & 63;
  const int p = l & 15, g = l >> 4;
  unsigned short* hb = Hb[w];
  const int hwb = p*128 + ((g & 1) * 4);

  const int ntg = blockIdx.x*4 + w;       // 0..1023
  const int b = ntg >> 8, nt = ntg & 255;
  const int pt = b*NN + nt*16 + p;        // this lane's point (for D stores)

  const unsigned short* qb = qfrag + ((size_t)(b*256 + nt))*2048 + l*8;
  const bf16x8 f00 = *reinterpret_cast<const bf16x8*>(qb);          // ks0 hi
  const bf16x8 f01 = *reinterpret_cast<const bf16x8*>(qb + 512);    // ks0 lo
  const bf16x8 f10 = *reinterpret_cast<const bf16x8*>(qb + 1024);   // ks1 hi
  const bf16x8 f11 = *reinterpret_cast<const bf16x8*>(qb + 1536);   // ks1 lo

  // x = lrelu(bn1(W1@f)) -> Hb (bf16 D-writes)
  X_STEP(0) X_STEP(1) X_STEP(2) X_STEP(3)
  X_STEP(4) X_STEP(5) X_STEP(6) X_STEP(7)

  // x as B-frags, then q/k/v (D-layout stores, point-major)
  RD_B()
  QKV_STEP(0, 120, qbf) QKV_STEP(1, 120, qbf) QKV_STEP(2, 120, qbf) QKV_STEP(3, 120, qbf)
  QKV_STEP(4, 120, qbf) QKV_STEP(5, 120, qbf) QKV_STEP(6, 120, qbf) QKV_STEP(7, 120, qbf)
  QKV_STEP(0, 152, kbf) QKV_STEP(1, 152, kbf) QKV_STEP(2, 152, kbf) QKV_STEP(3, 152, kbf)
  QKV_STEP(4, 152, kbf) QKV_STEP(5, 152, kbf) QKV_STEP(6, 152, kbf) QKV_STEP(7, 152, kbf)
  QKV_STEP(0, 184, vbf) QKV_STEP(1, 184, vbf) QKV_STEP(2, 184, vbf) QKV_STEP(3, 184, vbf)
  QKV_STEP(4, 184, vbf) QKV_STEP(5, 184, vbf) QKV_STEP(6, 184, vbf) QKV_STEP(7, 184, vbf)
}

// ---------------------------------------------------------------- staged attention
#define H1_STEP(tt) { \
  f32x4 acc = {0.f,0.f,0.f,0.f}; \
  acc = mfma16(FRG(96+(tt)), bv, acc); \
  const f32x4 sh = *reinterpret_cast<const f32x4*>(&bnT[0][(tt)*16 + g*4]); \
  uint2 hp; \
  hp.x = pk2(lrelu(acc[0]+sh[0]), lrelu(acc[1]+sh[1])); \
  hp.y = pk2(lrelu(acc[2]+sh[2]), lrelu(acc[3]+sh[3])); \
  *reinterpret_cast<uint2*>(&hb[hwb + (((tt)*2 + (g>>1))^p)*8]) = hp; }

#define PE_STEP(tt, PE) { \
  f32x4 acc = {0.f,0.f,0.f,0.f}; \
  acc = mfma16(FRG(0+(tt)*4+0), b0, acc); \
  acc = mfma16(FRG(0+(tt)*4+1), b1, acc); \
  acc = mfma16(FRG(0+(tt)*4+2), b2, acc); \
  acc = mfma16(FRG(0+(tt)*4+3), b3, acc); \
  const f32x4 sh = *reinterpret_cast<const f32x4*>(&bnT[1][(tt)*16 + g*4]); \
  PE[0]=lrelu(acc[0]+sh[0]); PE[1]=lrelu(acc[1]+sh[1]); \
  PE[2]=lrelu(acc[2]+sh[2]); PE[3]=lrelu(acc[3]+sh[3]); }

#define VPE_STEP(tt, PE) { \
  const uint2 du = *reinterpret_cast<const uint2*>(&hb[p*128 + (((tt)*2+(g>>1))^p)*8 + (g&1)*4]); \
  uint2 st; \
  st.x = pk2(bfl(du.x)+PE[0], bfh(du.x)+PE[1]); \
  st.y = pk2(bfl(du.y)+PE[2], bfh(du.y)+PE[3]); \
  *reinterpret_cast<uint2*>(&imgV[(size_t)Gc*1024 + l*16 + (tt)*2]) = st; }

#define QPE_STEP(tt, PE) { \
  const uint2 qu = *reinterpret_cast<const uint2*>(&qbf[(size_t)gp*DM + (tt)*16 + g*4]); \
  uint2 hp; \
  hp.x = pk2(bfl(qu.x)+PE[0], bfh(qu.x)+PE[1]); \
  hp.y = pk2(bfl(qu.y)+PE[2], bfh(qu.y)+PE[3]); \
  *reinterpret_cast<uint2*>(&hb[hwb + (((tt)*2 + (g>>1))^p)*8]) = hp; }

__global__ __launch_bounds__(256, 2) void k_pe5(
    const float* __restrict__ pos, const unsigned short* __restrict__ qbf,
    const unsigned short* __restrict__ kbf, const unsigned short* __restrict__ vbf,
    const int* __restrict__ idx_ws, const unsigned short* __restrict__ wfrag,
    const float* __restrict__ bnd1, const float* __restrict__ bnd2,
    const float* __restrict__ bng1, const float* __restrict__ bng2,
    unsigned short* __restrict__ imgA, uint32_t* __restrict__ imgV, int g0){
  __shared__ __align__(16) unsigned short Hb[4][2048];
  __shared__ float bnT[2][DM];

  const int t = threadIdx.x;
  if (t < DM){
    const float* bp[2] = {bnd1, bnd2};
    #pragma unroll
    for (int s4=0;s4<2;s4++){
      const float g = bp[s4][t], be = bp[s4][DM+t], mn = bp[s4][2*DM+t], vr = bp[s4][3*DM+t];
      const float sc = g * rsqrtf(vr + EPS);
      bnT[s4][t] = be - mn*sc;
    }
  }
  __syncthreads();

  const int w = t >> 6, l = t & 63;
  const int p = l & 15, g = l >> 4;
  unsigned short* hb = Hb[w];
  const int hwb = p*128 + ((g & 1) * 4);

  const int Gc = blockIdx.x*4 + w;
  const int gp = g0 + Gc;
  const int b = gp >> 12, n = gp & (NN-1);
  const int mi = idx_ws[gp*KK + p];

  uint32_t bw0 = 0u, bw1 = 0u;
  if (g == 0){
    const float* posb = pos + (size_t)b*3*NN;
    const float rx = posb[n]      - posb[mi];
    const float ry = posb[NN+n]   - posb[NN+mi];
    const float rz = posb[2*NN+n] - posb[2*NN+mi];
    bw0 = pk2(rx, ry);
    bw1 = pk2(rz, 0.f);
  }
  u32x4 bwv = {bw0, bw1, 0u, 0u};
  const bf16x8 bv = __builtin_bit_cast(bf16x8, bwv);

  H1_STEP(0) H1_STEP(1) H1_STEP(2) H1_STEP(3)
  H1_STEP(4) H1_STEP(5) H1_STEP(6) H1_STEP(7)

  f32x4 pe0, pe1, pe2, pe3, pe4, pe5, pe6, pe7;
  {
    RD_B()
    PE_STEP(0, pe0) PE_STEP(1, pe1) PE_STEP(2, pe2) PE_STEP(3, pe3)
    PE_STEP(4, pe4) PE_STEP(5, pe5) PE_STEP(6, pe6) PE_STEP(7, pe7)
  }

  {
    const unsigned short* vrow = vbf + ((size_t)(b*NN) + mi)*DM;
    const bf16x8 xv0 = *reinterpret_cast<const bf16x8*>(&vrow[ 0 + g*8]);
    const bf16x8 xv1 = *reinterpret_cast<const bf16x8*>(&vrow[32 + g*8]);
    const bf16x8 xv2 = *reinterpret_cast<const bf16x8*>(&vrow[64 + g*8]);
    const bf16x8 xv3 = *reinterpret_cast<const bf16x8*>(&vrow[96 + g*8]);
    *reinterpret_cast<bf16x8*>(&hb[p*128 + ((0*4+g)^p)*8]) = xv0;
    *reinterpret_cast<bf16x8*>(&hb[p*128 + ((1*4+g)^p)*8]) = xv1;
    *reinterpret_cast<bf16x8*>(&hb[p*128 + ((2*4+g)^p)*8]) = xv2;
    *reinterpret_cast<bf16x8*>(&hb[p*128 + ((3*4+g)^p)*8]) = xv3;
    VPE_STEP(0, pe0) VPE_STEP(1, pe1) VPE_STEP(2, pe2) VPE_STEP(3, pe3)
    VPE_STEP(4, pe4) VPE_STEP(5, pe5) VPE_STEP(6, pe6) VPE_STEP(7, pe7)
  }

  QPE_STEP(0, pe0) QPE_STEP(1, pe1) QPE_STEP(2, pe2) QPE_STEP(3, pe3)
  QPE_STEP(4, pe4) QPE_STEP(5, pe5) QPE_STEP(6, pe6) QPE_STEP(7, pe7)
  {
    const unsigned short* krow = kbf + ((size_t)(b*NN) + mi)*DM;
    const bf16x8 xk0 = *reinterpret_cast<const bf16x8*>(&krow[ 0 + g*8]);
    const bf16x8 xk1 = *reinterpret_cast<const bf16x8*>(&krow[32 + g*8]);
    const bf16x8 xk2 = *reinterpret_cast<const bf16x8*>(&krow[64 + g*8]);
    const bf16x8 xk3 = *reinterpret_cast<const bf16x8*>(&krow[96 + g*8]);
    RD_B()
    const u32x4 f0 = sub8(__builtin_bit_cast(u32x4, b0), __builtin_bit_cast(u32x4, xk0));
    const u32x4 f1 = sub8(__builtin_bit_cast(u32x4, b1), __builtin_bit_cast(u32x4, xk1));
    const u32x4 f2 = sub8(__builtin_bit_cast(u32x4, b2), __builtin_bit_cast(u32x4, xk2));
    const u32x4 f3 = sub8(__builtin_bit_cast(u32x4, b3), __builtin_bit_cast(u32x4, xk3));
    *reinterpret_cast<u32x4*>(&imgA[(size_t)Gc*2048 + 0*512 + l*8]) = f0;
    *reinterpret_cast<u32x4*>(&imgA[(size_t)Gc*2048 + 1*512 + l*8]) = f1;
    *reinterpret_cast<u32x4*>(&imgA[(size_t)Gc*2048 + 2*512 + l*8]) = f2;
    *reinterpret_cast<u32x4*>(&imgA[(size_t)Gc*2048 + 3*512 + l*8]) = f3;
  }
}

#define G1_STEP(tt) { \
  f32x4 acc = {0.f,0.f,0.f,0.f}; \
  acc = mfma16(FRG(32+(tt)*4+0), b0, acc); \
  acc = mfma16(FRG(32+(tt)*4+1), b1, acc); \
  acc = mfma16(FRG(32+(tt)*4+2), b2, acc); \
  acc = mfma16(FRG(32+(tt)*4+3), b3, acc); \
  const f32x4 sh = *reinterpret_cast<const f32x4*>(&bnT[2][(tt)*16 + g*4]); \
  uint2 hp; \
  hp.x = pk2(lrelu(acc[0]+sh[0]), lrelu(acc[1]+sh[1])); \
  hp.y = pk2(lrelu(acc[2]+sh[2]), lrelu(acc[3]+sh[3])); \
  *reinterpret_cast<uint2*>(&hb[hwb + (((tt)*2 + (g>>1))^p)*8]) = hp; }

#define E_STEP(tt, E) { \
  f32x4 acc = {0.f,0.f,0.f,0.f}; \
  acc = mfma16(FRG(64+(tt)*4+0), b0, acc); \
  acc = mfma16(FRG(64+(tt)*4+1), b1, acc); \
  acc = mfma16(FRG(64+(tt)*4+2), b2, acc); \
  acc = mfma16(FRG(64+(tt)*4+3), b3, acc); \
  const f32x4 sh = *reinterpret_cast<const f32x4*>(&bnT[3][(tt)*16 + g*4]); \
  E[0]=lrelu(acc[0]+sh[0])*0.015625f; E[1]=lrelu(acc[1]+sh[1])*0.015625f; \
  E[2]=lrelu(acc[2]+sh[2])*0.015625f; E[3]=lrelu(acc[3]+sh[3])*0.015625f; }

#define EXP_STEP(E) { \
  E[0]=__expf(E[0]-m); E[1]=__expf(E[1]-m); E[2]=__expf(E[2]-m); E[3]=__expf(E[3]-m); }

#define RED5(tt, E) { \
  const uint2 vu = *reinterpret_cast<const uint2*>(&imgV[(size_t)Gc*1024 + l*16 + (tt)*2]); \
  float o0, o1, o2, o3; \
  { float num=E[0]*bfl(vu.x), den=E[0]; \
    num+=sx16(num,1); den+=sx16(den,1); num+=sx16(num,2); den+=sx16(den,2); \
    num+=sx16(num,4); den+=sx16(den,4); num+=sx16(num,8); den+=sx16(den,8); \
    o0 = num*__builtin_amdgcn_rcpf(den); } \
  { float num=E[1]*bfh(vu.x), den=E[1]; \
    num+=sx16(num,1); den+=sx16(den,1); num+=sx16(num,2); den+=sx16(den,2); \
    num+=sx16(num,4); den+=sx16(den,4); num+=sx16(num,8); den+=sx16(den,8); \
    o1 = num*__builtin_amdgcn_rcpf(den); } \
  { float num=E[2]*bfl(vu.y), den=E[2]; \
    num+=sx16(num,1); den+=sx16(den,1); num+=sx16(num,2); den+=sx16(den,2); \
    num+=sx16(num,4); den+=sx16(den,4); num+=sx16(num,8); den+=sx16(den,8); \
    o2 = num*__builtin_amdgcn_rcpf(den); } \
  { float num=E[3]*bfh(vu.y), den=E[3]; \
    num+=sx16(num,1); den+=sx16(den,1); num+=sx16(num,2); den+=sx16(den,2); \
    num+=sx16(num,4); den+=sx16(den,4); num+=sx16(num,8); den+=sx16(den,8); \
    o3 = num*__builtin_amdgcn_rcpf(den); } \
  if (p == 0){ \
    uint2 st; st.x = pk2(o0,o1); st.y = pk2(o2,o3); \
    *reinterpret_cast<uint2*>(&resbf[(size_t)gp*DM + (tt)*16 + g*4]) = st; } }

__global__ __launch_bounds__(256, 2) void k_attn5(
    const unsigned short* __restrict__ imgA, const uint32_t* __restrict__ imgV,
    const unsigned short* __restrict__ wfrag,
    const float* __restrict__ bng1, const float* __restrict__ bng2,
    unsigned short* __restrict__ resbf, int g0){
  __shared__ __align__(16) unsigned short Hb[4][2048];
  __shared__ float bnT[4][DM];   // rows 2,3 used

  const int t = threadIdx.x;
  if (t < DM){
    const float* bp[2] = {bng1, bng2};
    #pragma unroll
    for (int s4=0;s4<2;s4++){
      const float g = bp[s4][t], be = bp[s4][DM+t], mn = bp[s4][2*DM+t], vr = bp[s4][3*DM+t];
      const float sc = g * rsqrtf(vr + EPS);
      bnT[2+s4][t] = be - mn*sc;
    }
  }
  __syncthreads();

  const int w = t >> 6, l = t & 63;
  const int p = l & 15, g = l >> 4;
  unsigned short* hb = Hb[w];
  const int hwb = p*128 + ((g & 1) * 4);

  const int Gc = blockIdx.x*4 + w;
  const int gp = g0 + Gc;

  {
    const bf16x8 b0 = *reinterpret_cast<const bf16x8*>(&imgA[(size_t)Gc*2048 + 0*512 + l*8]);
    const bf16x8 b1 = *reinterpret_cast<const bf16x8*>(&imgA[(size_t)Gc*2048 + 1*512 + l*8]);
    const bf16x8 b2 = *reinterpret_cast<const bf16x8*>(&imgA[(size_t)Gc*2048 + 2*512 + l*8]);
    const bf16x8 b3 = *reinterpret_cast<const bf16x8*>(&imgA[(size_t)Gc*2048 + 3*512 + l*8]);
    G1_STEP(0) G1_STEP(1) G1_STEP(2) G1_STEP(3)
    G1_STEP(4) G1_STEP(5) G1_STEP(6) G1_STEP(7)
  }

  f32x4 e0, e1, e2, e3, e4, e5, e6, e7;
  {
    RD_B()
    E_STEP(0, e0) E_STEP(1, e1) E_STEP(2, e2) E_STEP(3, e3)
    E_STEP(4, e4) E_STEP(5, e5) E_STEP(6, e6) E_STEP(7, e7)
  }

  f32x4 mm = vmax4(vmax4(vmax4(e0,e1), vmax4(e2,e3)), vmax4(vmax4(e4,e5), vmax4(e6,e7)));
  float m = fmaxf(fmaxf(mm[0],mm[1]), fmaxf(mm[2],mm[3]));
  m = fmaxf(m, sx16(m,1)); m = fmaxf(m, sx16(m,2));
  m = fmaxf(m, sx16(m,4)); m = fmaxf(m, sx16(m,8));
  EXP_STEP(e0) EXP_STEP(e1) EXP_STEP(e2) EXP_STEP(e3)
  EXP_STEP(e4) EXP_STEP(e5) EXP_STEP(e6) EXP_STEP(e7)

  RED5(0, e0) RED5(1, e1) RED5(2, e2) RED5(3, e3)
  RED5(4, e4) RED5(5, e5) RED5(6, e6) RED5(7, e7)
}

// ---------------------------------------------------------------- out = lrelu(bn2(W2@res)) + feats  (res is bf16)
__global__ __launch_bounds__(256, 1) void k_out(const unsigned short* __restrict__ resbf,
                                             const float* __restrict__ W2,
                                             const float* __restrict__ bn2,
                                             const float* __restrict__ feats,
                                             float* __restrict__ out){
  __shared__ float W2s[DP][DM+4];
  __shared__ float rt[128][DM+4];
  __shared__ float ob[DP][132];
  __shared__ float bS[DP], bT[DP];
  const int t = threadIdx.x;
  const int b = blockIdx.x >> 5;
  const int n0 = (blockIdx.x & 31) * 128;
  for (int i=t; i<DP*DM; i+=256){ W2s[i>>7][i&127] = W2[i]; }
  if (t < DP){
    float g=bn2[t], be=bn2[DP+t], mn=bn2[2*DP+t], vr=bn2[3*DP+t];
    float s = g*rsqrtf(vr+EPS); bS[t]=s; bT[t]=be-mn*s;
  }
  for (int i=t; i<128*(DM/4); i+=256){
    const int j=i>>5, c4=(i&31)*4;
    const ushort4 u = *reinterpret_cast<const ushort4*>(&resbf[((size_t)(b*NN)+n0+j)*DM + c4]);
    rt[j][c4+0] = bf2f(u.x); rt[j][c4+1] = bf2f(u.y);
    rt[j][c4+2] = bf2f(u.z); rt[j][c4+3] = bf2f(u.w);
  }
  __syncthreads();
  const int j = t>>1, cq = t&1;
  float acc[32];
  #pragma unroll
  for (int i=0;i<32;i++) acc[i]=0.f;
  for (int c=0;c<DM;c+=4){
    const float4 rv = *reinterpret_cast<const float4*>(&rt[j][c]);
    #pragma unroll
    for (int i=0;i<32;i++){
      const float4 wv = *reinterpret_cast<const float4*>(&W2s[cq+2*i][c]);
      acc[i] += wv.x*rv.x + wv.y*rv.y + wv.z*rv.z + wv.w*rv.w;
    }
  }
  #pragma unroll
  for (int i=0;i<32;i++) ob[cq+2*i][j] = acc[i];
  __syncthreads();
  for (int i=t; i<DP*128; i+=256){
    const int ch=i>>7, jj=i&127;
    const size_t o = (size_t)b*DP*NN + (size_t)ch*NN + n0 + jj;
    out[o] = lrelu(ob[ch][jj]*bS[ch] + bT[ch]) + feats[o];
  }
}

// ----------------------------------------------------------------
extern "C" void kernel_launch(void* const* d_in, const int* in_sizes, int n_in,
                              void* d_out, int out_size, void* d_ws, size_t ws_size,
                              hipStream_t stream) {
  const float* feats = (const float*)d_in[0];
  const float* pos   = (const float*)d_in[1];
  const float* W1    = (const float*)d_in[2];
  const float* bn1   = (const float*)d_in[3];
  const float* W2    = (const float*)d_in[4];
  const float* bn2   = (const float*)d_in[5];
  const float* Wq    = (const float*)d_in[6];
  const float* Wk    = (const float*)d_in[7];
  const float* Wv    = (const float*)d_in[8];
  const float* Wd1   = (const float*)d_in[9];
  const float* bnd1  = (const float*)d_in[10];
  const float* Wd2   = (const float*)d_in[11];
  const float* bnd2  = (const float*)d_in[12];
  const float* Wg1   = (const float*)d_in[13];
  const float* bng1  = (const float*)d_in[14];
  const float* Wg2   = (const float*)d_in[15];
  const float* bng2  = (const float*)d_in[16];
  float* out = (float*)d_out;

  unsigned short* qbf = (unsigned short*)d_ws;              // 4 MiB
  unsigned short* kbf = qbf + 2097152;                      // 4 MiB
  unsigned short* vbf = kbf + 2097152;                      // 4 MiB
  float* sqn = (float*)(vbf + 2097152);                     // 64 KiB
  int*   idx = (int*)(sqn + 16384);                         // 1 MiB
  unsigned short* wfrag = (unsigned short*)(idx + 262144);  // 216 KiB (216 frags)
  unsigned short* poolu = wfrag + 110592;                   // 20 MiB pool
  // knn phase overlays
  float* fpm = (float*)poolu;                               // 4 MiB
  unsigned short* cfrag = (unsigned short*)(fpm + 1048576); // 4 MiB
  unsigned short* qfrag = cfrag + 2097152;                  // 4 MiB
  int* cand = (int*)(qfrag + 2097152);                      // 8 MiB (128/query)
  // attn phase overlays
  unsigned short* resbf = poolu;                            // 4 MiB
  unsigned short* imgA  = poolu + 2097152;                  // 8 MiB (over cfrag+qfrag)
  uint32_t* imgV = (uint32_t*)(imgA + 4194304);             // 8 MiB (over cand)

  k_sqnorm<<<(NB*NN)/256, 256, 0, stream>>>(feats, sqn);
  k_fprep <<<NB*(NN/64), 256, 0, stream>>>(feats, cfrag, qfrag, fpm);
  k_knn5  <<<NB*512, 256, 0, stream>>>(cfrag, qfrag, sqn, cand);
  k_refine<<<(NB*NN)/4, 256, 0, stream>>>(fpm, sqn, cand, idx);
  k_wprep2<<<54, 256, 0, stream>>>(Wd1, bnd1, Wd2, bnd2, Wg1, bng1, Wg2, bng2,
                                   W1, bn1, Wq, Wk, Wv, wfrag);
  k_xqkv2 <<<NB*64, 256, 0, stream>>>(qfrag, wfrag, bn1, qbf, kbf, vbf);

  for (int c = 0; c < NCHUNK; ++c){
    const int g0 = c * CHPTS;
    k_pe5  <<<CHPTS/4, 256, 0, stream>>>(pos, qbf, kbf, vbf, idx, wfrag,
                                         bnd1, bnd2, bng1, bng2, imgA, imgV, g0);
    k_attn5<<<CHPTS/4, 256, 0, stream>>>(imgA, imgV, wfrag, bng1, bng2, resbf, g0);
  }

  k_out   <<<NB*(NN/128), 256, 0, stream>>>(resbf, W2, bn2, feats, out);
}

// Round 15
// 365.074 us; speedup vs baseline: 7.1365x; 1.2784x over previous
//
#include <hip/hip_runtime.h>
#include <cstdint>
#include <cstddef>

#define NB 4
#define NN 4096
#define KK 16
#define DP 64
#define DM 128
#define EPS 1e-5f

typedef __attribute__((ext_vector_type(8))) short bf16x8;
typedef __attribute__((ext_vector_type(4))) float f32x4;
typedef __attribute__((ext_vector_type(4))) unsigned int u32x4;

__device__ __forceinline__ float lrelu(float x){ return x >= 0.f ? x : 0.2f*x; }

__device__ __forceinline__ unsigned short f2bf(float x){
  union { float f; uint32_t u; } a; a.f = x;
  return (unsigned short)((a.u + 0x7fffu + ((a.u >> 16) & 1u)) >> 16);
}
__device__ __forceinline__ float bf2f(unsigned short h){
  union { uint32_t u; float f; } a; a.u = ((uint32_t)h) << 16; return a.f;
}
__device__ __forceinline__ uint32_t pk2(float a, float b){
  return (uint32_t)f2bf(a) | ((uint32_t)f2bf(b) << 16);
}
__device__ __forceinline__ float bfl(uint32_t w){ return __uint_as_float(w << 16); }
__device__ __forceinline__ float bfh(uint32_t w){ return __uint_as_float(w & 0xffff0000u); }

__device__ __forceinline__ f32x4 mfma16(bf16x8 a, bf16x8 b, f32x4 c){
  return __builtin_amdgcn_mfma_f32_16x16x32_bf16(a, b, c, 0, 0, 0);
}
__device__ __forceinline__ float sx16(float v, int m){ return __shfl_xor(v, m, 16); }
__device__ __forceinline__ f32x4 vmax4(f32x4 a, f32x4 b){
  f32x4 r; r[0]=fmaxf(a[0],b[0]); r[1]=fmaxf(a[1],b[1]); r[2]=fmaxf(a[2],b[2]); r[3]=fmaxf(a[3],b[3]); return r;
}
__device__ __forceinline__ u32x4 sub8(u32x4 a, u32x4 k){
  u32x4 r;
  r[0] = pk2(bfl(a[0])-bfl(k[0]), bfh(a[0])-bfh(k[0]));
  r[1] = pk2(bfl(a[1])-bfl(k[1]), bfh(a[1])-bfh(k[1]));
  r[2] = pk2(bfl(a[2])-bfl(k[2]), bfh(a[2])-bfh(k[2]));
  r[3] = pk2(bfl(a[3])-bfl(k[3]), bfh(a[3])-bfh(k[3]));
  return r;
}

// ---------------------------------------------------------------- sq norms
__global__ __launch_bounds__(256) void k_sqnorm(const float* __restrict__ feats,
                                                float* __restrict__ sqn){
  const int i = blockIdx.x*256 + threadIdx.x;
  const int b = i >> 12, n = i & (NN-1);
  const float* f = feats + (size_t)b*DP*NN + n;
  float s = 0.f;
  #pragma unroll
  for (int c=0;c<DP;c++){ const float v = f[(size_t)c*NN]; s += v*v; }
  sqn[i] = s;
}

// ---------------------------------------------------------------- feats -> bf16 hi/lo MFMA fragments + point-major f32 copy
__global__ __launch_bounds__(256) void k_fprep(const float* __restrict__ feats,
                                               unsigned short* __restrict__ cfrag,
                                               unsigned short* __restrict__ qfrag,
                                               float* __restrict__ fpm){
  __shared__ float ft[DP][65];
  const int t = threadIdx.x;
  const int b = blockIdx.x >> 6;
  const int n0 = (blockIdx.x & 63) * 64;
  for (int i=t; i<DP*64; i+=256){
    const int dim = i >> 6, pt = i & 63;
    ft[dim][pt] = feats[(size_t)b*DP*NN + (size_t)dim*NN + n0 + pt];
  }
  __syncthreads();
  for (int i=t; i<64*DP; i+=256){
    const int pt = i >> 6, dim = i & 63;
    fpm[((size_t)(b*NN) + n0 + pt)*DP + dim] = ft[dim][pt];
  }
  #pragma unroll
  for (int v = t; v < 1024; v += 256){
    const int l = v & 63, hl = (v>>6)&1, ks = (v>>7)&1, ntl = v>>8;
    const int ptl = ntl*16 + (l&15);
    const int d0 = ks*32 + (l>>4)*8;
    unsigned short qo[8], co[8];
    #pragma unroll
    for (int j=0;j<8;j++){
      const float x = ft[d0+j][ptl];
      const unsigned short qh = f2bf(x);
      const float y = -2.f*x;
      const unsigned short ch = f2bf(y);
      qo[j] = hl ? f2bf(x - bf2f(qh)) : qh;
      co[j] = hl ? f2bf(y - bf2f(ch)) : ch;
    }
    const int nt = (n0 >> 4) + ntl;
    const size_t off = ((size_t)((b*256 + nt)*4 + ks*2 + hl))*512 + l*8;
    uint4 qv, cv;
    qv.x = (uint32_t)qo[0] | ((uint32_t)qo[1]<<16);
    qv.y = (uint32_t)qo[2] | ((uint32_t)qo[3]<<16);
    qv.z = (uint32_t)qo[4] | ((uint32_t)qo[5]<<16);
    qv.w = (uint32_t)qo[6] | ((uint32_t)qo[7]<<16);
    cv.x = (uint32_t)co[0] | ((uint32_t)co[1]<<16);
    cv.y = (uint32_t)co[2] | ((uint32_t)co[3]<<16);
    cv.z = (uint32_t)co[4] | ((uint32_t)co[5]<<16);
    cv.w = (uint32_t)co[6] | ((uint32_t)co[7]<<16);
    *reinterpret_cast<uint4*>(qfrag + off) = qv;
    *reinterpret_cast<uint4*>(cfrag + off) = cv;
  }
}

// ---------------------------------------------------------------- MFMA kNN v5: (query-tile, eighth) per wave
__global__ __launch_bounds__(256, 4) void k_knn5(const unsigned short* __restrict__ cfrag,
                                                 const unsigned short* __restrict__ qfrag,
                                                 const float* __restrict__ sqn,
                                                 int* __restrict__ cand){
  const int t = threadIdx.x, w = t >> 6, l = t & 63, g = l >> 4;
  const int b = blockIdx.x >> 9;
  const int combo = (blockIdx.x & 511)*4 + w;
  const int qt = combo >> 3, eighth = combo & 7;
  const int ct0 = eighth * 32;

  bf16x8 qf00, qf01, qf10, qf11;
  {
    const unsigned short* qb = qfrag + ((size_t)(b*256 + qt))*2048 + l*8;
    qf00 = *reinterpret_cast<const bf16x8*>(qb);
    qf01 = *reinterpret_cast<const bf16x8*>(qb + 512);
    qf10 = *reinterpret_cast<const bf16x8*>(qb + 1024);
    qf11 = *reinterpret_cast<const bf16x8*>(qb + 1536);
  }
  const unsigned short* cb = cfrag + ((size_t)(b*256))*2048 + l*8;
  const float sqq = sqn[b*NN + qt*16 + (l & 15)];

  uint32_t kk[16];
  #pragma unroll
  for (int s=0;s<16;s++) kk[s] = 0xFFFFFFFFu;

  bf16x8 c00 = *reinterpret_cast<const bf16x8*>(cb + (size_t)ct0*2048);
  bf16x8 c01 = *reinterpret_cast<const bf16x8*>(cb + (size_t)ct0*2048 + 512);
  bf16x8 c10 = *reinterpret_cast<const bf16x8*>(cb + (size_t)ct0*2048 + 1024);
  bf16x8 c11 = *reinterpret_cast<const bf16x8*>(cb + (size_t)ct0*2048 + 1536);

  const float* sqb = sqn + b*NN + g*4;

  #pragma unroll 1
  for (int it=0; it<32; ++it){
    const int ct = ct0 + it;
    bf16x8 n00, n01, n10, n11;
    if (it < 31){
      const unsigned short* nb_ = cb + (size_t)(ct+1)*2048;
      n00 = *reinterpret_cast<const bf16x8*>(nb_);
      n01 = *reinterpret_cast<const bf16x8*>(nb_ + 512);
      n10 = *reinterpret_cast<const bf16x8*>(nb_ + 1024);
      n11 = *reinterpret_cast<const bf16x8*>(nb_ + 1536);
    }
    f32x4 acc = {0.f,0.f,0.f,0.f};
    acc = mfma16(c00, qf00, acc);
    acc = mfma16(c10, qf10, acc);
    acc = mfma16(c00, qf01, acc);
    acc = mfma16(c01, qf00, acc);
    acc = mfma16(c10, qf11, acc);
    acc = mfma16(c11, qf10, acc);
    const float4 sq4 = *reinterpret_cast<const float4*>(&sqb[ct*16]);
    const int cbase = ct*16 + g*4;
    uint32_t pv[4];
    pv[0] = (__float_as_uint(fmaxf(acc[0]+sq4.x+sqq, 0.f)) & 0xFFFFF000u) | (cbase+0);
    pv[1] = (__float_as_uint(fmaxf(acc[1]+sq4.y+sqq, 0.f)) & 0xFFFFF000u) | (cbase+1);
    pv[2] = (__float_as_uint(fmaxf(acc[2]+sq4.z+sqq, 0.f)) & 0xFFFFF000u) | (cbase+2);
    pv[3] = (__float_as_uint(fmaxf(acc[3]+sq4.w+sqq, 0.f)) & 0xFFFFF000u) | (cbase+3);
    const uint32_t mn = min(min(pv[0],pv[1]), min(pv[2],pv[3]));
    if (mn < kk[15]){
      #pragma unroll
      for (int u=0;u<4;u++){
        uint32_t v = pv[u];
        if (v < kk[15]){
          #pragma unroll
          for (int s=0;s<16;s++){
            const uint32_t hi = max(kk[s], v);
            kk[s] = min(kk[s], v);
            v = hi;
          }
        }
      }
    }
    c00 = n00; c01 = n01; c10 = n10; c11 = n11;
  }

  const int q = qt*16 + (l & 15);
  int* op = cand + ((size_t)(b*NN) + q)*128 + eighth*16;
  #pragma unroll 1
  for (int r=0; r<KK; ++r){
    uint32_t bm = kk[0];
    uint32_t om;
    om = __shfl_xor((int)bm, 16); bm = min(bm, om);
    om = __shfl_xor((int)bm, 32); bm = min(bm, om);
    if (kk[0] == bm){
      #pragma unroll
      for (int s=0;s<15;s++) kk[s] = kk[s+1];
      kk[15] = 0xFFFFFFFFu;
    }
    if (g == 0) op[r] = (int)(bm & 0xFFFu);
  }
}

// ---------------------------------------------------------------- exact f32 refine v2: bitonic-128 (u64 dist|idx), wave/query
__global__ __launch_bounds__(256) void k_refine2(const float* __restrict__ fpm,
                                                 const float* __restrict__ sqn,
                                                 const int* __restrict__ cand,
                                                 int* __restrict__ idx_ws){
  const int t = threadIdx.x, w = t >> 6, l = t & 63;
  const int q = blockIdx.x*4 + w;
  const int b = q >> 12;
  const int mi0 = cand[(size_t)q*128 + l];
  const int mi1 = cand[(size_t)q*128 + 64 + l];
  const float* qv = fpm + (size_t)q*DP;
  const float* cv0 = fpm + ((size_t)(b*NN) + mi0)*DP;
  const float* cv1 = fpm + ((size_t)(b*NN) + mi1)*DP;
  float dot0 = 0.f, dot1 = 0.f;
  #pragma unroll
  for (int d=0; d<DP; d+=4){
    const float4 a  = *reinterpret_cast<const float4*>(&qv[d]);
    const float4 x0 = *reinterpret_cast<const float4*>(&cv0[d]);
    const float4 x1 = *reinterpret_cast<const float4*>(&cv1[d]);
    dot0 += a.x*x0.x + a.y*x0.y + a.z*x0.z + a.w*x0.w;
    dot1 += a.x*x1.x + a.y*x1.y + a.z*x1.z + a.w*x1.w;
  }
  const float sqq = sqn[q];
  const float d0f = fmaxf(sqq + sqn[b*NN + mi0] - 2.f*dot0, 0.f);
  const float d1f = fmaxf(sqq + sqn[b*NN + mi1] - 2.f*dot1, 0.f);
  unsigned long long v0 = ((unsigned long long)__float_as_uint(d0f) << 32) | (unsigned)mi0;
  unsigned long long v1 = ((unsigned long long)__float_as_uint(d1f) << 32) | (unsigned)mi1;

  // bitonic sort of 128 elements: e0 = l (slot0), e1 = l+64 (slot1); ascending by element id
  #pragma unroll
  for (int k = 2; k <= 64; k <<= 1){
    #pragma unroll
    for (int j = k>>1; j >= 1; j >>= 1){
      const bool lp  = (l & j) == 0;
      const bool tm0 = ((l & k) == 0) == lp;
      const bool tm1 = (((l + 64) & k) == 0) == lp;
      const unsigned long long p0 = __shfl_xor(v0, j);
      const unsigned long long p1 = __shfl_xor(v1, j);
      v0 = tm0 ? (v0 < p0 ? v0 : p0) : (v0 > p0 ? v0 : p0);
      v1 = tm1 ? (v1 < p1 ? v1 : p1) : (v1 > p1 ? v1 : p1);
    }
  }
  { // k=128, j=64: in-lane pair, all ascending
    const unsigned long long lo = v0 < v1 ? v0 : v1;
    const unsigned long long hi = v0 < v1 ? v1 : v0;
    v0 = lo; v1 = hi;
  }
  #pragma unroll
  for (int j = 32; j >= 1; j >>= 1){ // k=128 tail: all ascending
    const bool tm = (l & j) == 0;
    const unsigned long long p0 = __shfl_xor(v0, j);
    const unsigned long long p1 = __shfl_xor(v1, j);
    v0 = tm ? (v0 < p0 ? v0 : p0) : (v0 > p0 ? v0 : p0);
    v1 = tm ? (v1 < p1 ? v1 : p1) : (v1 > p1 ? v1 : p1);
  }
  if (l < KK) idx_ws[(size_t)q*KK + l] = (int)(v0 & 0xFFFu);
}

// ---------------------------------------------------------------- weight prep v2: 216 bf16 MFMA fragments
__global__ __launch_bounds__(256) void k_wprep2(
    const float* __restrict__ Wd1, const float* __restrict__ bnd1,
    const float* __restrict__ Wd2, const float* __restrict__ bnd2,
    const float* __restrict__ Wg1, const float* __restrict__ bng1,
    const float* __restrict__ Wg2, const float* __restrict__ bng2,
    const float* __restrict__ W1, const float* __restrict__ bn1,
    const float* __restrict__ Wq, const float* __restrict__ Wk,
    const float* __restrict__ Wv,
    unsigned short* __restrict__ wfrag){
  const int i = blockIdx.x*256 + threadIdx.x;
  if (i >= 216*64) return;
  const int f = i >> 6, l = i & 63;
  const int r16 = l & 15, kg = (l >> 4) * 8;
  unsigned short o8[8];
  if (f < 96){
    const int mat = f >> 5, tt = (f >> 2) & 7, ks = f & 3;
    const float* W; const float* bn;
    if (mat == 0){ W = Wd2; bn = bnd2; }
    else if (mat == 1){ W = Wg1; bn = bng1; }
    else { W = Wg2; bn = bng2; }
    const int row = tt*16 + r16;
    const float s = bn[row] * rsqrtf(bn[3*DM+row] + EPS);
    const float* src = W + (size_t)row*DM + ks*32 + kg;
    #pragma unroll
    for (int j=0;j<8;j++) o8[j] = f2bf(s * src[j]);
  } else if (f < 104){
    const int tt = f - 96;
    const int row = tt*16 + r16;
    const float s = bnd1[row] * rsqrtf(bnd1[3*DM+row] + EPS);
    #pragma unroll
    for (int j=0;j<8;j++){
      const int k = kg + j;
      o8[j] = (k < 3) ? f2bf(s * Wd1[row*3 + k]) : (unsigned short)0;
    }
  } else if (f < 120){
    const int fp = f - 104;
    const int tt = fp >> 1, ks = fp & 1;
    const int row = tt*16 + r16;
    const float s = bn1[row] * rsqrtf(bn1[3*DM+row] + EPS);
    const float* src = W1 + (size_t)row*DP + ks*32 + kg;
    #pragma unroll
    for (int j=0;j<8;j++) o8[j] = f2bf(s * src[j]);
  } else {
    const int fp = f - 120;
    const float* W = (fp < 32) ? Wq : (fp < 64 ? Wk : Wv);
    const int r = fp & 31, tt = r >> 2, ks = r & 3;
    const int row = tt*16 + r16;
    const float* src = W + (size_t)row*DM + ks*32 + kg;
    #pragma unroll
    for (int j=0;j<8;j++) o8[j] = f2bf(src[j]);
  }
  uint4 v;
  v.x = (uint32_t)o8[0] | ((uint32_t)o8[1]<<16);
  v.y = (uint32_t)o8[2] | ((uint32_t)o8[3]<<16);
  v.z = (uint32_t)o8[4] | ((uint32_t)o8[5]<<16);
  v.w = (uint32_t)o8[6] | ((uint32_t)o8[7]<<16);
  *reinterpret_cast<uint4*>(wfrag + (size_t)i*8) = v;
}

// ---------------------------------------------------------------- common frag/LDS macros
#define FRG(fi) (*reinterpret_cast<const bf16x8*>(&wfrag[(size_t)(fi)*512 + l*8]))

#define RD_B() \
  const bf16x8 b0 = *reinterpret_cast<const bf16x8*>(&hb[p*128 + ((0*4+g)^p)*8]); \
  const bf16x8 b1 = *reinterpret_cast<const bf16x8*>(&hb[p*128 + ((1*4+g)^p)*8]); \
  const bf16x8 b2 = *reinterpret_cast<const bf16x8*>(&hb[p*128 + ((2*4+g)^p)*8]); \
  const bf16x8 b3 = *reinterpret_cast<const bf16x8*>(&hb[p*128 + ((3*4+g)^p)*8]);

// ---------------------------------------------------------------- x -> q,k,v via MFMA (wave = 16 points)
#define X_STEP(tt) { \
  f32x4 acc = {0.f,0.f,0.f,0.f}; \
  acc = mfma16(FRG(104+(tt)*2+0), f00, acc); \
  acc = mfma16(FRG(104+(tt)*2+1), f10, acc); \
  acc = mfma16(FRG(104+(tt)*2+0), f01, acc); \
  acc = mfma16(FRG(104+(tt)*2+1), f11, acc); \
  const f32x4 sh = *reinterpret_cast<const f32x4*>(&bnT1[(tt)*16 + g*4]); \
  uint2 hp; \
  hp.x = pk2(lrelu(acc[0]+sh[0]), lrelu(acc[1]+sh[1])); \
  hp.y = pk2(lrelu(acc[2]+sh[2]), lrelu(acc[3]+sh[3])); \
  *reinterpret_cast<uint2*>(&hb[hwb + (((tt)*2 + (g>>1))^p)*8]) = hp; }

#define QKV_STEP(tt, base, OUT) { \
  f32x4 acc = {0.f,0.f,0.f,0.f}; \
  acc = mfma16(FRG((base)+(tt)*4+0), b0, acc); \
  acc = mfma16(FRG((base)+(tt)*4+1), b1, acc); \
  acc = mfma16(FRG((base)+(tt)*4+2), b2, acc); \
  acc = mfma16(FRG((base)+(tt)*4+3), b3, acc); \
  uint2 st; \
  st.x = pk2(acc[0], acc[1]); \
  st.y = pk2(acc[2], acc[3]); \
  *reinterpret_cast<uint2*>(&OUT[(size_t)(pt)*DM + (tt)*16 + g*4]) = st; }

__global__ __launch_bounds__(256) void k_xqkv2(const unsigned short* __restrict__ qfrag,
                                               const unsigned short* __restrict__ wfrag,
                                               const float* __restrict__ bn1,
                                               unsigned short* __restrict__ qbf,
                                               unsigned short* __restrict__ kbf,
                                               unsigned short* __restrict__ vbf){
  __shared__ __align__(16) unsigned short Hb[4][2048];
  __shared__ float bnT1[DM];
  const int t = threadIdx.x;
  if (t < DM){
    const float s = bn1[t] * rsqrtf(bn1[3*DM+t] + EPS);
    bnT1[t] = bn1[DM+t] - bn1[2*DM+t]*s;
  }
  __syncthreads();

  const int w = t >> 6, l = t & 63;
  const int p = l & 15, g = l >> 4;
  unsigned short* hb = Hb[w];
  const int hwb = p*128 + ((g & 1) * 4);

  const int ntg = blockIdx.x*4 + w;
  const int b = ntg >> 8, nt = ntg & 255;
  const int pt = b*NN + nt*16 + p;

  const unsigned short* qb = qfrag + ((size_t)(b*256 + nt))*2048 + l*8;
  const bf16x8 f00 = *reinterpret_cast<const bf16x8*>(qb);
  const bf16x8 f01 = *reinterpret_cast<const bf16x8*>(qb + 512);
  const bf16x8 f10 = *reinterpret_cast<const bf16x8*>(qb + 1024);
  const bf16x8 f11 = *reinterpret_cast<const bf16x8*>(qb + 1536);

  X_STEP(0) X_STEP(1) X_STEP(2) X_STEP(3)
  X_STEP(4) X_STEP(5) X_STEP(6) X_STEP(7)

  RD_B()
  QKV_STEP(0, 120, qbf) QKV_STEP(1, 120, qbf) QKV_STEP(2, 120, qbf) QKV_STEP(3, 120, qbf)
  QKV_STEP(4, 120, qbf) QKV_STEP(5, 120, qbf) QKV_STEP(6, 120, qbf) QKV_STEP(7, 120, qbf)
  QKV_STEP(0, 152, kbf) QKV_STEP(1, 152, kbf) QKV_STEP(2, 152, kbf) QKV_STEP(3, 152, kbf)
  QKV_STEP(4, 152, kbf) QKV_STEP(5, 152, kbf) QKV_STEP(6, 152, kbf) QKV_STEP(7, 152, kbf)
  QKV_STEP(0, 184, vbf) QKV_STEP(1, 184, vbf) QKV_STEP(2, 184, vbf) QKV_STEP(3, 184, vbf)
  QKV_STEP(4, 184, vbf) QKV_STEP(5, 184, vbf) QKV_STEP(6, 184, vbf) QKV_STEP(7, 184, vbf)
}

// ---------------------------------------------------------------- fused attention (pe + attn, no intermediate images)
#define H1_STEP(tt) { \
  f32x4 acc = {0.f,0.f,0.f,0.f}; \
  acc = mfma16(FRG(96+(tt)), bv, acc); \
  const f32x4 sh = *reinterpret_cast<const f32x4*>(&bnT[0][(tt)*16 + g*4]); \
  uint2 hp; \
  hp.x = pk2(lrelu(acc[0]+sh[0]), lrelu(acc[1]+sh[1])); \
  hp.y = pk2(lrelu(acc[2]+sh[2]), lrelu(acc[3]+sh[3])); \
  *reinterpret_cast<uint2*>(&hb[hwb + (((tt)*2 + (g>>1))^p)*8]) = hp; }

#define PE_STEP(tt, PE) { \
  f32x4 acc = {0.f,0.f,0.f,0.f}; \
  acc = mfma16(FRG(0+(tt)*4+0), b0, acc); \
  acc = mfma16(FRG(0+(tt)*4+1), b1, acc); \
  acc = mfma16(FRG(0+(tt)*4+2), b2, acc); \
  acc = mfma16(FRG(0+(tt)*4+3), b3, acc); \
  const f32x4 sh = *reinterpret_cast<const f32x4*>(&bnT[1][(tt)*16 + g*4]); \
  PE[0]=lrelu(acc[0]+sh[0]); PE[1]=lrelu(acc[1]+sh[1]); \
  PE[2]=lrelu(acc[2]+sh[2]); PE[3]=lrelu(acc[3]+sh[3]); }

// vpe = transpose-read(v frags in Hb) + pe, kept in f32 registers
#define VPER_STEP(tt, PE, VPE) { \
  const uint2 du = *reinterpret_cast<const uint2*>(&hb[p*128 + (((tt)*2+(g>>1))^p)*8 + (g&1)*4]); \
  VPE[0] = bfl(du.x)+PE[0]; VPE[1] = bfh(du.x)+PE[1]; \
  VPE[2] = bfl(du.y)+PE[2]; VPE[3] = bfh(du.y)+PE[3]; }

#define QPE_STEP(tt, PE) { \
  const uint2 qu = *reinterpret_cast<const uint2*>(&qbf[(size_t)gp*DM + (tt)*16 + g*4]); \
  uint2 hp; \
  hp.x = pk2(bfl(qu.x)+PE[0], bfh(qu.x)+PE[1]); \
  hp.y = pk2(bfl(qu.y)+PE[2], bfh(qu.y)+PE[3]); \
  *reinterpret_cast<uint2*>(&hb[hwb + (((tt)*2 + (g>>1))^p)*8]) = hp; }

#define G1A_STEP(tt) { \
  f32x4 acc = {0.f,0.f,0.f,0.f}; \
  acc = mfma16(FRG(32+(tt)*4+0), ai0, acc); \
  acc = mfma16(FRG(32+(tt)*4+1), ai1, acc); \
  acc = mfma16(FRG(32+(tt)*4+2), ai2, acc); \
  acc = mfma16(FRG(32+(tt)*4+3), ai3, acc); \
  const f32x4 sh = *reinterpret_cast<const f32x4*>(&bnT[2][(tt)*16 + g*4]); \
  uint2 hp; \
  hp.x = pk2(lrelu(acc[0]+sh[0]), lrelu(acc[1]+sh[1])); \
  hp.y = pk2(lrelu(acc[2]+sh[2]), lrelu(acc[3]+sh[3])); \
  *reinterpret_cast<uint2*>(&hb[hwb + (((tt)*2 + (g>>1))^p)*8]) = hp; }

#define E_STEP(tt, E) { \
  f32x4 acc = {0.f,0.f,0.f,0.f}; \
  acc = mfma16(FRG(64+(tt)*4+0), b0, acc); \
  acc = mfma16(FRG(64+(tt)*4+1), b1, acc); \
  acc = mfma16(FRG(64+(tt)*4+2), b2, acc); \
  acc = mfma16(FRG(64+(tt)*4+3), b3, acc); \
  const f32x4 sh = *reinterpret_cast<const f32x4*>(&bnT[3][(tt)*16 + g*4]); \
  E[0]=lrelu(acc[0]+sh[0])*0.015625f; E[1]=lrelu(acc[1]+sh[1])*0.015625f; \
  E[2]=lrelu(acc[2]+sh[2])*0.015625f; E[3]=lrelu(acc[3]+sh[3])*0.015625f; }

#define EXP_STEP(E) { \
  E[0]=__expf(E[0]-m); E[1]=__expf(E[1]-m); E[2]=__expf(E[2]-m); E[3]=__expf(E[3]-m); }

#define REDF1(PE_r, E_r, OUT) { \
  float num = (E_r)*(PE_r); \
  float den = (E_r); \
  num += sx16(num,1); den += sx16(den,1); \
  num += sx16(num,2); den += sx16(den,2); \
  num += sx16(num,4); den += sx16(den,4); \
  num += sx16(num,8); den += sx16(den,8); \
  OUT = num * __builtin_amdgcn_rcpf(den); }

#define REDF_STEP(tt, E, VPE) { \
  float o0, o1, o2, o3; \
  REDF1(VPE[0], E[0], o0) REDF1(VPE[1], E[1], o1) \
  REDF1(VPE[2], E[2], o2) REDF1(VPE[3], E[3], o3) \
  if (p == 0){ \
    uint2 st; st.x = pk2(o0,o1); st.y = pk2(o2,o3); \
    *reinterpret_cast<uint2*>(&resbf[(size_t)gp*DM + (tt)*16 + g*4]) = st; } }

__global__ __launch_bounds__(256, 2) void k_fa(
    const float* __restrict__ pos, const unsigned short* __restrict__ qbf,
    const unsigned short* __restrict__ kbf, const unsigned short* __restrict__ vbf,
    const int* __restrict__ idx_ws, const unsigned short* __restrict__ wfrag,
    const float* __restrict__ bnd1, const float* __restrict__ bnd2,
    const float* __restrict__ bng1, const float* __restrict__ bng2,
    unsigned short* __restrict__ resbf){
  __shared__ __align__(16) unsigned short Hb[4][2048];
  __shared__ float bnT[4][DM];

  const int t = threadIdx.x;
  if (t < DM){
    const float* bp[4] = {bnd1, bnd2, bng1, bng2};
    #pragma unroll
    for (int s4=0;s4<4;s4++){
      const float g = bp[s4][t], be = bp[s4][DM+t], mn = bp[s4][2*DM+t], vr = bp[s4][3*DM+t];
      const float sc = g * rsqrtf(vr + EPS);
      bnT[s4][t] = be - mn*sc;
    }
  }
  __syncthreads();

  const int w = t >> 6, l = t & 63;
  const int p = l & 15, g = l >> 4;
  unsigned short* hb = Hb[w];
  const int hwb = p*128 + ((g & 1) * 4);

  const int gp = blockIdx.x*4 + w;
  const int b = gp >> 12, n = gp & (NN-1);
  const int mi = idx_ws[gp*KK + p];

  // rel-pos B fragment
  uint32_t bw0 = 0u, bw1 = 0u;
  if (g == 0){
    const float* posb = pos + (size_t)b*3*NN;
    const float rx = posb[n]      - posb[mi];
    const float ry = posb[NN+n]   - posb[NN+mi];
    const float rz = posb[2*NN+n] - posb[2*NN+mi];
    bw0 = pk2(rx, ry);
    bw1 = pk2(rz, 0.f);
  }
  u32x4 bwv = {bw0, bw1, 0u, 0u};
  const bf16x8 bv = __builtin_bit_cast(bf16x8, bwv);

  // layer 1 -> Hb
  H1_STEP(0) H1_STEP(1) H1_STEP(2) H1_STEP(3)
  H1_STEP(4) H1_STEP(5) H1_STEP(6) H1_STEP(7)

  // layer 2: pe
  f32x4 pe0, pe1, pe2, pe3, pe4, pe5, pe6, pe7;
  {
    RD_B()
    PE_STEP(0, pe0) PE_STEP(1, pe1) PE_STEP(2, pe2) PE_STEP(3, pe3)
    PE_STEP(4, pe4) PE_STEP(5, pe5) PE_STEP(6, pe6) PE_STEP(7, pe7)
  }

  // v gather -> Hb transpose -> vpe (f32 regs)
  f32x4 vp0, vp1, vp2, vp3, vp4, vp5, vp6, vp7;
  {
    const unsigned short* vrow = vbf + ((size_t)(b*NN) + mi)*DM;
    const bf16x8 xv0 = *reinterpret_cast<const bf16x8*>(&vrow[ 0 + g*8]);
    const bf16x8 xv1 = *reinterpret_cast<const bf16x8*>(&vrow[32 + g*8]);
    const bf16x8 xv2 = *reinterpret_cast<const bf16x8*>(&vrow[64 + g*8]);
    const bf16x8 xv3 = *reinterpret_cast<const bf16x8*>(&vrow[96 + g*8]);
    *reinterpret_cast<bf16x8*>(&hb[p*128 + ((0*4+g)^p)*8]) = xv0;
    *reinterpret_cast<bf16x8*>(&hb[p*128 + ((1*4+g)^p)*8]) = xv1;
    *reinterpret_cast<bf16x8*>(&hb[p*128 + ((2*4+g)^p)*8]) = xv2;
    *reinterpret_cast<bf16x8*>(&hb[p*128 + ((3*4+g)^p)*8]) = xv3;
    VPER_STEP(0, pe0, vp0) VPER_STEP(1, pe1, vp1) VPER_STEP(2, pe2, vp2) VPER_STEP(3, pe3, vp3)
    VPER_STEP(4, pe4, vp4) VPER_STEP(5, pe5, vp5) VPER_STEP(6, pe6, vp6) VPER_STEP(7, pe7, vp7)
  }

  // q + pe -> Hb
  QPE_STEP(0, pe0) QPE_STEP(1, pe1) QPE_STEP(2, pe2) QPE_STEP(3, pe3)
  QPE_STEP(4, pe4) QPE_STEP(5, pe5) QPE_STEP(6, pe6) QPE_STEP(7, pe7)

  // aIn frags = (q+pe) - k, then layer 3 -> Hb
  {
    const unsigned short* krow = kbf + ((size_t)(b*NN) + mi)*DM;
    const bf16x8 xk0 = *reinterpret_cast<const bf16x8*>(&krow[ 0 + g*8]);
    const bf16x8 xk1 = *reinterpret_cast<const bf16x8*>(&krow[32 + g*8]);
    const bf16x8 xk2 = *reinterpret_cast<const bf16x8*>(&krow[64 + g*8]);
    const bf16x8 xk3 = *reinterpret_cast<const bf16x8*>(&krow[96 + g*8]);
    RD_B()
    const bf16x8 ai0 = __builtin_bit_cast(bf16x8, sub8(__builtin_bit_cast(u32x4, b0), __builtin_bit_cast(u32x4, xk0)));
    const bf16x8 ai1 = __builtin_bit_cast(bf16x8, sub8(__builtin_bit_cast(u32x4, b1), __builtin_bit_cast(u32x4, xk1)));
    const bf16x8 ai2 = __builtin_bit_cast(bf16x8, sub8(__builtin_bit_cast(u32x4, b2), __builtin_bit_cast(u32x4, xk2)));
    const bf16x8 ai3 = __builtin_bit_cast(bf16x8, sub8(__builtin_bit_cast(u32x4, b3), __builtin_bit_cast(u32x4, xk3)));
    G1A_STEP(0) G1A_STEP(1) G1A_STEP(2) G1A_STEP(3)
    G1A_STEP(4) G1A_STEP(5) G1A_STEP(6) G1A_STEP(7)
  }

  // layer 4: logits
  f32x4 e0, e1, e2, e3, e4, e5, e6, e7;
  {
    RD_B()
    E_STEP(0, e0) E_STEP(1, e1) E_STEP(2, e2) E_STEP(3, e3)
    E_STEP(4, e4) E_STEP(5, e5) E_STEP(6, e6) E_STEP(7, e7)
  }

  // softmax over neighbors
  f32x4 mm = vmax4(vmax4(vmax4(e0,e1), vmax4(e2,e3)), vmax4(vmax4(e4,e5), vmax4(e6,e7)));
  float m = fmaxf(fmaxf(mm[0],mm[1]), fmaxf(mm[2],mm[3]));
  m = fmaxf(m, sx16(m,1)); m = fmaxf(m, sx16(m,2));
  m = fmaxf(m, sx16(m,4)); m = fmaxf(m, sx16(m,8));
  EXP_STEP(e0) EXP_STEP(e1) EXP_STEP(e2) EXP_STEP(e3)
  EXP_STEP(e4) EXP_STEP(e5) EXP_STEP(e6) EXP_STEP(e7)

  // weighted reduce of vpe
  REDF_STEP(0, e0, vp0) REDF_STEP(1, e1, vp1) REDF_STEP(2, e2, vp2) REDF_STEP(3, e3, vp3)
  REDF_STEP(4, e4, vp4) REDF_STEP(5, e5, vp5) REDF_STEP(6, e6, vp6) REDF_STEP(7, e7, vp7)
}

// ---------------------------------------------------------------- out = lrelu(bn2(W2@res)) + feats  (res is bf16)
__global__ __launch_bounds__(256, 1) void k_out(const unsigned short* __restrict__ resbf,
                                             const float* __restrict__ W2,
                                             const float* __restrict__ bn2,
                                             const float* __restrict__ feats,
                                             float* __restrict__ out){
  __shared__ float W2s[DP][DM+4];
  __shared__ float rt[128][DM+4];
  __shared__ float ob[DP][132];
  __shared__ float bS[DP], bT[DP];
  const int t = threadIdx.x;
  const int b = blockIdx.x >> 5;
  const int n0 = (blockIdx.x & 31) * 128;
  for (int i=t; i<DP*DM; i+=256){ W2s[i>>7][i&127] = W2[i]; }
  if (t < DP){
    float g=bn2[t], be=bn2[DP+t], mn=bn2[2*DP+t], vr=bn2[3*DP+t];
    float s = g*rsqrtf(vr+EPS); bS[t]=s; bT[t]=be-mn*s;
  }
  for (int i=t; i<128*(DM/4); i+=256){
    const int j=i>>5, c4=(i&31)*4;
    const ushort4 u = *reinterpret_cast<const ushort4*>(&resbf[((size_t)(b*NN)+n0+j)*DM + c4]);
    rt[j][c4+0] = bf2f(u.x); rt[j][c4+1] = bf2f(u.y);
    rt[j][c4+2] = bf2f(u.z); rt[j][c4+3] = bf2f(u.w);
  }
  __syncthreads();
  const int j = t>>1, cq = t&1;
  float acc[32];
  #pragma unroll
  for (int i=0;i<32;i++) acc[i]=0.f;
  for (int c=0;c<DM;c+=4){
    const float4 rv = *reinterpret_cast<const float4*>(&rt[j][c]);
    #pragma unroll
    for (int i=0;i<32;i++){
      const float4 wv = *reinterpret_cast<const float4*>(&W2s[cq+2*i][c]);
      acc[i] += wv.x*rv.x + wv.y*rv.y + wv.z*rv.z + wv.w*rv.w;
    }
  }
  #pragma unroll
  for (int i=0;i<32;i++) ob[cq+2*i][j] = acc[i];
  __syncthreads();
  for (int i=t; i<DP*128; i+=256){
    const int ch=i>>7, jj=i&127;
    const size_t o = (size_t)b*DP*NN + (size_t)ch*NN + n0 + jj;
    out[o] = lrelu(ob[ch][jj]*bS[ch] + bT[ch]) + feats[o];
  }
}

// ----------------------------------------------------------------
extern "C" void kernel_launch(void* const* d_in, const int* in_sizes, int n_in,
                              void* d_out, int out_size, void* d_ws, size_t ws_size,
                              hipStream_t stream) {
  const float* feats = (const float*)d_in[0];
  const float* pos   = (const float*)d_in[1];
  const float* W1    = (const float*)d_in[2];
  const float* bn1   = (const float*)d_in[3];
  const float* W2    = (const float*)d_in[4];
  const float* bn2   = (const float*)d_in[5];
  const float* Wq    = (const float*)d_in[6];
  const float* Wk    = (const float*)d_in[7];
  const float* Wv    = (const float*)d_in[8];
  const float* Wd1   = (const float*)d_in[9];
  const float* bnd1  = (const float*)d_in[10];
  const float* Wd2   = (const float*)d_in[11];
  const float* bnd2  = (const float*)d_in[12];
  const float* Wg1   = (const float*)d_in[13];
  const float* bng1  = (const float*)d_in[14];
  const float* Wg2   = (const float*)d_in[15];
  const float* bng2  = (const float*)d_in[16];
  float* out = (float*)d_out;

  unsigned short* qbf = (unsigned short*)d_ws;              // 4 MiB
  unsigned short* kbf = qbf + 2097152;                      // 4 MiB
  unsigned short* vbf = kbf + 2097152;                      // 4 MiB
  float* sqn = (float*)(vbf + 2097152);                     // 64 KiB
  int*   idx = (int*)(sqn + 16384);                         // 1 MiB
  unsigned short* wfrag = (unsigned short*)(idx + 262144);  // 216 KiB
  unsigned short* poolu = wfrag + 110592;                   // 20 MiB pool
  // knn phase overlays
  float* fpm = (float*)poolu;                               // 4 MiB
  unsigned short* cfrag = (unsigned short*)(fpm + 1048576); // 4 MiB
  unsigned short* qfrag = cfrag + 2097152;                  // 4 MiB
  int* cand = (int*)(qfrag + 2097152);                      // 8 MiB (128/query)
  // post-refine overlay: res (bf16, 4 MiB) over fpm (dead after k_refine2)
  unsigned short* resbf = poolu;

  k_sqnorm <<<(NB*NN)/256, 256, 0, stream>>>(feats, sqn);
  k_fprep  <<<NB*(NN/64), 256, 0, stream>>>(feats, cfrag, qfrag, fpm);
  k_knn5   <<<NB*512, 256, 0, stream>>>(cfrag, qfrag, sqn, cand);
  k_refine2<<<(NB*NN)/4, 256, 0, stream>>>(fpm, sqn, cand, idx);
  k_wprep2 <<<54, 256, 0, stream>>>(Wd1, bnd1, Wd2, bnd2, Wg1, bng1, Wg2, bng2,
                                    W1, bn1, Wq, Wk, Wv, wfrag);
  k_xqkv2  <<<NB*64, 256, 0, stream>>>(qfrag, wfrag, bn1, qbf, kbf, vbf);
  k_fa     <<<(NB*NN)/4, 256, 0, stream>>>(pos, qbf, kbf, vbf, idx, wfrag,
                                           bnd1, bnd2, bng1, bng2, resbf);
  k_out    <<<NB*(NN/128), 256, 0, stream>>>(resbf, W2, bn2, feats, out);
}

// Round 16
// 349.638 us; speedup vs baseline: 7.4516x; 1.0441x over previous
//
#include <hip/hip_runtime.h>
#include <hip/hip_fp16.h>
#include <cstdint>
#include <cstddef>

#define NB 4
#define NN 4096
#define KK 16
#define DP 64
#define DM 128
#define EPS 1e-5f

typedef __attribute__((ext_vector_type(8))) short bf16x8;
typedef __attribute__((ext_vector_type(4))) float f32x4;
typedef __attribute__((ext_vector_type(4))) unsigned int u32x4;

__device__ __forceinline__ float lrelu(float x){ return x >= 0.f ? x : 0.2f*x; }

__device__ __forceinline__ unsigned short f2bf(float x){
  union { float f; uint32_t u; } a; a.f = x;
  return (unsigned short)((a.u + 0x7fffu + ((a.u >> 16) & 1u)) >> 16);
}
__device__ __forceinline__ float bf2f(unsigned short h){
  union { uint32_t u; float f; } a; a.u = ((uint32_t)h) << 16; return a.f;
}
__device__ __forceinline__ uint32_t pk2(float a, float b){
  return (uint32_t)f2bf(a) | ((uint32_t)f2bf(b) << 16);
}
__device__ __forceinline__ float bfl(uint32_t w){ return __uint_as_float(w << 16); }
__device__ __forceinline__ float bfh(uint32_t w){ return __uint_as_float(w & 0xffff0000u); }

__device__ __forceinline__ f32x4 mfma16(bf16x8 a, bf16x8 b, f32x4 c){
  return __builtin_amdgcn_mfma_f32_16x16x32_bf16(a, b, c, 0, 0, 0);
}
__device__ __forceinline__ float sx16(float v, int m){ return __shfl_xor(v, m, 16); }
__device__ __forceinline__ u32x4 sub8(u32x4 a, u32x4 k){
  u32x4 r;
  r[0] = pk2(bfl(a[0])-bfl(k[0]), bfh(a[0])-bfh(k[0]));
  r[1] = pk2(bfl(a[1])-bfl(k[1]), bfh(a[1])-bfh(k[1]));
  r[2] = pk2(bfl(a[2])-bfl(k[2]), bfh(a[2])-bfh(k[2]));
  r[3] = pk2(bfl(a[3])-bfl(k[3]), bfh(a[3])-bfh(k[3]));
  return r;
}
// packed (num|den) half2 tree-reduce over the 16 neighbor lanes, then num/den
__device__ __forceinline__ float redh(float num, float den){
  __half2 nd = __floats2half2_rn(num, den);
  uint32_t u = __builtin_bit_cast(uint32_t, nd);
  #pragma unroll
  for (int m = 1; m < 16; m <<= 1){
    const uint32_t o = (uint32_t)__shfl_xor((int)u, m, 16);
    const __half2 s = __hadd2(__builtin_bit_cast(__half2, u), __builtin_bit_cast(__half2, o));
    u = __builtin_bit_cast(uint32_t, s);
  }
  const __half2 r = __builtin_bit_cast(__half2, u);
  return __low2float(r) * __builtin_amdgcn_rcpf(__high2float(r));
}

// ---------------------------------------------------------------- feats -> bf16 hi/lo MFMA fragments + fpm + sqn (fused)
__global__ __launch_bounds__(256) void k_fprep(const float* __restrict__ feats,
                                               unsigned short* __restrict__ cfrag,
                                               unsigned short* __restrict__ qfrag,
                                               float* __restrict__ fpm,
                                               float* __restrict__ sqn){
  __shared__ float ft[DP][65];
  const int t = threadIdx.x;
  const int b = blockIdx.x >> 6;
  const int n0 = (blockIdx.x & 63) * 64;
  for (int i=t; i<DP*64; i+=256){
    const int dim = i >> 6, pt = i & 63;
    ft[dim][pt] = feats[(size_t)b*DP*NN + (size_t)dim*NN + n0 + pt];
  }
  __syncthreads();
  // sq norms from the staged tile
  if (t < 64){
    float s = 0.f;
    #pragma unroll
    for (int d=0; d<DP; d++){ const float v = ft[d][t]; s += v*v; }
    sqn[b*NN + n0 + t] = s;
  }
  for (int i=t; i<64*DP; i+=256){
    const int pt = i >> 6, dim = i & 63;
    fpm[((size_t)(b*NN) + n0 + pt)*DP + dim] = ft[dim][pt];
  }
  #pragma unroll
  for (int v = t; v < 1024; v += 256){
    const int l = v & 63, hl = (v>>6)&1, ks = (v>>7)&1, ntl = v>>8;
    const int ptl = ntl*16 + (l&15);
    const int d0 = ks*32 + (l>>4)*8;
    unsigned short qo[8], co[8];
    #pragma unroll
    for (int j=0;j<8;j++){
      const float x = ft[d0+j][ptl];
      const unsigned short qh = f2bf(x);
      const float y = -2.f*x;
      const unsigned short ch = f2bf(y);
      qo[j] = hl ? f2bf(x - bf2f(qh)) : qh;
      co[j] = hl ? f2bf(y - bf2f(ch)) : ch;
    }
    const int nt = (n0 >> 4) + ntl;
    const size_t off = ((size_t)((b*256 + nt)*4 + ks*2 + hl))*512 + l*8;
    uint4 qv, cv;
    qv.x = (uint32_t)qo[0] | ((uint32_t)qo[1]<<16);
    qv.y = (uint32_t)qo[2] | ((uint32_t)qo[3]<<16);
    qv.z = (uint32_t)qo[4] | ((uint32_t)qo[5]<<16);
    qv.w = (uint32_t)qo[6] | ((uint32_t)qo[7]<<16);
    cv.x = (uint32_t)co[0] | ((uint32_t)co[1]<<16);
    cv.y = (uint32_t)co[2] | ((uint32_t)co[3]<<16);
    cv.z = (uint32_t)co[4] | ((uint32_t)co[5]<<16);
    cv.w = (uint32_t)co[6] | ((uint32_t)co[7]<<16);
    *reinterpret_cast<uint4*>(qfrag + off) = qv;
    *reinterpret_cast<uint4*>(cfrag + off) = cv;
  }
}

// ---------------------------------------------------------------- MFMA kNN v5: (query-tile, eighth) per wave
__global__ __launch_bounds__(256, 4) void k_knn5(const unsigned short* __restrict__ cfrag,
                                                 const unsigned short* __restrict__ qfrag,
                                                 const float* __restrict__ sqn,
                                                 int* __restrict__ cand){
  const int t = threadIdx.x, w = t >> 6, l = t & 63, g = l >> 4;
  const int b = blockIdx.x >> 9;
  const int combo = (blockIdx.x & 511)*4 + w;
  const int qt = combo >> 3, eighth = combo & 7;
  const int ct0 = eighth * 32;

  bf16x8 qf00, qf01, qf10, qf11;
  {
    const unsigned short* qb = qfrag + ((size_t)(b*256 + qt))*2048 + l*8;
    qf00 = *reinterpret_cast<const bf16x8*>(qb);
    qf01 = *reinterpret_cast<const bf16x8*>(qb + 512);
    qf10 = *reinterpret_cast<const bf16x8*>(qb + 1024);
    qf11 = *reinterpret_cast<const bf16x8*>(qb + 1536);
  }
  const unsigned short* cb = cfrag + ((size_t)(b*256))*2048 + l*8;
  const float sqq = sqn[b*NN + qt*16 + (l & 15)];

  uint32_t kk[16];
  #pragma unroll
  for (int s=0;s<16;s++) kk[s] = 0xFFFFFFFFu;

  bf16x8 c00 = *reinterpret_cast<const bf16x8*>(cb + (size_t)ct0*2048);
  bf16x8 c01 = *reinterpret_cast<const bf16x8*>(cb + (size_t)ct0*2048 + 512);
  bf16x8 c10 = *reinterpret_cast<const bf16x8*>(cb + (size_t)ct0*2048 + 1024);
  bf16x8 c11 = *reinterpret_cast<const bf16x8*>(cb + (size_t)ct0*2048 + 1536);

  const float* sqb = sqn + b*NN + g*4;

  #pragma unroll 1
  for (int it=0; it<32; ++it){
    const int ct = ct0 + it;
    bf16x8 n00, n01, n10, n11;
    if (it < 31){
      const unsigned short* nb_ = cb + (size_t)(ct+1)*2048;
      n00 = *reinterpret_cast<const bf16x8*>(nb_);
      n01 = *reinterpret_cast<const bf16x8*>(nb_ + 512);
      n10 = *reinterpret_cast<const bf16x8*>(nb_ + 1024);
      n11 = *reinterpret_cast<const bf16x8*>(nb_ + 1536);
    }
    f32x4 acc = {0.f,0.f,0.f,0.f};
    acc = mfma16(c00, qf00, acc);
    acc = mfma16(c10, qf10, acc);
    acc = mfma16(c00, qf01, acc);
    acc = mfma16(c01, qf00, acc);
    acc = mfma16(c10, qf11, acc);
    acc = mfma16(c11, qf10, acc);
    const float4 sq4 = *reinterpret_cast<const float4*>(&sqb[ct*16]);
    const int cbase = ct*16 + g*4;
    uint32_t pv[4];
    pv[0] = (__float_as_uint(fmaxf(acc[0]+sq4.x+sqq, 0.f)) & 0xFFFFF000u) | (cbase+0);
    pv[1] = (__float_as_uint(fmaxf(acc[1]+sq4.y+sqq, 0.f)) & 0xFFFFF000u) | (cbase+1);
    pv[2] = (__float_as_uint(fmaxf(acc[2]+sq4.z+sqq, 0.f)) & 0xFFFFF000u) | (cbase+2);
    pv[3] = (__float_as_uint(fmaxf(acc[3]+sq4.w+sqq, 0.f)) & 0xFFFFF000u) | (cbase+3);
    const uint32_t mn = min(min(pv[0],pv[1]), min(pv[2],pv[3]));
    if (mn < kk[15]){
      #pragma unroll
      for (int u=0;u<4;u++){
        uint32_t v = pv[u];
        if (v < kk[15]){
          #pragma unroll
          for (int s=0;s<16;s++){
            const uint32_t hi = max(kk[s], v);
            kk[s] = min(kk[s], v);
            v = hi;
          }
        }
      }
    }
    c00 = n00; c01 = n01; c10 = n10; c11 = n11;
  }

  const int q = qt*16 + (l & 15);
  int* op = cand + ((size_t)(b*NN) + q)*128 + eighth*16;
  #pragma unroll 1
  for (int r=0; r<KK; ++r){
    uint32_t bm = kk[0];
    uint32_t om;
    om = __shfl_xor((int)bm, 16); bm = min(bm, om);
    om = __shfl_xor((int)bm, 32); bm = min(bm, om);
    if (kk[0] == bm){
      #pragma unroll
      for (int s=0;s<15;s++) kk[s] = kk[s+1];
      kk[15] = 0xFFFFFFFFu;
    }
    if (g == 0) op[r] = (int)(bm & 0xFFFu);
  }
}

// ---------------------------------------------------------------- exact f32 refine v2: bitonic-128 (u64 dist|idx), wave/query
__global__ __launch_bounds__(256) void k_refine2(const float* __restrict__ fpm,
                                                 const float* __restrict__ sqn,
                                                 const int* __restrict__ cand,
                                                 int* __restrict__ idx_ws){
  const int t = threadIdx.x, w = t >> 6, l = t & 63;
  const int q = blockIdx.x*4 + w;
  const int b = q >> 12;
  const int mi0 = cand[(size_t)q*128 + l];
  const int mi1 = cand[(size_t)q*128 + 64 + l];
  const float* qv = fpm + (size_t)q*DP;
  const float* cv0 = fpm + ((size_t)(b*NN) + mi0)*DP;
  const float* cv1 = fpm + ((size_t)(b*NN) + mi1)*DP;
  float dot0 = 0.f, dot1 = 0.f;
  #pragma unroll
  for (int d=0; d<DP; d+=4){
    const float4 a  = *reinterpret_cast<const float4*>(&qv[d]);
    const float4 x0 = *reinterpret_cast<const float4*>(&cv0[d]);
    const float4 x1 = *reinterpret_cast<const float4*>(&cv1[d]);
    dot0 += a.x*x0.x + a.y*x0.y + a.z*x0.z + a.w*x0.w;
    dot1 += a.x*x1.x + a.y*x1.y + a.z*x1.z + a.w*x1.w;
  }
  const float sqq = sqn[q];
  const float d0f = fmaxf(sqq + sqn[b*NN + mi0] - 2.f*dot0, 0.f);
  const float d1f = fmaxf(sqq + sqn[b*NN + mi1] - 2.f*dot1, 0.f);
  unsigned long long v0 = ((unsigned long long)__float_as_uint(d0f) << 32) | (unsigned)mi0;
  unsigned long long v1 = ((unsigned long long)__float_as_uint(d1f) << 32) | (unsigned)mi1;

  #pragma unroll
  for (int k = 2; k <= 64; k <<= 1){
    #pragma unroll
    for (int j = k>>1; j >= 1; j >>= 1){
      const bool lp  = (l & j) == 0;
      const bool tm0 = ((l & k) == 0) == lp;
      const bool tm1 = (((l + 64) & k) == 0) == lp;
      const unsigned long long p0 = __shfl_xor(v0, j);
      const unsigned long long p1 = __shfl_xor(v1, j);
      v0 = tm0 ? (v0 < p0 ? v0 : p0) : (v0 > p0 ? v0 : p0);
      v1 = tm1 ? (v1 < p1 ? v1 : p1) : (v1 > p1 ? v1 : p1);
    }
  }
  {
    const unsigned long long lo = v0 < v1 ? v0 : v1;
    const unsigned long long hi = v0 < v1 ? v1 : v0;
    v0 = lo; v1 = hi;
  }
  #pragma unroll
  for (int j = 32; j >= 1; j >>= 1){
    const bool tm = (l & j) == 0;
    const unsigned long long p0 = __shfl_xor(v0, j);
    const unsigned long long p1 = __shfl_xor(v1, j);
    v0 = tm ? (v0 < p0 ? v0 : p0) : (v0 > p0 ? v0 : p0);
    v1 = tm ? (v1 < p1 ? v1 : p1) : (v1 > p1 ? v1 : p1);
  }
  if (l < KK) idx_ws[(size_t)q*KK + l] = (int)(v0 & 0xFFFu);
}

// ---------------------------------------------------------------- weight prep v2: 216 bf16 MFMA fragments
__global__ __launch_bounds__(256) void k_wprep2(
    const float* __restrict__ Wd1, const float* __restrict__ bnd1,
    const float* __restrict__ Wd2, const float* __restrict__ bnd2,
    const float* __restrict__ Wg1, const float* __restrict__ bng1,
    const float* __restrict__ Wg2, const float* __restrict__ bng2,
    const float* __restrict__ W1, const float* __restrict__ bn1,
    const float* __restrict__ Wq, const float* __restrict__ Wk,
    const float* __restrict__ Wv,
    unsigned short* __restrict__ wfrag){
  const int i = blockIdx.x*256 + threadIdx.x;
  if (i >= 216*64) return;
  const int f = i >> 6, l = i & 63;
  const int r16 = l & 15, kg = (l >> 4) * 8;
  unsigned short o8[8];
  if (f < 96){
    const int mat = f >> 5, tt = (f >> 2) & 7, ks = f & 3;
    const float* W; const float* bn;
    if (mat == 0){ W = Wd2; bn = bnd2; }
    else if (mat == 1){ W = Wg1; bn = bng1; }
    else { W = Wg2; bn = bng2; }
    const int row = tt*16 + r16;
    const float s = bn[row] * rsqrtf(bn[3*DM+row] + EPS);
    const float* src = W + (size_t)row*DM + ks*32 + kg;
    #pragma unroll
    for (int j=0;j<8;j++) o8[j] = f2bf(s * src[j]);
  } else if (f < 104){
    const int tt = f - 96;
    const int row = tt*16 + r16;
    const float s = bnd1[row] * rsqrtf(bnd1[3*DM+row] + EPS);
    #pragma unroll
    for (int j=0;j<8;j++){
      const int k = kg + j;
      o8[j] = (k < 3) ? f2bf(s * Wd1[row*3 + k]) : (unsigned short)0;
    }
  } else if (f < 120){
    const int fp = f - 104;
    const int tt = fp >> 1, ks = fp & 1;
    const int row = tt*16 + r16;
    const float s = bn1[row] * rsqrtf(bn1[3*DM+row] + EPS);
    const float* src = W1 + (size_t)row*DP + ks*32 + kg;
    #pragma unroll
    for (int j=0;j<8;j++) o8[j] = f2bf(s * src[j]);
  } else {
    const int fp = f - 120;
    const float* W = (fp < 32) ? Wq : (fp < 64 ? Wk : Wv);
    const int r = fp & 31, tt = r >> 2, ks = r & 3;
    const int row = tt*16 + r16;
    const float* src = W + (size_t)row*DM + ks*32 + kg;
    #pragma unroll
    for (int j=0;j<8;j++) o8[j] = f2bf(src[j]);
  }
  uint4 v;
  v.x = (uint32_t)o8[0] | ((uint32_t)o8[1]<<16);
  v.y = (uint32_t)o8[2] | ((uint32_t)o8[3]<<16);
  v.z = (uint32_t)o8[4] | ((uint32_t)o8[5]<<16);
  v.w = (uint32_t)o8[6] | ((uint32_t)o8[7]<<16);
  *reinterpret_cast<uint4*>(wfrag + (size_t)i*8) = v;
}

// ---------------------------------------------------------------- common frag/LDS macros
#define FRG(fi) (*reinterpret_cast<const bf16x8*>(&wfrag[(size_t)(fi)*512 + l*8]))

#define RD_B() \
  const bf16x8 b0 = *reinterpret_cast<const bf16x8*>(&hb[p*128 + ((0*4+g)^p)*8]); \
  const bf16x8 b1 = *reinterpret_cast<const bf16x8*>(&hb[p*128 + ((1*4+g)^p)*8]); \
  const bf16x8 b2 = *reinterpret_cast<const bf16x8*>(&hb[p*128 + ((2*4+g)^p)*8]); \
  const bf16x8 b3 = *reinterpret_cast<const bf16x8*>(&hb[p*128 + ((3*4+g)^p)*8]);

// ---------------------------------------------------------------- x -> q,k,v via MFMA (wave = 16 points)
#define X_STEP(tt) { \
  f32x4 acc = {0.f,0.f,0.f,0.f}; \
  acc = mfma16(FRG(104+(tt)*2+0), f00, acc); \
  acc = mfma16(FRG(104+(tt)*2+1), f10, acc); \
  acc = mfma16(FRG(104+(tt)*2+0), f01, acc); \
  acc = mfma16(FRG(104+(tt)*2+1), f11, acc); \
  const f32x4 sh = *reinterpret_cast<const f32x4*>(&bnT1[(tt)*16 + g*4]); \
  uint2 hp; \
  hp.x = pk2(lrelu(acc[0]+sh[0]), lrelu(acc[1]+sh[1])); \
  hp.y = pk2(lrelu(acc[2]+sh[2]), lrelu(acc[3]+sh[3])); \
  *reinterpret_cast<uint2*>(&hb[hwb + (((tt)*2 + (g>>1))^p)*8]) = hp; }

#define QKV_STEP(tt, base, OUT) { \
  f32x4 acc = {0.f,0.f,0.f,0.f}; \
  acc = mfma16(FRG((base)+(tt)*4+0), b0, acc); \
  acc = mfma16(FRG((base)+(tt)*4+1), b1, acc); \
  acc = mfma16(FRG((base)+(tt)*4+2), b2, acc); \
  acc = mfma16(FRG((base)+(tt)*4+3), b3, acc); \
  uint2 st; \
  st.x = pk2(acc[0], acc[1]); \
  st.y = pk2(acc[2], acc[3]); \
  *reinterpret_cast<uint2*>(&OUT[(size_t)(pt)*DM + (tt)*16 + g*4]) = st; }

__global__ __launch_bounds__(256) void k_xqkv2(const unsigned short* __restrict__ qfrag,
                                               const unsigned short* __restrict__ wfrag,
                                               const float* __restrict__ bn1,
                                               unsigned short* __restrict__ qbf,
                                               unsigned short* __restrict__ kbf,
                                               unsigned short* __restrict__ vbf){
  __shared__ __align__(16) unsigned short Hb[4][2048];
  __shared__ float bnT1[DM];
  const int t = threadIdx.x;
  if (t < DM){
    const float s = bn1[t] * rsqrtf(bn1[3*DM+t] + EPS);
    bnT1[t] = bn1[DM+t] - bn1[2*DM+t]*s;
  }
  __syncthreads();

  const int w = t >> 6, l = t & 63;
  const int p = l & 15, g = l >> 4;
  unsigned short* hb = Hb[w];
  const int hwb = p*128 + ((g & 1) * 4);

  const int ntg = blockIdx.x*4 + w;
  const int b = ntg >> 8, nt = ntg & 255;
  const int pt = b*NN + nt*16 + p;

  const unsigned short* qb = qfrag + ((size_t)(b*256 + nt))*2048 + l*8;
  const bf16x8 f00 = *reinterpret_cast<const bf16x8*>(qb);
  const bf16x8 f01 = *reinterpret_cast<const bf16x8*>(qb + 512);
  const bf16x8 f10 = *reinterpret_cast<const bf16x8*>(qb + 1024);
  const bf16x8 f11 = *reinterpret_cast<const bf16x8*>(qb + 1536);

  X_STEP(0) X_STEP(1) X_STEP(2) X_STEP(3)
  X_STEP(4) X_STEP(5) X_STEP(6) X_STEP(7)

  RD_B()
  QKV_STEP(0, 120, qbf) QKV_STEP(1, 120, qbf) QKV_STEP(2, 120, qbf) QKV_STEP(3, 120, qbf)
  QKV_STEP(4, 120, qbf) QKV_STEP(5, 120, qbf) QKV_STEP(6, 120, qbf) QKV_STEP(7, 120, qbf)
  QKV_STEP(0, 152, kbf) QKV_STEP(1, 152, kbf) QKV_STEP(2, 152, kbf) QKV_STEP(3, 152, kbf)
  QKV_STEP(4, 152, kbf) QKV_STEP(5, 152, kbf) QKV_STEP(6, 152, kbf) QKV_STEP(7, 152, kbf)
  QKV_STEP(0, 184, vbf) QKV_STEP(1, 184, vbf) QKV_STEP(2, 184, vbf) QKV_STEP(3, 184, vbf)
  QKV_STEP(4, 184, vbf) QKV_STEP(5, 184, vbf) QKV_STEP(6, 184, vbf) QKV_STEP(7, 184, vbf)
}

// ---------------------------------------------------------------- fused attention (pe + attn, no intermediate images)
#define H1_STEP(tt) { \
  f32x4 acc = {0.f,0.f,0.f,0.f}; \
  acc = mfma16(FRG(96+(tt)), bv, acc); \
  const f32x4 sh = *reinterpret_cast<const f32x4*>(&bnT[0][(tt)*16 + g*4]); \
  uint2 hp; \
  hp.x = pk2(lrelu(acc[0]+sh[0]), lrelu(acc[1]+sh[1])); \
  hp.y = pk2(lrelu(acc[2]+sh[2]), lrelu(acc[3]+sh[3])); \
  *reinterpret_cast<uint2*>(&hb[hwb + (((tt)*2 + (g>>1))^p)*8]) = hp; }

#define PE_STEP(tt, PE) { \
  f32x4 acc = {0.f,0.f,0.f,0.f}; \
  acc = mfma16(FRG(0+(tt)*4+0), b0, acc); \
  acc = mfma16(FRG(0+(tt)*4+1), b1, acc); \
  acc = mfma16(FRG(0+(tt)*4+2), b2, acc); \
  acc = mfma16(FRG(0+(tt)*4+3), b3, acc); \
  const f32x4 sh = *reinterpret_cast<const f32x4*>(&bnT[1][(tt)*16 + g*4]); \
  PE[0]=lrelu(acc[0]+sh[0]); PE[1]=lrelu(acc[1]+sh[1]); \
  PE[2]=lrelu(acc[2]+sh[2]); PE[3]=lrelu(acc[3]+sh[3]); }

#define VPER_STEP(tt, PE, VPE) { \
  const uint2 du = *reinterpret_cast<const uint2*>(&hb[p*128 + (((tt)*2+(g>>1))^p)*8 + (g&1)*4]); \
  VPE[0] = bfl(du.x)+PE[0]; VPE[1] = bfh(du.x)+PE[1]; \
  VPE[2] = bfl(du.y)+PE[2]; VPE[3] = bfh(du.y)+PE[3]; }

#define QPE_STEP(tt, PE) { \
  const uint2 qu = *reinterpret_cast<const uint2*>(&qbf[(size_t)gp*DM + (tt)*16 + g*4]); \
  uint2 hp; \
  hp.x = pk2(bfl(qu.x)+PE[0], bfh(qu.x)+PE[1]); \
  hp.y = pk2(bfl(qu.y)+PE[2], bfh(qu.y)+PE[3]); \
  *reinterpret_cast<uint2*>(&hb[hwb + (((tt)*2 + (g>>1))^p)*8]) = hp; }

#define G1A_STEP(tt) { \
  f32x4 acc = {0.f,0.f,0.f,0.f}; \
  acc = mfma16(FRG(32+(tt)*4+0), ai0, acc); \
  acc = mfma16(FRG(32+(tt)*4+1), ai1, acc); \
  acc = mfma16(FRG(32+(tt)*4+2), ai2, acc); \
  acc = mfma16(FRG(32+(tt)*4+3), ai3, acc); \
  const f32x4 sh = *reinterpret_cast<const f32x4*>(&bnT[2][(tt)*16 + g*4]); \
  uint2 hp; \
  hp.x = pk2(lrelu(acc[0]+sh[0]), lrelu(acc[1]+sh[1])); \
  hp.y = pk2(lrelu(acc[2]+sh[2]), lrelu(acc[3]+sh[3])); \
  *reinterpret_cast<uint2*>(&hb[hwb + (((tt)*2 + (g>>1))^p)*8]) = hp; }

#define E_STEP(tt, E) { \
  f32x4 acc = {0.f,0.f,0.f,0.f}; \
  acc = mfma16(FRG(64+(tt)*4+0), b0, acc); \
  acc = mfma16(FRG(64+(tt)*4+1), b1, acc); \
  acc = mfma16(FRG(64+(tt)*4+2), b2, acc); \
  acc = mfma16(FRG(64+(tt)*4+3), b3, acc); \
  const f32x4 sh = *reinterpret_cast<const f32x4*>(&bnT[3][(tt)*16 + g*4]); \
  E[0]=lrelu(acc[0]+sh[0])*0.015625f; E[1]=lrelu(acc[1]+sh[1])*0.015625f; \
  E[2]=lrelu(acc[2]+sh[2])*0.015625f; E[3]=lrelu(acc[3]+sh[3])*0.015625f; }

// exp without safe-max: logits are lrelu(bn(.))/64, |logit| << 80 -> no overflow risk
#define EXP0_STEP(E) { \
  E[0]=__expf(E[0]); E[1]=__expf(E[1]); E[2]=__expf(E[2]); E[3]=__expf(E[3]); }

#define REDF_STEP(tt, E, VPE) { \
  const float o0 = redh(E[0]*VPE[0], E[0]); \
  const float o1 = redh(E[1]*VPE[1], E[1]); \
  const float o2 = redh(E[2]*VPE[2], E[2]); \
  const float o3 = redh(E[3]*VPE[3], E[3]); \
  if (p == 0){ \
    uint2 st; st.x = pk2(o0,o1); st.y = pk2(o2,o3); \
    *reinterpret_cast<uint2*>(&resbf[(size_t)gp*DM + (tt)*16 + g*4]) = st; } }

__global__ __launch_bounds__(256, 2) void k_fa(
    const float* __restrict__ pos, const unsigned short* __restrict__ qbf,
    const unsigned short* __restrict__ kbf, const unsigned short* __restrict__ vbf,
    const int* __restrict__ idx_ws, const unsigned short* __restrict__ wfrag,
    const float* __restrict__ bnd1, const float* __restrict__ bnd2,
    const float* __restrict__ bng1, const float* __restrict__ bng2,
    unsigned short* __restrict__ resbf){
  __shared__ __align__(16) unsigned short Hb[4][2048];
  __shared__ float bnT[4][DM];

  const int t = threadIdx.x;
  if (t < DM){
    const float* bp[4] = {bnd1, bnd2, bng1, bng2};
    #pragma unroll
    for (int s4=0;s4<4;s4++){
      const float g = bp[s4][t], be = bp[s4][DM+t], mn = bp[s4][2*DM+t], vr = bp[s4][3*DM+t];
      const float sc = g * rsqrtf(vr + EPS);
      bnT[s4][t] = be - mn*sc;
    }
  }
  __syncthreads();

  const int w = t >> 6, l = t & 63;
  const int p = l & 15, g = l >> 4;
  unsigned short* hb = Hb[w];
  const int hwb = p*128 + ((g & 1) * 4);

  const int gp = blockIdx.x*4 + w;
  const int b = gp >> 12, n = gp & (NN-1);
  const int mi = idx_ws[gp*KK + p];

  uint32_t bw0 = 0u, bw1 = 0u;
  if (g == 0){
    const float* posb = pos + (size_t)b*3*NN;
    const float rx = posb[n]      - posb[mi];
    const float ry = posb[NN+n]   - posb[NN+mi];
    const float rz = posb[2*NN+n] - posb[2*NN+mi];
    bw0 = pk2(rx, ry);
    bw1 = pk2(rz, 0.f);
  }
  u32x4 bwv = {bw0, bw1, 0u, 0u};
  const bf16x8 bv = __builtin_bit_cast(bf16x8, bwv);

  H1_STEP(0) H1_STEP(1) H1_STEP(2) H1_STEP(3)
  H1_STEP(4) H1_STEP(5) H1_STEP(6) H1_STEP(7)

  f32x4 pe0, pe1, pe2, pe3, pe4, pe5, pe6, pe7;
  {
    RD_B()
    PE_STEP(0, pe0) PE_STEP(1, pe1) PE_STEP(2, pe2) PE_STEP(3, pe3)
    PE_STEP(4, pe4) PE_STEP(5, pe5) PE_STEP(6, pe6) PE_STEP(7, pe7)
  }

  f32x4 vp0, vp1, vp2, vp3, vp4, vp5, vp6, vp7;
  {
    const unsigned short* vrow = vbf + ((size_t)(b*NN) + mi)*DM;
    const bf16x8 xv0 = *reinterpret_cast<const bf16x8*>(&vrow[ 0 + g*8]);
    const bf16x8 xv1 = *reinterpret_cast<const bf16x8*>(&vrow[32 + g*8]);
    const bf16x8 xv2 = *reinterpret_cast<const bf16x8*>(&vrow[64 + g*8]);
    const bf16x8 xv3 = *reinterpret_cast<const bf16x8*>(&vrow[96 + g*8]);
    *reinterpret_cast<bf16x8*>(&hb[p*128 + ((0*4+g)^p)*8]) = xv0;
    *reinterpret_cast<bf16x8*>(&hb[p*128 + ((1*4+g)^p)*8]) = xv1;
    *reinterpret_cast<bf16x8*>(&hb[p*128 + ((2*4+g)^p)*8]) = xv2;
    *reinterpret_cast<bf16x8*>(&hb[p*128 + ((3*4+g)^p)*8]) = xv3;
    VPER_STEP(0, pe0, vp0) VPER_STEP(1, pe1, vp1) VPER_STEP(2, pe2, vp2) VPER_STEP(3, pe3, vp3)
    VPER_STEP(4, pe4, vp4) VPER_STEP(5, pe5, vp5) VPER_STEP(6, pe6, vp6) VPER_STEP(7, pe7, vp7)
  }

  QPE_STEP(0, pe0) QPE_STEP(1, pe1) QPE_STEP(2, pe2) QPE_STEP(3, pe3)
  QPE_STEP(4, pe4) QPE_STEP(5, pe5) QPE_STEP(6, pe6) QPE_STEP(7, pe7)

  {
    const unsigned short* krow = kbf + ((size_t)(b*NN) + mi)*DM;
    const bf16x8 xk0 = *reinterpret_cast<const bf16x8*>(&krow[ 0 + g*8]);
    const bf16x8 xk1 = *reinterpret_cast<const bf16x8*>(&krow[32 + g*8]);
    const bf16x8 xk2 = *reinterpret_cast<const bf16x8*>(&krow[64 + g*8]);
    const bf16x8 xk3 = *reinterpret_cast<const bf16x8*>(&krow[96 + g*8]);
    RD_B()
    const bf16x8 ai0 = __builtin_bit_cast(bf16x8, sub8(__builtin_bit_cast(u32x4, b0), __builtin_bit_cast(u32x4, xk0)));
    const bf16x8 ai1 = __builtin_bit_cast(bf16x8, sub8(__builtin_bit_cast(u32x4, b1), __builtin_bit_cast(u32x4, xk1)));
    const bf16x8 ai2 = __builtin_bit_cast(bf16x8, sub8(__builtin_bit_cast(u32x4, b2), __builtin_bit_cast(u32x4, xk2)));
    const bf16x8 ai3 = __builtin_bit_cast(bf16x8, sub8(__builtin_bit_cast(u32x4, b3), __builtin_bit_cast(u32x4, xk3)));
    G1A_STEP(0) G1A_STEP(1) G1A_STEP(2) G1A_STEP(3)
    G1A_STEP(4) G1A_STEP(5) G1A_STEP(6) G1A_STEP(7)
  }

  f32x4 e0, e1, e2, e3, e4, e5, e6, e7;
  {
    RD_B()
    E_STEP(0, e0) E_STEP(1, e1) E_STEP(2, e2) E_STEP(3, e3)
    E_STEP(4, e4) E_STEP(5, e5) E_STEP(6, e6) E_STEP(7, e7)
  }

  EXP0_STEP(e0) EXP0_STEP(e1) EXP0_STEP(e2) EXP0_STEP(e3)
  EXP0_STEP(e4) EXP0_STEP(e5) EXP0_STEP(e6) EXP0_STEP(e7)

  REDF_STEP(0, e0, vp0) REDF_STEP(1, e1, vp1) REDF_STEP(2, e2, vp2) REDF_STEP(3, e3, vp3)
  REDF_STEP(4, e4, vp4) REDF_STEP(5, e5, vp5) REDF_STEP(6, e6, vp6) REDF_STEP(7, e7, vp7)
}

// ---------------------------------------------------------------- out = lrelu(bn2(W2@res)) + feats  (res is bf16)
__global__ __launch_bounds__(256, 1) void k_out(const unsigned short* __restrict__ resbf,
                                             const float* __restrict__ W2,
                                             const float* __restrict__ bn2,
                                             const float* __restrict__ feats,
                                             float* __restrict__ out){
  __shared__ float W2s[DP][DM+4];
  __shared__ float rt[128][DM+4];
  __shared__ float ob[DP][132];
  __shared__ float bS[DP], bT[DP];
  const int t = threadIdx.x;
  const int b = blockIdx.x >> 5;
  const int n0 = (blockIdx.x & 31) * 128;
  for (int i=t; i<DP*DM; i+=256){ W2s[i>>7][i&127] = W2[i]; }
  if (t < DP){
    float g=bn2[t], be=bn2[DP+t], mn=bn2[2*DP+t], vr=bn2[3*DP+t];
    float s = g*rsqrtf(vr+EPS); bS[t]=s; bT[t]=be-mn*s;
  }
  for (int i=t; i<128*(DM/4); i+=256){
    const int j=i>>5, c4=(i&31)*4;
    const ushort4 u = *reinterpret_cast<const ushort4*>(&resbf[((size_t)(b*NN)+n0+j)*DM + c4]);
    rt[j][c4+0] = bf2f(u.x); rt[j][c4+1] = bf2f(u.y);
    rt[j][c4+2] = bf2f(u.z); rt[j][c4+3] = bf2f(u.w);
  }
  __syncthreads();
  const int j = t>>1, cq = t&1;
  float acc[32];
  #pragma unroll
  for (int i=0;i<32;i++) acc[i]=0.f;
  for (int c=0;c<DM;c+=4){
    const float4 rv = *reinterpret_cast<const float4*>(&rt[j][c]);
    #pragma unroll
    for (int i=0;i<32;i++){
      const float4 wv = *reinterpret_cast<const float4*>(&W2s[cq+2*i][c]);
      acc[i] += wv.x*rv.x + wv.y*rv.y + wv.z*rv.z + wv.w*rv.w;
    }
  }
  #pragma unroll
  for (int i=0;i<32;i++) ob[cq+2*i][j] = acc[i];
  __syncthreads();
  for (int i=t; i<DP*128; i+=256){
    const int ch=i>>7, jj=i&127;
    const size_t o = (size_t)b*DP*NN + (size_t)ch*NN + n0 + jj;
    out[o] = lrelu(ob[ch][jj]*bS[ch] + bT[ch]) + feats[o];
  }
}

// ----------------------------------------------------------------
extern "C" void kernel_launch(void* const* d_in, const int* in_sizes, int n_in,
                              void* d_out, int out_size, void* d_ws, size_t ws_size,
                              hipStream_t stream) {
  const float* feats = (const float*)d_in[0];
  const float* pos   = (const float*)d_in[1];
  const float* W1    = (const float*)d_in[2];
  const float* bn1   = (const float*)d_in[3];
  const float* W2    = (const float*)d_in[4];
  const float* bn2   = (const float*)d_in[5];
  const float* Wq    = (const float*)d_in[6];
  const float* Wk    = (const float*)d_in[7];
  const float* Wv    = (const float*)d_in[8];
  const float* Wd1   = (const float*)d_in[9];
  const float* bnd1  = (const float*)d_in[10];
  const float* Wd2   = (const float*)d_in[11];
  const float* bnd2  = (const float*)d_in[12];
  const float* Wg1   = (const float*)d_in[13];
  const float* bng1  = (const float*)d_in[14];
  const float* Wg2   = (const float*)d_in[15];
  const float* bng2  = (const float*)d_in[16];
  float* out = (float*)d_out;

  unsigned short* qbf = (unsigned short*)d_ws;              // 4 MiB
  unsigned short* kbf = qbf + 2097152;                      // 4 MiB
  unsigned short* vbf = kbf + 2097152;                      // 4 MiB
  float* sqn = (float*)(vbf + 2097152);                     // 64 KiB
  int*   idx = (int*)(sqn + 16384);                         // 1 MiB
  unsigned short* wfrag = (unsigned short*)(idx + 262144);  // 216 KiB
  unsigned short* poolu = wfrag + 110592;                   // 20 MiB pool
  // knn phase overlays
  float* fpm = (float*)poolu;                               // 4 MiB
  unsigned short* cfrag = (unsigned short*)(fpm + 1048576); // 4 MiB
  unsigned short* qfrag = cfrag + 2097152;                  // 4 MiB
  int* cand = (int*)(qfrag + 2097152);                      // 8 MiB (128/query)
  // post-refine overlay: res (bf16, 4 MiB) over fpm (dead after k_refine2)
  unsigned short* resbf = poolu;

  k_fprep  <<<NB*(NN/64), 256, 0, stream>>>(feats, cfrag, qfrag, fpm, sqn);
  k_knn5   <<<NB*512, 256, 0, stream>>>(cfrag, qfrag, sqn, cand);
  k_refine2<<<(NB*NN)/4, 256, 0, stream>>>(fpm, sqn, cand, idx);
  k_wprep2 <<<54, 256, 0, stream>>>(Wd1, bnd1, Wd2, bnd2, Wg1, bng1, Wg2, bng2,
                                    W1, bn1, Wq, Wk, Wv, wfrag);
  k_xqkv2  <<<NB*64, 256, 0, stream>>>(qfrag, wfrag, bn1, qbf, kbf, vbf);
  k_fa     <<<(NB*NN)/4, 256, 0, stream>>>(pos, qbf, kbf, vbf, idx, wfrag,
                                           bnd1, bnd2, bng1, bng2, resbf);
  k_out    <<<NB*(NN/128), 256, 0, stream>>>(resbf, W2, bn2, feats, out);
}

// Round 17
// 341.318 us; speedup vs baseline: 7.6332x; 1.0244x over previous
//
#include <hip/hip_runtime.h>
#include <hip/hip_fp16.h>
#include <cstdint>
#include <cstddef>

#define NB 4
#define NN 4096
#define KK 16
#define DP 64
#define DM 128
#define EPS 1e-5f

typedef __attribute__((ext_vector_type(8))) short bf16x8;
typedef __attribute__((ext_vector_type(4))) float f32x4;
typedef __attribute__((ext_vector_type(4))) unsigned int u32x4;

__device__ __forceinline__ float lrelu(float x){ return x >= 0.f ? x : 0.2f*x; }

__device__ __forceinline__ unsigned short f2bf(float x){
  union { float f; uint32_t u; } a; a.f = x;
  return (unsigned short)((a.u + 0x7fffu + ((a.u >> 16) & 1u)) >> 16);
}
__device__ __forceinline__ float bf2f(unsigned short h){
  union { uint32_t u; float f; } a; a.u = ((uint32_t)h) << 16; return a.f;
}
// HW packed f32x2 -> bf16x2 (lo = a, hi = b); single VALU op vs ~11 for emulated RNE
__device__ __forceinline__ uint32_t pk2(float a, float b){
  uint32_t r;
  asm("v_cvt_pk_bf16_f32 %0, %1, %2" : "=v"(r) : "v"(a), "v"(b));
  return r;
}
__device__ __forceinline__ float bfl(uint32_t w){ return __uint_as_float(w << 16); }
__device__ __forceinline__ float bfh(uint32_t w){ return __uint_as_float(w & 0xffff0000u); }

__device__ __forceinline__ f32x4 mfma16(bf16x8 a, bf16x8 b, f32x4 c){
  return __builtin_amdgcn_mfma_f32_16x16x32_bf16(a, b, c, 0, 0, 0);
}
__device__ __forceinline__ u32x4 sub8(u32x4 a, u32x4 k){
  u32x4 r;
  r[0] = pk2(bfl(a[0])-bfl(k[0]), bfh(a[0])-bfh(k[0]));
  r[1] = pk2(bfl(a[1])-bfl(k[1]), bfh(a[1])-bfh(k[1]));
  r[2] = pk2(bfl(a[2])-bfl(k[2]), bfh(a[2])-bfh(k[2]));
  r[3] = pk2(bfl(a[3])-bfl(k[3]), bfh(a[3])-bfh(k[3]));
  return r;
}
// packed (num|den) half2 reduce over the 16 neighbor lanes via DPP row rotations
// (the 16 lanes of one g-group are a DPP row; rotation tree = exact allreduce for adds)
__device__ __forceinline__ uint32_t dpp_ror(uint32_t u, const int ctrl_is_8, const int ctrl){
  // ctrl must be a literal at each call site; helper instantiated per-rot below
  return u;
}
__device__ __forceinline__ float redh(float num, float den){
  __half2 nd = __floats2half2_rn(num, den);
  uint32_t u = __builtin_bit_cast(uint32_t, nd);
  uint32_t o;
  o = (uint32_t)__builtin_amdgcn_update_dpp(0, (int)u, 0x128, 0xf, 0xf, true); // row_ror:8
  u = __builtin_bit_cast(uint32_t, __hadd2(__builtin_bit_cast(__half2,u), __builtin_bit_cast(__half2,o)));
  o = (uint32_t)__builtin_amdgcn_update_dpp(0, (int)u, 0x124, 0xf, 0xf, true); // row_ror:4
  u = __builtin_bit_cast(uint32_t, __hadd2(__builtin_bit_cast(__half2,u), __builtin_bit_cast(__half2,o)));
  o = (uint32_t)__builtin_amdgcn_update_dpp(0, (int)u, 0x122, 0xf, 0xf, true); // row_ror:2
  u = __builtin_bit_cast(uint32_t, __hadd2(__builtin_bit_cast(__half2,u), __builtin_bit_cast(__half2,o)));
  o = (uint32_t)__builtin_amdgcn_update_dpp(0, (int)u, 0x121, 0xf, 0xf, true); // row_ror:1
  u = __builtin_bit_cast(uint32_t, __hadd2(__builtin_bit_cast(__half2,u), __builtin_bit_cast(__half2,o)));
  const __half2 r = __builtin_bit_cast(__half2, u);
  return __low2float(r) * __builtin_amdgcn_rcpf(__high2float(r));
}

// ---------------------------------------------------------------- feats -> bf16 hi/lo MFMA fragments + fpm + sqn (fused)
__global__ __launch_bounds__(256) void k_fprep(const float* __restrict__ feats,
                                               unsigned short* __restrict__ cfrag,
                                               unsigned short* __restrict__ qfrag,
                                               float* __restrict__ fpm,
                                               float* __restrict__ sqn){
  __shared__ float ft[DP][65];
  const int t = threadIdx.x;
  const int b = blockIdx.x >> 6;
  const int n0 = (blockIdx.x & 63) * 64;
  for (int i=t; i<DP*64; i+=256){
    const int dim = i >> 6, pt = i & 63;
    ft[dim][pt] = feats[(size_t)b*DP*NN + (size_t)dim*NN + n0 + pt];
  }
  __syncthreads();
  if (t < 64){
    float s = 0.f;
    #pragma unroll
    for (int d=0; d<DP; d++){ const float v = ft[d][t]; s += v*v; }
    sqn[b*NN + n0 + t] = s;
  }
  for (int i=t; i<64*DP; i+=256){
    const int pt = i >> 6, dim = i & 63;
    fpm[((size_t)(b*NN) + n0 + pt)*DP + dim] = ft[dim][pt];
  }
  #pragma unroll
  for (int v = t; v < 1024; v += 256){
    const int l = v & 63, hl = (v>>6)&1, ks = (v>>7)&1, ntl = v>>8;
    const int ptl = ntl*16 + (l&15);
    const int d0 = ks*32 + (l>>4)*8;
    unsigned short qo[8], co[8];
    #pragma unroll
    for (int j=0;j<8;j++){
      const float x = ft[d0+j][ptl];
      const unsigned short qh = f2bf(x);
      const float y = -2.f*x;
      const unsigned short ch = f2bf(y);
      qo[j] = hl ? f2bf(x - bf2f(qh)) : qh;
      co[j] = hl ? f2bf(y - bf2f(ch)) : ch;
    }
    const int nt = (n0 >> 4) + ntl;
    const size_t off = ((size_t)((b*256 + nt)*4 + ks*2 + hl))*512 + l*8;
    uint4 qv, cv;
    qv.x = (uint32_t)qo[0] | ((uint32_t)qo[1]<<16);
    qv.y = (uint32_t)qo[2] | ((uint32_t)qo[3]<<16);
    qv.z = (uint32_t)qo[4] | ((uint32_t)qo[5]<<16);
    qv.w = (uint32_t)qo[6] | ((uint32_t)qo[7]<<16);
    cv.x = (uint32_t)co[0] | ((uint32_t)co[1]<<16);
    cv.y = (uint32_t)co[2] | ((uint32_t)co[3]<<16);
    cv.z = (uint32_t)co[4] | ((uint32_t)co[5]<<16);
    cv.w = (uint32_t)co[6] | ((uint32_t)co[7]<<16);
    *reinterpret_cast<uint4*>(qfrag + off) = qv;
    *reinterpret_cast<uint4*>(cfrag + off) = cv;
  }
}

// ---------------------------------------------------------------- MFMA kNN v5: (query-tile, eighth) per wave
__global__ __launch_bounds__(256, 4) void k_knn5(const unsigned short* __restrict__ cfrag,
                                                 const unsigned short* __restrict__ qfrag,
                                                 const float* __restrict__ sqn,
                                                 int* __restrict__ cand){
  const int t = threadIdx.x, w = t >> 6, l = t & 63, g = l >> 4;
  const int b = blockIdx.x >> 9;
  const int combo = (blockIdx.x & 511)*4 + w;
  const int qt = combo >> 3, eighth = combo & 7;
  const int ct0 = eighth * 32;

  bf16x8 qf00, qf01, qf10, qf11;
  {
    const unsigned short* qb = qfrag + ((size_t)(b*256 + qt))*2048 + l*8;
    qf00 = *reinterpret_cast<const bf16x8*>(qb);
    qf01 = *reinterpret_cast<const bf16x8*>(qb + 512);
    qf10 = *reinterpret_cast<const bf16x8*>(qb + 1024);
    qf11 = *reinterpret_cast<const bf16x8*>(qb + 1536);
  }
  const unsigned short* cb = cfrag + ((size_t)(b*256))*2048 + l*8;
  const float sqq = sqn[b*NN + qt*16 + (l & 15)];

  uint32_t kk[16];
  #pragma unroll
  for (int s=0;s<16;s++) kk[s] = 0xFFFFFFFFu;

  bf16x8 c00 = *reinterpret_cast<const bf16x8*>(cb + (size_t)ct0*2048);
  bf16x8 c01 = *reinterpret_cast<const bf16x8*>(cb + (size_t)ct0*2048 + 512);
  bf16x8 c10 = *reinterpret_cast<const bf16x8*>(cb + (size_t)ct0*2048 + 1024);
  bf16x8 c11 = *reinterpret_cast<const bf16x8*>(cb + (size_t)ct0*2048 + 1536);

  const float* sqb = sqn + b*NN + g*4;

  #pragma unroll 1
  for (int it=0; it<32; ++it){
    const int ct = ct0 + it;
    bf16x8 n00, n01, n10, n11;
    if (it < 31){
      const unsigned short* nb_ = cb + (size_t)(ct+1)*2048;
      n00 = *reinterpret_cast<const bf16x8*>(nb_);
      n01 = *reinterpret_cast<const bf16x8*>(nb_ + 512);
      n10 = *reinterpret_cast<const bf16x8*>(nb_ + 1024);
      n11 = *reinterpret_cast<const bf16x8*>(nb_ + 1536);
    }
    f32x4 acc = {0.f,0.f,0.f,0.f};
    acc = mfma16(c00, qf00, acc);
    acc = mfma16(c10, qf10, acc);
    acc = mfma16(c00, qf01, acc);
    acc = mfma16(c01, qf00, acc);
    acc = mfma16(c10, qf11, acc);
    acc = mfma16(c11, qf10, acc);
    const float4 sq4 = *reinterpret_cast<const float4*>(&sqb[ct*16]);
    const int cbase = ct*16 + g*4;
    uint32_t pv[4];
    pv[0] = (__float_as_uint(fmaxf(acc[0]+sq4.x+sqq, 0.f)) & 0xFFFFF000u) | (cbase+0);
    pv[1] = (__float_as_uint(fmaxf(acc[1]+sq4.y+sqq, 0.f)) & 0xFFFFF000u) | (cbase+1);
    pv[2] = (__float_as_uint(fmaxf(acc[2]+sq4.z+sqq, 0.f)) & 0xFFFFF000u) | (cbase+2);
    pv[3] = (__float_as_uint(fmaxf(acc[3]+sq4.w+sqq, 0.f)) & 0xFFFFF000u) | (cbase+3);
    const uint32_t mn = min(min(pv[0],pv[1]), min(pv[2],pv[3]));
    if (mn < kk[15]){
      #pragma unroll
      for (int u=0;u<4;u++){
        uint32_t v = pv[u];
        if (v < kk[15]){
          #pragma unroll
          for (int s=0;s<16;s++){
            const uint32_t hi = max(kk[s], v);
            kk[s] = min(kk[s], v);
            v = hi;
          }
        }
      }
    }
    c00 = n00; c01 = n01; c10 = n10; c11 = n11;
  }

  const int q = qt*16 + (l & 15);
  int* op = cand + ((size_t)(b*NN) + q)*128 + eighth*16;
  #pragma unroll 1
  for (int r=0; r<KK; ++r){
    uint32_t bm = kk[0];
    uint32_t om;
    om = __shfl_xor((int)bm, 16); bm = min(bm, om);
    om = __shfl_xor((int)bm, 32); bm = min(bm, om);
    if (kk[0] == bm){
      #pragma unroll
      for (int s=0;s<15;s++) kk[s] = kk[s+1];
      kk[15] = 0xFFFFFFFFu;
    }
    if (g == 0) op[r] = (int)(bm & 0xFFFu);
  }
}

// ---------------------------------------------------------------- exact f32 refine v2: bitonic-128 (u64 dist|idx), wave/query
__global__ __launch_bounds__(256) void k_refine2(const float* __restrict__ fpm,
                                                 const float* __restrict__ sqn,
                                                 const int* __restrict__ cand,
                                                 int* __restrict__ idx_ws){
  const int t = threadIdx.x, w = t >> 6, l = t & 63;
  const int q = blockIdx.x*4 + w;
  const int b = q >> 12;
  const int mi0 = cand[(size_t)q*128 + l];
  const int mi1 = cand[(size_t)q*128 + 64 + l];
  const float* qv = fpm + (size_t)q*DP;
  const float* cv0 = fpm + ((size_t)(b*NN) + mi0)*DP;
  const float* cv1 = fpm + ((size_t)(b*NN) + mi1)*DP;
  float dot0 = 0.f, dot1 = 0.f;
  #pragma unroll
  for (int d=0; d<DP; d+=4){
    const float4 a  = *reinterpret_cast<const float4*>(&qv[d]);
    const float4 x0 = *reinterpret_cast<const float4*>(&cv0[d]);
    const float4 x1 = *reinterpret_cast<const float4*>(&cv1[d]);
    dot0 += a.x*x0.x + a.y*x0.y + a.z*x0.z + a.w*x0.w;
    dot1 += a.x*x1.x + a.y*x1.y + a.z*x1.z + a.w*x1.w;
  }
  const float sqq = sqn[q];
  const float d0f = fmaxf(sqq + sqn[b*NN + mi0] - 2.f*dot0, 0.f);
  const float d1f = fmaxf(sqq + sqn[b*NN + mi1] - 2.f*dot1, 0.f);
  unsigned long long v0 = ((unsigned long long)__float_as_uint(d0f) << 32) | (unsigned)mi0;
  unsigned long long v1 = ((unsigned long long)__float_as_uint(d1f) << 32) | (unsigned)mi1;

  #pragma unroll
  for (int k = 2; k <= 64; k <<= 1){
    #pragma unroll
    for (int j = k>>1; j >= 1; j >>= 1){
      const bool lp  = (l & j) == 0;
      const bool tm0 = ((l & k) == 0) == lp;
      const bool tm1 = (((l + 64) & k) == 0) == lp;
      const unsigned long long p0 = __shfl_xor(v0, j);
      const unsigned long long p1 = __shfl_xor(v1, j);
      v0 = tm0 ? (v0 < p0 ? v0 : p0) : (v0 > p0 ? v0 : p0);
      v1 = tm1 ? (v1 < p1 ? v1 : p1) : (v1 > p1 ? v1 : p1);
    }
  }
  {
    const unsigned long long lo = v0 < v1 ? v0 : v1;
    const unsigned long long hi = v0 < v1 ? v1 : v0;
    v0 = lo; v1 = hi;
  }
  #pragma unroll
  for (int j = 32; j >= 1; j >>= 1){
    const bool tm = (l & j) == 0;
    const unsigned long long p0 = __shfl_xor(v0, j);
    const unsigned long long p1 = __shfl_xor(v1, j);
    v0 = tm ? (v0 < p0 ? v0 : p0) : (v0 > p0 ? v0 : p0);
    v1 = tm ? (v1 < p1 ? v1 : p1) : (v1 > p1 ? v1 : p1);
  }
  if (l < KK) idx_ws[(size_t)q*KK + l] = (int)(v0 & 0xFFFu);
}

// ---------------------------------------------------------------- weight prep v2: 216 bf16 MFMA fragments
__global__ __launch_bounds__(256) void k_wprep2(
    const float* __restrict__ Wd1, const float* __restrict__ bnd1,
    const float* __restrict__ Wd2, const float* __restrict__ bnd2,
    const float* __restrict__ Wg1, const float* __restrict__ bng1,
    const float* __restrict__ Wg2, const float* __restrict__ bng2,
    const float* __restrict__ W1, const float* __restrict__ bn1,
    const float* __restrict__ Wq, const float* __restrict__ Wk,
    const float* __restrict__ Wv,
    unsigned short* __restrict__ wfrag){
  const int i = blockIdx.x*256 + threadIdx.x;
  if (i >= 216*64) return;
  const int f = i >> 6, l = i & 63;
  const int r16 = l & 15, kg = (l >> 4) * 8;
  unsigned short o8[8];
  if (f < 96){
    const int mat = f >> 5, tt = (f >> 2) & 7, ks = f & 3;
    const float* W; const float* bn;
    if (mat == 0){ W = Wd2; bn = bnd2; }
    else if (mat == 1){ W = Wg1; bn = bng1; }
    else { W = Wg2; bn = bng2; }
    const int row = tt*16 + r16;
    const float s = bn[row] * rsqrtf(bn[3*DM+row] + EPS);
    const float* src = W + (size_t)row*DM + ks*32 + kg;
    #pragma unroll
    for (int j=0;j<8;j++) o8[j] = f2bf(s * src[j]);
  } else if (f < 104){
    const int tt = f - 96;
    const int row = tt*16 + r16;
    const float s = bnd1[row] * rsqrtf(bnd1[3*DM+row] + EPS);
    #pragma unroll
    for (int j=0;j<8;j++){
      const int k = kg + j;
      o8[j] = (k < 3) ? f2bf(s * Wd1[row*3 + k]) : (unsigned short)0;
    }
  } else if (f < 120){
    const int fp = f - 104;
    const int tt = fp >> 1, ks = fp & 1;
    const int row = tt*16 + r16;
    const float s = bn1[row] * rsqrtf(bn1[3*DM+row] + EPS);
    const float* src = W1 + (size_t)row*DP + ks*32 + kg;
    #pragma unroll
    for (int j=0;j<8;j++) o8[j] = f2bf(s * src[j]);
  } else {
    const int fp = f - 120;
    const float* W = (fp < 32) ? Wq : (fp < 64 ? Wk : Wv);
    const int r = fp & 31, tt = r >> 2, ks = r & 3;
    const int row = tt*16 + r16;
    const float* src = W + (size_t)row*DM + ks*32 + kg;
    #pragma unroll
    for (int j=0;j<8;j++) o8[j] = f2bf(src[j]);
  }
  uint4 v;
  v.x = (uint32_t)o8[0] | ((uint32_t)o8[1]<<16);
  v.y = (uint32_t)o8[2] | ((uint32_t)o8[3]<<16);
  v.z = (uint32_t)o8[4] | ((uint32_t)o8[5]<<16);
  v.w = (uint32_t)o8[6] | ((uint32_t)o8[7]<<16);
  *reinterpret_cast<uint4*>(wfrag + (size_t)i*8) = v;
}

// ---------------------------------------------------------------- common frag/LDS macros
#define FRG(fi) (*reinterpret_cast<const bf16x8*>(&wfrag[(size_t)(fi)*512 + l*8]))

#define RD_B() \
  const bf16x8 b0 = *reinterpret_cast<const bf16x8*>(&hb[p*128 + ((0*4+g)^p)*8]); \
  const bf16x8 b1 = *reinterpret_cast<const bf16x8*>(&hb[p*128 + ((1*4+g)^p)*8]); \
  const bf16x8 b2 = *reinterpret_cast<const bf16x8*>(&hb[p*128 + ((2*4+g)^p)*8]); \
  const bf16x8 b3 = *reinterpret_cast<const bf16x8*>(&hb[p*128 + ((3*4+g)^p)*8]);

// ---------------------------------------------------------------- x -> q,k,v via MFMA (wave = 16 points)
#define X_STEP(tt) { \
  f32x4 acc = {0.f,0.f,0.f,0.f}; \
  acc = mfma16(FRG(104+(tt)*2+0), f00, acc); \
  acc = mfma16(FRG(104+(tt)*2+1), f10, acc); \
  acc = mfma16(FRG(104+(tt)*2+0), f01, acc); \
  acc = mfma16(FRG(104+(tt)*2+1), f11, acc); \
  const f32x4 sh = *reinterpret_cast<const f32x4*>(&bnT1[(tt)*16 + g*4]); \
  uint2 hp; \
  hp.x = pk2(lrelu(acc[0]+sh[0]), lrelu(acc[1]+sh[1])); \
  hp.y = pk2(lrelu(acc[2]+sh[2]), lrelu(acc[3]+sh[3])); \
  *reinterpret_cast<uint2*>(&hb[hwb + (((tt)*2 + (g>>1))^p)*8]) = hp; }

#define QKV_STEP(tt, base, OUT) { \
  f32x4 acc = {0.f,0.f,0.f,0.f}; \
  acc = mfma16(FRG((base)+(tt)*4+0), b0, acc); \
  acc = mfma16(FRG((base)+(tt)*4+1), b1, acc); \
  acc = mfma16(FRG((base)+(tt)*4+2), b2, acc); \
  acc = mfma16(FRG((base)+(tt)*4+3), b3, acc); \
  uint2 st; \
  st.x = pk2(acc[0], acc[1]); \
  st.y = pk2(acc[2], acc[3]); \
  *reinterpret_cast<uint2*>(&OUT[(size_t)(pt)*DM + (tt)*16 + g*4]) = st; }

__global__ __launch_bounds__(256) void k_xqkv2(const unsigned short* __restrict__ qfrag,
                                               const unsigned short* __restrict__ wfrag,
                                               const float* __restrict__ bn1,
                                               unsigned short* __restrict__ qbf,
                                               unsigned short* __restrict__ kbf,
                                               unsigned short* __restrict__ vbf){
  __shared__ __align__(16) unsigned short Hb[4][2048];
  __shared__ float bnT1[DM];
  const int t = threadIdx.x;
  if (t < DM){
    const float s = bn1[t] * rsqrtf(bn1[3*DM+t] + EPS);
    bnT1[t] = bn1[DM+t] - bn1[2*DM+t]*s;
  }
  __syncthreads();

  const int w = t >> 6, l = t & 63;
  const int p = l & 15, g = l >> 4;
  unsigned short* hb = Hb[w];
  const int hwb = p*128 + ((g & 1) * 4);

  const int ntg = blockIdx.x*4 + w;
  const int b = ntg >> 8, nt = ntg & 255;
  const int pt = b*NN + nt*16 + p;

  const unsigned short* qb = qfrag + ((size_t)(b*256 + nt))*2048 + l*8;
  const bf16x8 f00 = *reinterpret_cast<const bf16x8*>(qb);
  const bf16x8 f01 = *reinterpret_cast<const bf16x8*>(qb + 512);
  const bf16x8 f10 = *reinterpret_cast<const bf16x8*>(qb + 1024);
  const bf16x8 f11 = *reinterpret_cast<const bf16x8*>(qb + 1536);

  X_STEP(0) X_STEP(1) X_STEP(2) X_STEP(3)
  X_STEP(4) X_STEP(5) X_STEP(6) X_STEP(7)

  RD_B()
  QKV_STEP(0, 120, qbf) QKV_STEP(1, 120, qbf) QKV_STEP(2, 120, qbf) QKV_STEP(3, 120, qbf)
  QKV_STEP(4, 120, qbf) QKV_STEP(5, 120, qbf) QKV_STEP(6, 120, qbf) QKV_STEP(7, 120, qbf)
  QKV_STEP(0, 152, kbf) QKV_STEP(1, 152, kbf) QKV_STEP(2, 152, kbf) QKV_STEP(3, 152, kbf)
  QKV_STEP(4, 152, kbf) QKV_STEP(5, 152, kbf) QKV_STEP(6, 152, kbf) QKV_STEP(7, 152, kbf)
  QKV_STEP(0, 184, vbf) QKV_STEP(1, 184, vbf) QKV_STEP(2, 184, vbf) QKV_STEP(3, 184, vbf)
  QKV_STEP(4, 184, vbf) QKV_STEP(5, 184, vbf) QKV_STEP(6, 184, vbf) QKV_STEP(7, 184, vbf)
}

// ---------------------------------------------------------------- fused attention (pe + attn, no intermediate images)
#define H1_STEP(tt) { \
  f32x4 acc = {0.f,0.f,0.f,0.f}; \
  acc = mfma16(FRG(96+(tt)), bv, acc); \
  const f32x4 sh = *reinterpret_cast<const f32x4*>(&bnT[0][(tt)*16 + g*4]); \
  uint2 hp; \
  hp.x = pk2(lrelu(acc[0]+sh[0]), lrelu(acc[1]+sh[1])); \
  hp.y = pk2(lrelu(acc[2]+sh[2]), lrelu(acc[3]+sh[3])); \
  *reinterpret_cast<uint2*>(&hb[hwb + (((tt)*2 + (g>>1))^p)*8]) = hp; }

#define PE_STEP(tt, PE) { \
  f32x4 acc = {0.f,0.f,0.f,0.f}; \
  acc = mfma16(FRG(0+(tt)*4+0), b0, acc); \
  acc = mfma16(FRG(0+(tt)*4+1), b1, acc); \
  acc = mfma16(FRG(0+(tt)*4+2), b2, acc); \
  acc = mfma16(FRG(0+(tt)*4+3), b3, acc); \
  const f32x4 sh = *reinterpret_cast<const f32x4*>(&bnT[1][(tt)*16 + g*4]); \
  PE[0]=lrelu(acc[0]+sh[0]); PE[1]=lrelu(acc[1]+sh[1]); \
  PE[2]=lrelu(acc[2]+sh[2]); PE[3]=lrelu(acc[3]+sh[3]); }

#define VPER_STEP(tt, PE, VPE) { \
  const uint2 du = *reinterpret_cast<const uint2*>(&hb[p*128 + (((tt)*2+(g>>1))^p)*8 + (g&1)*4]); \
  VPE[0] = bfl(du.x)+PE[0]; VPE[1] = bfh(du.x)+PE[1]; \
  VPE[2] = bfl(du.y)+PE[2]; VPE[3] = bfh(du.y)+PE[3]; }

#define QPE_STEP(tt, PE) { \
  const uint2 qu = *reinterpret_cast<const uint2*>(&qbf[(size_t)gp*DM + (tt)*16 + g*4]); \
  uint2 hp; \
  hp.x = pk2(bfl(qu.x)+PE[0], bfh(qu.x)+PE[1]); \
  hp.y = pk2(bfl(qu.y)+PE[2], bfh(qu.y)+PE[3]); \
  *reinterpret_cast<uint2*>(&hb[hwb + (((tt)*2 + (g>>1))^p)*8]) = hp; }

#define G1A_STEP(tt) { \
  f32x4 acc = {0.f,0.f,0.f,0.f}; \
  acc = mfma16(FRG(32+(tt)*4+0), ai0, acc); \
  acc = mfma16(FRG(32+(tt)*4+1), ai1, acc); \
  acc = mfma16(FRG(32+(tt)*4+2), ai2, acc); \
  acc = mfma16(FRG(32+(tt)*4+3), ai3, acc); \
  const f32x4 sh = *reinterpret_cast<const f32x4*>(&bnT[2][(tt)*16 + g*4]); \
  uint2 hp; \
  hp.x = pk2(lrelu(acc[0]+sh[0]), lrelu(acc[1]+sh[1])); \
  hp.y = pk2(lrelu(acc[2]+sh[2]), lrelu(acc[3]+sh[3])); \
  *reinterpret_cast<uint2*>(&hb[hwb + (((tt)*2 + (g>>1))^p)*8]) = hp; }

#define E_STEP(tt, E) { \
  f32x4 acc = {0.f,0.f,0.f,0.f}; \
  acc = mfma16(FRG(64+(tt)*4+0), b0, acc); \
  acc = mfma16(FRG(64+(tt)*4+1), b1, acc); \
  acc = mfma16(FRG(64+(tt)*4+2), b2, acc); \
  acc = mfma16(FRG(64+(tt)*4+3), b3, acc); \
  const f32x4 sh = *reinterpret_cast<const f32x4*>(&bnT[3][(tt)*16 + g*4]); \
  E[0]=lrelu(acc[0]+sh[0])*0.015625f; E[1]=lrelu(acc[1]+sh[1])*0.015625f; \
  E[2]=lrelu(acc[2]+sh[2])*0.015625f; E[3]=lrelu(acc[3]+sh[3])*0.015625f; }

// exp without safe-max: logits are lrelu(bn(.))/64, |logit| small -> no overflow risk
#define EXP0_STEP(E) { \
  E[0]=__expf(E[0]); E[1]=__expf(E[1]); E[2]=__expf(E[2]); E[3]=__expf(E[3]); }

#define REDF_STEP(tt, E, VPE) { \
  const float o0 = redh(E[0]*VPE[0], E[0]); \
  const float o1 = redh(E[1]*VPE[1], E[1]); \
  const float o2 = redh(E[2]*VPE[2], E[2]); \
  const float o3 = redh(E[3]*VPE[3], E[3]); \
  if (p == 0){ \
    uint2 st; st.x = pk2(o0,o1); st.y = pk2(o2,o3); \
    *reinterpret_cast<uint2*>(&resbf[(size_t)gp*DM + (tt)*16 + g*4]) = st; } }

__global__ __launch_bounds__(256, 2) void k_fa(
    const float* __restrict__ pos, const unsigned short* __restrict__ qbf,
    const unsigned short* __restrict__ kbf, const unsigned short* __restrict__ vbf,
    const int* __restrict__ idx_ws, const unsigned short* __restrict__ wfrag,
    const float* __restrict__ bnd1, const float* __restrict__ bnd2,
    const float* __restrict__ bng1, const float* __restrict__ bng2,
    unsigned short* __restrict__ resbf){
  __shared__ __align__(16) unsigned short Hb[4][2048];
  __shared__ float bnT[4][DM];

  const int t = threadIdx.x;
  if (t < DM){
    const float* bp[4] = {bnd1, bnd2, bng1, bng2};
    #pragma unroll
    for (int s4=0;s4<4;s4++){
      const float g = bp[s4][t], be = bp[s4][DM+t], mn = bp[s4][2*DM+t], vr = bp[s4][3*DM+t];
      const float sc = g * rsqrtf(vr + EPS);
      bnT[s4][t] = be - mn*sc;
    }
  }
  __syncthreads();

  const int w = t >> 6, l = t & 63;
  const int p = l & 15, g = l >> 4;
  unsigned short* hb = Hb[w];
  const int hwb = p*128 + ((g & 1) * 4);

  const int gp = blockIdx.x*4 + w;
  const int b = gp >> 12, n = gp & (NN-1);
  const int mi = idx_ws[gp*KK + p];

  uint32_t bw0 = 0u, bw1 = 0u;
  if (g == 0){
    const float* posb = pos + (size_t)b*3*NN;
    const float rx = posb[n]      - posb[mi];
    const float ry = posb[NN+n]   - posb[NN+mi];
    const float rz = posb[2*NN+n] - posb[2*NN+mi];
    bw0 = pk2(rx, ry);
    bw1 = pk2(rz, 0.f);
  }
  u32x4 bwv = {bw0, bw1, 0u, 0u};
  const bf16x8 bv = __builtin_bit_cast(bf16x8, bwv);

  H1_STEP(0) H1_STEP(1) H1_STEP(2) H1_STEP(3)
  H1_STEP(4) H1_STEP(5) H1_STEP(6) H1_STEP(7)

  f32x4 pe0, pe1, pe2, pe3, pe4, pe5, pe6, pe7;
  {
    RD_B()
    PE_STEP(0, pe0) PE_STEP(1, pe1) PE_STEP(2, pe2) PE_STEP(3, pe3)
    PE_STEP(4, pe4) PE_STEP(5, pe5) PE_STEP(6, pe6) PE_STEP(7, pe7)
  }

  f32x4 vp0, vp1, vp2, vp3, vp4, vp5, vp6, vp7;
  {
    const unsigned short* vrow = vbf + ((size_t)(b*NN) + mi)*DM;
    const bf16x8 xv0 = *reinterpret_cast<const bf16x8*>(&vrow[ 0 + g*8]);
    const bf16x8 xv1 = *reinterpret_cast<const bf16x8*>(&vrow[32 + g*8]);
    const bf16x8 xv2 = *reinterpret_cast<const bf16x8*>(&vrow[64 + g*8]);
    const bf16x8 xv3 = *reinterpret_cast<const bf16x8*>(&vrow[96 + g*8]);
    *reinterpret_cast<bf16x8*>(&hb[p*128 + ((0*4+g)^p)*8]) = xv0;
    *reinterpret_cast<bf16x8*>(&hb[p*128 + ((1*4+g)^p)*8]) = xv1;
    *reinterpret_cast<bf16x8*>(&hb[p*128 + ((2*4+g)^p)*8]) = xv2;
    *reinterpret_cast<bf16x8*>(&hb[p*128 + ((3*4+g)^p)*8]) = xv3;
    VPER_STEP(0, pe0, vp0) VPER_STEP(1, pe1, vp1) VPER_STEP(2, pe2, vp2) VPER_STEP(3, pe3, vp3)
    VPER_STEP(4, pe4, vp4) VPER_STEP(5, pe5, vp5) VPER_STEP(6, pe6, vp6) VPER_STEP(7, pe7, vp7)
  }

  QPE_STEP(0, pe0) QPE_STEP(1, pe1) QPE_STEP(2, pe2) QPE_STEP(3, pe3)
  QPE_STEP(4, pe4) QPE_STEP(5, pe5) QPE_STEP(6, pe6) QPE_STEP(7, pe7)

  {
    const unsigned short* krow = kbf + ((size_t)(b*NN) + mi)*DM;
    const bf16x8 xk0 = *reinterpret_cast<const bf16x8*>(&krow[ 0 + g*8]);
    const bf16x8 xk1 = *reinterpret_cast<const bf16x8*>(&krow[32 + g*8]);
    const bf16x8 xk2 = *reinterpret_cast<const bf16x8*>(&krow[64 + g*8]);
    const bf16x8 xk3 = *reinterpret_cast<const bf16x8*>(&krow[96 + g*8]);
    RD_B()
    const bf16x8 ai0 = __builtin_bit_cast(bf16x8, sub8(__builtin_bit_cast(u32x4, b0), __builtin_bit_cast(u32x4, xk0)));
    const bf16x8 ai1 = __builtin_bit_cast(bf16x8, sub8(__builtin_bit_cast(u32x4, b1), __builtin_bit_cast(u32x4, xk1)));
    const bf16x8 ai2 = __builtin_bit_cast(bf16x8, sub8(__builtin_bit_cast(u32x4, b2), __builtin_bit_cast(u32x4, xk2)));
    const bf16x8 ai3 = __builtin_bit_cast(bf16x8, sub8(__builtin_bit_cast(u32x4, b3), __builtin_bit_cast(u32x4, xk3)));
    G1A_STEP(0) G1A_STEP(1) G1A_STEP(2) G1A_STEP(3)
    G1A_STEP(4) G1A_STEP(5) G1A_STEP(6) G1A_STEP(7)
  }

  f32x4 e0, e1, e2, e3, e4, e5, e6, e7;
  {
    RD_B()
    E_STEP(0, e0) E_STEP(1, e1) E_STEP(2, e2) E_STEP(3, e3)
    E_STEP(4, e4) E_STEP(5, e5) E_STEP(6, e6) E_STEP(7, e7)
  }

  EXP0_STEP(e0) EXP0_STEP(e1) EXP0_STEP(e2) EXP0_STEP(e3)
  EXP0_STEP(e4) EXP0_STEP(e5) EXP0_STEP(e6) EXP0_STEP(e7)

  REDF_STEP(0, e0, vp0) REDF_STEP(1, e1, vp1) REDF_STEP(2, e2, vp2) REDF_STEP(3, e3, vp3)
  REDF_STEP(4, e4, vp4) REDF_STEP(5, e5, vp5) REDF_STEP(6, e6, vp6) REDF_STEP(7, e7, vp7)
}

// ---------------------------------------------------------------- out = lrelu(bn2(W2@res)) + feats  (res is bf16)
__global__ __launch_bounds__(256, 1) void k_out(const unsigned short* __restrict__ resbf,
                                             const float* __restrict__ W2,
                                             const float* __restrict__ bn2,
                                             const float* __restrict__ feats,
                                             float* __restrict__ out){
  __shared__ float W2s[DP][DM+4];
  __shared__ float rt[128][DM+4];
  __shared__ float ob[DP][132];
  __shared__ float bS[DP], bT[DP];
  const int t = threadIdx.x;
  const int b = blockIdx.x >> 5;
  const int n0 = (blockIdx.x & 31) * 128;
  for (int i=t; i<DP*DM; i+=256){ W2s[i>>7][i&127] = W2[i]; }
  if (t < DP){
    float g=bn2[t], be=bn2[DP+t], mn=bn2[2*DP+t], vr=bn2[3*DP+t];
    float s = g*rsqrtf(vr+EPS); bS[t]=s; bT[t]=be-mn*s;
  }
  for (int i=t; i<128*(DM/4); i+=256){
    const int j=i>>5, c4=(i&31)*4;
    const ushort4 u = *reinterpret_cast<const ushort4*>(&resbf[((size_t)(b*NN)+n0+j)*DM + c4]);
    rt[j][c4+0] = bf2f(u.x); rt[j][c4+1] = bf2f(u.y);
    rt[j][c4+2] = bf2f(u.z); rt[j][c4+3] = bf2f(u.w);
  }
  __syncthreads();
  const int j = t>>1, cq = t&1;
  float acc[32];
  #pragma unroll
  for (int i=0;i<32;i++) acc[i]=0.f;
  for (int c=0;c<DM;c+=4){
    const float4 rv = *reinterpret_cast<const float4*>(&rt[j][c]);
    #pragma unroll
    for (int i=0;i<32;i++){
      const float4 wv = *reinterpret_cast<const float4*>(&W2s[cq+2*i][c]);
      acc[i] += wv.x*rv.x + wv.y*rv.y + wv.z*rv.z + wv.w*rv.w;
    }
  }
  #pragma unroll
  for (int i=0;i<32;i++) ob[cq+2*i][j] = acc[i];
  __syncthreads();
  for (int i=t; i<DP*128; i+=256){
    const int ch=i>>7, jj=i&127;
    const size_t o = (size_t)b*DP*NN + (size_t)ch*NN + n0 + jj;
    out[o] = lrelu(ob[ch][jj]*bS[ch] + bT[ch]) + feats[o];
  }
}

// ----------------------------------------------------------------
extern "C" void kernel_launch(void* const* d_in, const int* in_sizes, int n_in,
                              void* d_out, int out_size, void* d_ws, size_t ws_size,
                              hipStream_t stream) {
  const float* feats = (const float*)d_in[0];
  const float* pos   = (const float*)d_in[1];
  const float* W1    = (const float*)d_in[2];
  const float* bn1   = (const float*)d_in[3];
  const float* W2    = (const float*)d_in[4];
  const float* bn2   = (const float*)d_in[5];
  const float* Wq    = (const float*)d_in[6];
  const float* Wk    = (const float*)d_in[7];
  const float* Wv    = (const float*)d_in[8];
  const float* Wd1   = (const float*)d_in[9];
  const float* bnd1  = (const float*)d_in[10];
  const float* Wd2   = (const float*)d_in[11];
  const float* bnd2  = (const float*)d_in[12];
  const float* Wg1   = (const float*)d_in[13];
  const float* bng1  = (const float*)d_in[14];
  const float* Wg2   = (const float*)d_in[15];
  const float* bng2  = (const float*)d_in[16];
  float* out = (float*)d_out;

  unsigned short* qbf = (unsigned short*)d_ws;              // 4 MiB
  unsigned short* kbf = qbf + 2097152;                      // 4 MiB
  unsigned short* vbf = kbf + 2097152;                      // 4 MiB
  float* sqn = (float*)(vbf + 2097152);                     // 64 KiB
  int*   idx = (int*)(sqn + 16384);                         // 1 MiB
  unsigned short* wfrag = (unsigned short*)(idx + 262144);  // 216 KiB
  unsigned short* poolu = wfrag + 110592;                   // 20 MiB pool
  // knn phase overlays
  float* fpm = (float*)poolu;                               // 4 MiB
  unsigned short* cfrag = (unsigned short*)(fpm + 1048576); // 4 MiB
  unsigned short* qfrag = cfrag + 2097152;                  // 4 MiB
  int* cand = (int*)(qfrag + 2097152);                      // 8 MiB (128/query)
  // post-refine overlay: res (bf16, 4 MiB) over fpm (dead after k_refine2)
  unsigned short* resbf = poolu;

  k_fprep  <<<NB*(NN/64), 256, 0, stream>>>(feats, cfrag, qfrag, fpm, sqn);
  k_knn5   <<<NB*512, 256, 0, stream>>>(cfrag, qfrag, sqn, cand);
  k_refine2<<<(NB*NN)/4, 256, 0, stream>>>(fpm, sqn, cand, idx);
  k_wprep2 <<<54, 256, 0, stream>>>(Wd1, bnd1, Wd2, bnd2, Wg1, bng1, Wg2, bng2,
                                    W1, bn1, Wq, Wk, Wv, wfrag);
  k_xqkv2  <<<NB*64, 256, 0, stream>>>(qfrag, wfrag, bn1, qbf, kbf, vbf);
  k_fa     <<<(NB*NN)/4, 256, 0, stream>>>(pos, qbf, kbf, vbf, idx, wfrag,
                                           bnd1, bnd2, bng1, bng2, resbf);
  k_out    <<<NB*(NN/128), 256, 0, stream>>>(resbf, W2, bn2, feats, out);
}

// Round 18
// 264.437 us; speedup vs baseline: 9.8524x; 1.2907x over previous
//
#include <hip/hip_runtime.h>
#include <hip/hip_fp16.h>
#include <cstdint>
#include <cstddef>

#define NB 4
#define NN 4096
#define KK 16
#define DP 64
#define DM 128
#define EPS 1e-5f

typedef __attribute__((ext_vector_type(8))) short bf16x8;
typedef __attribute__((ext_vector_type(4))) float f32x4;
typedef __attribute__((ext_vector_type(4))) unsigned int u32x4;

__device__ __forceinline__ float lrelu(float x){ return x >= 0.f ? x : 0.2f*x; }

__device__ __forceinline__ unsigned short f2bf(float x){
  union { float f; uint32_t u; } a; a.f = x;
  return (unsigned short)((a.u + 0x7fffu + ((a.u >> 16) & 1u)) >> 16);
}
__device__ __forceinline__ float bf2f(unsigned short h){
  union { uint32_t u; float f; } a; a.u = ((uint32_t)h) << 16; return a.f;
}
// HW packed f32x2 -> bf16x2 (lo = a, hi = b)
__device__ __forceinline__ uint32_t pk2(float a, float b){
  uint32_t r;
  asm("v_cvt_pk_bf16_f32 %0, %1, %2" : "=v"(r) : "v"(a), "v"(b));
  return r;
}
__device__ __forceinline__ float bfl(uint32_t w){ return __uint_as_float(w << 16); }
__device__ __forceinline__ float bfh(uint32_t w){ return __uint_as_float(w & 0xffff0000u); }

__device__ __forceinline__ f32x4 mfma16(bf16x8 a, bf16x8 b, f32x4 c){
  return __builtin_amdgcn_mfma_f32_16x16x32_bf16(a, b, c, 0, 0, 0);
}
__device__ __forceinline__ u32x4 sub8(u32x4 a, u32x4 k){
  u32x4 r;
  r[0] = pk2(bfl(a[0])-bfl(k[0]), bfh(a[0])-bfh(k[0]));
  r[1] = pk2(bfl(a[1])-bfl(k[1]), bfh(a[1])-bfh(k[1]));
  r[2] = pk2(bfl(a[2])-bfl(k[2]), bfh(a[2])-bfh(k[2]));
  r[3] = pk2(bfl(a[3])-bfl(k[3]), bfh(a[3])-bfh(k[3]));
  return r;
}
// packed (num|den) half2 reduce over 16 neighbor lanes via DPP row rotations
__device__ __forceinline__ float redh(float num, float den){
  __half2 nd = __floats2half2_rn(num, den);
  uint32_t u = __builtin_bit_cast(uint32_t, nd);
  uint32_t o;
  o = (uint32_t)__builtin_amdgcn_update_dpp(0, (int)u, 0x128, 0xf, 0xf, true);
  u = __builtin_bit_cast(uint32_t, __hadd2(__builtin_bit_cast(__half2,u), __builtin_bit_cast(__half2,o)));
  o = (uint32_t)__builtin_amdgcn_update_dpp(0, (int)u, 0x124, 0xf, 0xf, true);
  u = __builtin_bit_cast(uint32_t, __hadd2(__builtin_bit_cast(__half2,u), __builtin_bit_cast(__half2,o)));
  o = (uint32_t)__builtin_amdgcn_update_dpp(0, (int)u, 0x122, 0xf, 0xf, true);
  u = __builtin_bit_cast(uint32_t, __hadd2(__builtin_bit_cast(__half2,u), __builtin_bit_cast(__half2,o)));
  o = (uint32_t)__builtin_amdgcn_update_dpp(0, (int)u, 0x121, 0xf, 0xf, true);
  u = __builtin_bit_cast(uint32_t, __hadd2(__builtin_bit_cast(__half2,u), __builtin_bit_cast(__half2,o)));
  const __half2 r = __builtin_bit_cast(__half2, u);
  return __low2float(r) * __builtin_amdgcn_rcpf(__high2float(r));
}

// ---------------------------------------------------------------- feats -> bf16 hi/lo MFMA fragments + fpm + sqn (fused)
__global__ __launch_bounds__(256) void k_fprep(const float* __restrict__ feats,
                                               unsigned short* __restrict__ cfrag,
                                               unsigned short* __restrict__ qfrag,
                                               float* __restrict__ fpm,
                                               float* __restrict__ sqn){
  __shared__ float ft[DP][65];
  const int t = threadIdx.x;
  const int b = blockIdx.x >> 6;
  const int n0 = (blockIdx.x & 63) * 64;
  for (int i=t; i<DP*64; i+=256){
    const int dim = i >> 6, pt = i & 63;
    ft[dim][pt] = feats[(size_t)b*DP*NN + (size_t)dim*NN + n0 + pt];
  }
  __syncthreads();
  if (t < 64){
    float s = 0.f;
    #pragma unroll
    for (int d=0; d<DP; d++){ const float v = ft[d][t]; s += v*v; }
    sqn[b*NN + n0 + t] = s;
  }
  for (int i=t; i<64*DP; i+=256){
    const int pt = i >> 6, dim = i & 63;
    fpm[((size_t)(b*NN) + n0 + pt)*DP + dim] = ft[dim][pt];
  }
  #pragma unroll
  for (int v = t; v < 1024; v += 256){
    const int l = v & 63, hl = (v>>6)&1, ks = (v>>7)&1, ntl = v>>8;
    const int ptl = ntl*16 + (l&15);
    const int d0 = ks*32 + (l>>4)*8;
    unsigned short qo[8], co[8];
    #pragma unroll
    for (int j=0;j<8;j++){
      const float x = ft[d0+j][ptl];
      const unsigned short qh = f2bf(x);
      const float y = -2.f*x;
      const unsigned short ch = f2bf(y);
      qo[j] = hl ? f2bf(x - bf2f(qh)) : qh;
      co[j] = hl ? f2bf(y - bf2f(ch)) : ch;
    }
    const int nt = (n0 >> 4) + ntl;
    const size_t off = ((size_t)((b*256 + nt)*4 + ks*2 + hl))*512 + l*8;
    uint4 qv, cv;
    qv.x = (uint32_t)qo[0] | ((uint32_t)qo[1]<<16);
    qv.y = (uint32_t)qo[2] | ((uint32_t)qo[3]<<16);
    qv.z = (uint32_t)qo[4] | ((uint32_t)qo[5]<<16);
    qv.w = (uint32_t)qo[6] | ((uint32_t)qo[7]<<16);
    cv.x = (uint32_t)co[0] | ((uint32_t)co[1]<<16);
    cv.y = (uint32_t)co[2] | ((uint32_t)co[3]<<16);
    cv.z = (uint32_t)co[4] | ((uint32_t)co[5]<<16);
    cv.w = (uint32_t)co[6] | ((uint32_t)co[7]<<16);
    *reinterpret_cast<uint4*>(qfrag + off) = qv;
    *reinterpret_cast<uint4*>(cfrag + off) = cv;
  }
}

// ---------------------------------------------------------------- MFMA kNN v5: (query-tile, eighth) per wave, writes packed (dist|idx)
__global__ __launch_bounds__(256, 4) void k_knn5(const unsigned short* __restrict__ cfrag,
                                                 const unsigned short* __restrict__ qfrag,
                                                 const float* __restrict__ sqn,
                                                 uint32_t* __restrict__ cand){
  const int t = threadIdx.x, w = t >> 6, l = t & 63, g = l >> 4;
  const int b = blockIdx.x >> 9;
  const int combo = (blockIdx.x & 511)*4 + w;
  const int qt = combo >> 3, eighth = combo & 7;
  const int ct0 = eighth * 32;

  bf16x8 qf00, qf01, qf10, qf11;
  {
    const unsigned short* qb = qfrag + ((size_t)(b*256 + qt))*2048 + l*8;
    qf00 = *reinterpret_cast<const bf16x8*>(qb);
    qf01 = *reinterpret_cast<const bf16x8*>(qb + 512);
    qf10 = *reinterpret_cast<const bf16x8*>(qb + 1024);
    qf11 = *reinterpret_cast<const bf16x8*>(qb + 1536);
  }
  const unsigned short* cb = cfrag + ((size_t)(b*256))*2048 + l*8;
  const float sqq = sqn[b*NN + qt*16 + (l & 15)];

  uint32_t kk[16];
  #pragma unroll
  for (int s=0;s<16;s++) kk[s] = 0xFFFFFFFFu;

  bf16x8 c00 = *reinterpret_cast<const bf16x8*>(cb + (size_t)ct0*2048);
  bf16x8 c01 = *reinterpret_cast<const bf16x8*>(cb + (size_t)ct0*2048 + 512);
  bf16x8 c10 = *reinterpret_cast<const bf16x8*>(cb + (size_t)ct0*2048 + 1024);
  bf16x8 c11 = *reinterpret_cast<const bf16x8*>(cb + (size_t)ct0*2048 + 1536);

  const float* sqb = sqn + b*NN + g*4;

  #pragma unroll 1
  for (int it=0; it<32; ++it){
    const int ct = ct0 + it;
    bf16x8 n00, n01, n10, n11;
    if (it < 31){
      const unsigned short* nb_ = cb + (size_t)(ct+1)*2048;
      n00 = *reinterpret_cast<const bf16x8*>(nb_);
      n01 = *reinterpret_cast<const bf16x8*>(nb_ + 512);
      n10 = *reinterpret_cast<const bf16x8*>(nb_ + 1024);
      n11 = *reinterpret_cast<const bf16x8*>(nb_ + 1536);
    }
    f32x4 acc = {0.f,0.f,0.f,0.f};
    acc = mfma16(c00, qf00, acc);
    acc = mfma16(c10, qf10, acc);
    acc = mfma16(c00, qf01, acc);
    acc = mfma16(c01, qf00, acc);
    acc = mfma16(c10, qf11, acc);
    acc = mfma16(c11, qf10, acc);
    const float4 sq4 = *reinterpret_cast<const float4*>(&sqb[ct*16]);
    const int cbase = ct*16 + g*4;
    uint32_t pv[4];
    pv[0] = (__float_as_uint(fmaxf(acc[0]+sq4.x+sqq, 0.f)) & 0xFFFFF000u) | (cbase+0);
    pv[1] = (__float_as_uint(fmaxf(acc[1]+sq4.y+sqq, 0.f)) & 0xFFFFF000u) | (cbase+1);
    pv[2] = (__float_as_uint(fmaxf(acc[2]+sq4.z+sqq, 0.f)) & 0xFFFFF000u) | (cbase+2);
    pv[3] = (__float_as_uint(fmaxf(acc[3]+sq4.w+sqq, 0.f)) & 0xFFFFF000u) | (cbase+3);
    const uint32_t mn = min(min(pv[0],pv[1]), min(pv[2],pv[3]));
    if (mn < kk[15]){
      #pragma unroll
      for (int u=0;u<4;u++){
        uint32_t v = pv[u];
        if (v < kk[15]){
          #pragma unroll
          for (int s=0;s<16;s++){
            const uint32_t hi = max(kk[s], v);
            kk[s] = min(kk[s], v);
            v = hi;
          }
        }
      }
    }
    c00 = n00; c01 = n01; c10 = n10; c11 = n11;
  }

  const int q = qt*16 + (l & 15);
  uint32_t* op = cand + ((size_t)(b*NN) + q)*128 + eighth*16;
  #pragma unroll 1
  for (int r=0; r<KK; ++r){
    uint32_t bm = kk[0];
    uint32_t om;
    om = __shfl_xor((int)bm, 16); bm = min(bm, om);
    om = __shfl_xor((int)bm, 32); bm = min(bm, om);
    if (kk[0] == bm){
      #pragma unroll
      for (int s=0;s<15;s++) kk[s] = kk[s+1];
      kk[15] = 0xFFFFFFFFu;
    }
    if (g == 0) op[r] = bm;     // packed (dist|idx)
  }
}

// ---------------------------------------------------------------- refine v3: approx pre-sort (shfl-only) -> exact dots on top-32
__global__ __launch_bounds__(256) void k_refine3(const float* __restrict__ fpm,
                                                 const float* __restrict__ sqn,
                                                 const uint32_t* __restrict__ cand,
                                                 int* __restrict__ idx_ws){
  const int t = threadIdx.x, w = t >> 6, l = t & 63;
  const int q = blockIdx.x*4 + w;
  const int b = q >> 12;

  // --- bitonic sort 128 packed u32 approx keys (no gathers)
  uint32_t v0 = cand[(size_t)q*128 + l];
  uint32_t v1 = cand[(size_t)q*128 + 64 + l];
  #pragma unroll
  for (int k = 2; k <= 64; k <<= 1){
    #pragma unroll
    for (int j = k>>1; j >= 1; j >>= 1){
      const bool lp  = (l & j) == 0;
      const bool tm0 = ((l & k) == 0) == lp;
      const bool tm1 = (((l + 64) & k) == 0) == lp;
      const uint32_t p0 = (uint32_t)__shfl_xor((int)v0, j);
      const uint32_t p1 = (uint32_t)__shfl_xor((int)v1, j);
      v0 = tm0 ? min(v0,p0) : max(v0,p0);
      v1 = tm1 ? min(v1,p1) : max(v1,p1);
    }
  }
  {
    const uint32_t lo = min(v0,v1), hi = max(v0,v1);
    v0 = lo; v1 = hi;
  }
  #pragma unroll
  for (int j = 32; j >= 1; j >>= 1){
    const bool tm = (l & j) == 0;
    const uint32_t p0 = (uint32_t)__shfl_xor((int)v0, j);
    const uint32_t p1 = (uint32_t)__shfl_xor((int)v1, j);
    v0 = tm ? min(v0,p0) : max(v0,p0);
    v1 = tm ? min(v1,p1) : max(v1,p1);
  }
  // v0 on lane r = approx rank r. top-32 = lanes 0..31.

  // --- exact f32 distance for top-32, 2 lanes per candidate (half-row each)
  const uint32_t pk = (uint32_t)__shfl((int)v0, (l >> 1));
  const int mi = (int)(pk & 0xFFFu);
  const int h = l & 1;
  const float* qv = fpm + (size_t)q*DP + h*32;
  const float* cv = fpm + ((size_t)(b*NN) + mi)*DP + h*32;
  float dot = 0.f;
  #pragma unroll
  for (int d=0; d<32; d+=4){
    const float4 a = *reinterpret_cast<const float4*>(&qv[d]);
    const float4 x = *reinterpret_cast<const float4*>(&cv[d]);
    dot += a.x*x.x + a.y*x.y + a.z*x.z + a.w*x.w;
  }
  dot += __shfl_xor(dot, 1);
  const float dist = fmaxf(sqn[q] + sqn[b*NN + mi] - 2.f*dot, 0.f);
  const unsigned long long v = ((unsigned long long)__float_as_uint(dist) << 32) | (unsigned)mi;

  // --- exact top-16 SET via rank count over the 32 distinct candidates
  // (each candidate duplicated on a lane pair; uniform-lane shuffles = readlane)
  int rank = 0;
  #pragma unroll
  for (int j=0; j<32; j++){
    const unsigned long long vj = __shfl(v, 2*j);
    rank += (vj < v) ? 1 : 0;
  }
  if (h == 0 && rank < KK) idx_ws[(size_t)q*KK + rank] = mi;
}

// ---------------------------------------------------------------- weight prep v2: 216 bf16 MFMA fragments
__global__ __launch_bounds__(256) void k_wprep2(
    const float* __restrict__ Wd1, const float* __restrict__ bnd1,
    const float* __restrict__ Wd2, const float* __restrict__ bnd2,
    const float* __restrict__ Wg1, const float* __restrict__ bng1,
    const float* __restrict__ Wg2, const float* __restrict__ bng2,
    const float* __restrict__ W1, const float* __restrict__ bn1,
    const float* __restrict__ Wq, const float* __restrict__ Wk,
    const float* __restrict__ Wv,
    unsigned short* __restrict__ wfrag){
  const int i = blockIdx.x*256 + threadIdx.x;
  if (i >= 216*64) return;
  const int f = i >> 6, l = i & 63;
  const int r16 = l & 15, kg = (l >> 4) * 8;
  unsigned short o8[8];
  if (f < 96){
    const int mat = f >> 5, tt = (f >> 2) & 7, ks = f & 3;
    const float* W; const float* bn;
    if (mat == 0){ W = Wd2; bn = bnd2; }
    else if (mat == 1){ W = Wg1; bn = bng1; }
    else { W = Wg2; bn = bng2; }
    const int row = tt*16 + r16;
    const float s = bn[row] * rsqrtf(bn[3*DM+row] + EPS);
    const float* src = W + (size_t)row*DM + ks*32 + kg;
    #pragma unroll
    for (int j=0;j<8;j++) o8[j] = f2bf(s * src[j]);
  } else if (f < 104){
    const int tt = f - 96;
    const int row = tt*16 + r16;
    const float s = bnd1[row] * rsqrtf(bnd1[3*DM+row] + EPS);
    #pragma unroll
    for (int j=0;j<8;j++){
      const int k = kg + j;
      o8[j] = (k < 3) ? f2bf(s * Wd1[row*3 + k]) : (unsigned short)0;
    }
  } else if (f < 120){
    const int fp = f - 104;
    const int tt = fp >> 1, ks = fp & 1;
    const int row = tt*16 + r16;
    const float s = bn1[row] * rsqrtf(bn1[3*DM+row] + EPS);
    const float* src = W1 + (size_t)row*DP + ks*32 + kg;
    #pragma unroll
    for (int j=0;j<8;j++) o8[j] = f2bf(s * src[j]);
  } else {
    const int fp = f - 120;
    const float* W = (fp < 32) ? Wq : (fp < 64 ? Wk : Wv);
    const int r = fp & 31, tt = r >> 2, ks = r & 3;
    const int row = tt*16 + r16;
    const float* src = W + (size_t)row*DM + ks*32 + kg;
    #pragma unroll
    for (int j=0;j<8;j++) o8[j] = f2bf(src[j]);
  }
  uint4 v;
  v.x = (uint32_t)o8[0] | ((uint32_t)o8[1]<<16);
  v.y = (uint32_t)o8[2] | ((uint32_t)o8[3]<<16);
  v.z = (uint32_t)o8[4] | ((uint32_t)o8[5]<<16);
  v.w = (uint32_t)o8[6] | ((uint32_t)o8[7]<<16);
  *reinterpret_cast<uint4*>(wfrag + (size_t)i*8) = v;
}

// ---------------------------------------------------------------- common frag/LDS macros
#define FRG(fi) (*reinterpret_cast<const bf16x8*>(&wfrag[(size_t)(fi)*512 + l*8]))

#define RD_B() \
  const bf16x8 b0 = *reinterpret_cast<const bf16x8*>(&hb[p*128 + ((0*4+g)^p)*8]); \
  const bf16x8 b1 = *reinterpret_cast<const bf16x8*>(&hb[p*128 + ((1*4+g)^p)*8]); \
  const bf16x8 b2 = *reinterpret_cast<const bf16x8*>(&hb[p*128 + ((2*4+g)^p)*8]); \
  const bf16x8 b3 = *reinterpret_cast<const bf16x8*>(&hb[p*128 + ((3*4+g)^p)*8]);

// ---------------------------------------------------------------- x -> q,k,v via MFMA (wave = 16 points)
#define X_STEP(tt) { \
  f32x4 acc = {0.f,0.f,0.f,0.f}; \
  acc = mfma16(FRG(104+(tt)*2+0), f00, acc); \
  acc = mfma16(FRG(104+(tt)*2+1), f10, acc); \
  acc = mfma16(FRG(104+(tt)*2+0), f01, acc); \
  acc = mfma16(FRG(104+(tt)*2+1), f11, acc); \
  const f32x4 sh = *reinterpret_cast<const f32x4*>(&bnT1[(tt)*16 + g*4]); \
  uint2 hp; \
  hp.x = pk2(lrelu(acc[0]+sh[0]), lrelu(acc[1]+sh[1])); \
  hp.y = pk2(lrelu(acc[2]+sh[2]), lrelu(acc[3]+sh[3])); \
  *reinterpret_cast<uint2*>(&hb[hwb + (((tt)*2 + (g>>1))^p)*8]) = hp; }

#define QKV_STEP(tt, base, OUT) { \
  f32x4 acc = {0.f,0.f,0.f,0.f}; \
  acc = mfma16(FRG((base)+(tt)*4+0), b0, acc); \
  acc = mfma16(FRG((base)+(tt)*4+1), b1, acc); \
  acc = mfma16(FRG((base)+(tt)*4+2), b2, acc); \
  acc = mfma16(FRG((base)+(tt)*4+3), b3, acc); \
  uint2 st; \
  st.x = pk2(acc[0], acc[1]); \
  st.y = pk2(acc[2], acc[3]); \
  *reinterpret_cast<uint2*>(&OUT[(size_t)(pt)*DM + (tt)*16 + g*4]) = st; }

__global__ __launch_bounds__(256) void k_xqkv2(const unsigned short* __restrict__ qfrag,
                                               const unsigned short* __restrict__ wfrag,
                                               const float* __restrict__ bn1,
                                               unsigned short* __restrict__ qbf,
                                               unsigned short* __restrict__ kbf,
                                               unsigned short* __restrict__ vbf){
  __shared__ __align__(16) unsigned short Hb[4][2048];
  __shared__ float bnT1[DM];
  const int t = threadIdx.x;
  if (t < DM){
    const float s = bn1[t] * rsqrtf(bn1[3*DM+t] + EPS);
    bnT1[t] = bn1[DM+t] - bn1[2*DM+t]*s;
  }
  __syncthreads();

  const int w = t >> 6, l = t & 63;
  const int p = l & 15, g = l >> 4;
  unsigned short* hb = Hb[w];
  const int hwb = p*128 + ((g & 1) * 4);

  const int ntg = blockIdx.x*4 + w;
  const int b = ntg >> 8, nt = ntg & 255;
  const int pt = b*NN + nt*16 + p;

  const unsigned short* qb = qfrag + ((size_t)(b*256 + nt))*2048 + l*8;
  const bf16x8 f00 = *reinterpret_cast<const bf16x8*>(qb);
  const bf16x8 f01 = *reinterpret_cast<const bf16x8*>(qb + 512);
  const bf16x8 f10 = *reinterpret_cast<const bf16x8*>(qb + 1024);
  const bf16x8 f11 = *reinterpret_cast<const bf16x8*>(qb + 1536);

  X_STEP(0) X_STEP(1) X_STEP(2) X_STEP(3)
  X_STEP(4) X_STEP(5) X_STEP(6) X_STEP(7)

  RD_B()
  QKV_STEP(0, 120, qbf) QKV_STEP(1, 120, qbf) QKV_STEP(2, 120, qbf) QKV_STEP(3, 120, qbf)
  QKV_STEP(4, 120, qbf) QKV_STEP(5, 120, qbf) QKV_STEP(6, 120, qbf) QKV_STEP(7, 120, qbf)
  QKV_STEP(0, 152, kbf) QKV_STEP(1, 152, kbf) QKV_STEP(2, 152, kbf) QKV_STEP(3, 152, kbf)
  QKV_STEP(4, 152, kbf) QKV_STEP(5, 152, kbf) QKV_STEP(6, 152, kbf) QKV_STEP(7, 152, kbf)
  QKV_STEP(0, 184, vbf) QKV_STEP(1, 184, vbf) QKV_STEP(2, 184, vbf) QKV_STEP(3, 184, vbf)
  QKV_STEP(4, 184, vbf) QKV_STEP(5, 184, vbf) QKV_STEP(6, 184, vbf) QKV_STEP(7, 184, vbf)
}

// ---------------------------------------------------------------- fused attention (pe + attn, no intermediate images)
#define H1_STEP(tt) { \
  f32x4 acc = {0.f,0.f,0.f,0.f}; \
  acc = mfma16(FRG(96+(tt)), bv, acc); \
  const f32x4 sh = *reinterpret_cast<const f32x4*>(&bnT[0][(tt)*16 + g*4]); \
  uint2 hp; \
  hp.x = pk2(lrelu(acc[0]+sh[0]), lrelu(acc[1]+sh[1])); \
  hp.y = pk2(lrelu(acc[2]+sh[2]), lrelu(acc[3]+sh[3])); \
  *reinterpret_cast<uint2*>(&hb[hwb + (((tt)*2 + (g>>1))^p)*8]) = hp; }

#define PE_STEP(tt, PE) { \
  f32x4 acc = {0.f,0.f,0.f,0.f}; \
  acc = mfma16(FRG(0+(tt)*4+0), b0, acc); \
  acc = mfma16(FRG(0+(tt)*4+1), b1, acc); \
  acc = mfma16(FRG(0+(tt)*4+2), b2, acc); \
  acc = mfma16(FRG(0+(tt)*4+3), b3, acc); \
  const f32x4 sh = *reinterpret_cast<const f32x4*>(&bnT[1][(tt)*16 + g*4]); \
  PE[0]=lrelu(acc[0]+sh[0]); PE[1]=lrelu(acc[1]+sh[1]); \
  PE[2]=lrelu(acc[2]+sh[2]); PE[3]=lrelu(acc[3]+sh[3]); }

#define VPER_STEP(tt, PE, VPE) { \
  const uint2 du = *reinterpret_cast<const uint2*>(&hb[p*128 + (((tt)*2+(g>>1))^p)*8 + (g&1)*4]); \
  VPE[0] = bfl(du.x)+PE[0]; VPE[1] = bfh(du.x)+PE[1]; \
  VPE[2] = bfl(du.y)+PE[2]; VPE[3] = bfh(du.y)+PE[3]; }

#define QPE_STEP(tt, PE) { \
  const uint2 qu = *reinterpret_cast<const uint2*>(&qbf[(size_t)gp*DM + (tt)*16 + g*4]); \
  uint2 hp; \
  hp.x = pk2(bfl(qu.x)+PE[0], bfh(qu.x)+PE[1]); \
  hp.y = pk2(bfl(qu.y)+PE[2], bfh(qu.y)+PE[3]); \
  *reinterpret_cast<uint2*>(&hb[hwb + (((tt)*2 + (g>>1))^p)*8]) = hp; }

#define G1A_STEP(tt) { \
  f32x4 acc = {0.f,0.f,0.f,0.f}; \
  acc = mfma16(FRG(32+(tt)*4+0), ai0, acc); \
  acc = mfma16(FRG(32+(tt)*4+1), ai1, acc); \
  acc = mfma16(FRG(32+(tt)*4+2), ai2, acc); \
  acc = mfma16(FRG(32+(tt)*4+3), ai3, acc); \
  const f32x4 sh = *reinterpret_cast<const f32x4*>(&bnT[2][(tt)*16 + g*4]); \
  uint2 hp; \
  hp.x = pk2(lrelu(acc[0]+sh[0]), lrelu(acc[1]+sh[1])); \
  hp.y = pk2(lrelu(acc[2]+sh[2]), lrelu(acc[3]+sh[3])); \
  *reinterpret_cast<uint2*>(&hb[hwb + (((tt)*2 + (g>>1))^p)*8]) = hp; }

#define E_STEP(tt, E) { \
  f32x4 acc = {0.f,0.f,0.f,0.f}; \
  acc = mfma16(FRG(64+(tt)*4+0), b0, acc); \
  acc = mfma16(FRG(64+(tt)*4+1), b1, acc); \
  acc = mfma16(FRG(64+(tt)*4+2), b2, acc); \
  acc = mfma16(FRG(64+(tt)*4+3), b3, acc); \
  const f32x4 sh = *reinterpret_cast<const f32x4*>(&bnT[3][(tt)*16 + g*4]); \
  E[0]=lrelu(acc[0]+sh[0])*0.015625f; E[1]=lrelu(acc[1]+sh[1])*0.015625f; \
  E[2]=lrelu(acc[2]+sh[2])*0.015625f; E[3]=lrelu(acc[3]+sh[3])*0.015625f; }

#define EXP0_STEP(E) { \
  E[0]=__expf(E[0]); E[1]=__expf(E[1]); E[2]=__expf(E[2]); E[3]=__expf(E[3]); }

#define REDF_STEP(tt, E, VPE) { \
  const float o0 = redh(E[0]*VPE[0], E[0]); \
  const float o1 = redh(E[1]*VPE[1], E[1]); \
  const float o2 = redh(E[2]*VPE[2], E[2]); \
  const float o3 = redh(E[3]*VPE[3], E[3]); \
  if (p == 0){ \
    uint2 st; st.x = pk2(o0,o1); st.y = pk2(o2,o3); \
    *reinterpret_cast<uint2*>(&resbf[(size_t)gp*DM + (tt)*16 + g*4]) = st; } }

__global__ __launch_bounds__(256, 2) void k_fa(
    const float* __restrict__ pos, const unsigned short* __restrict__ qbf,
    const unsigned short* __restrict__ kbf, const unsigned short* __restrict__ vbf,
    const int* __restrict__ idx_ws, const unsigned short* __restrict__ wfrag,
    const float* __restrict__ bnd1, const float* __restrict__ bnd2,
    const float* __restrict__ bng1, const float* __restrict__ bng2,
    unsigned short* __restrict__ resbf){
  __shared__ __align__(16) unsigned short Hb[4][2048];
  __shared__ float bnT[4][DM];

  const int t = threadIdx.x;
  if (t < DM){
    const float* bp[4] = {bnd1, bnd2, bng1, bng2};
    #pragma unroll
    for (int s4=0;s4<4;s4++){
      const float g = bp[s4][t], be = bp[s4][DM+t], mn = bp[s4][2*DM+t], vr = bp[s4][3*DM+t];
      const float sc = g * rsqrtf(vr + EPS);
      bnT[s4][t] = be - mn*sc;
    }
  }
  __syncthreads();

  const int w = t >> 6, l = t & 63;
  const int p = l & 15, g = l >> 4;
  unsigned short* hb = Hb[w];
  const int hwb = p*128 + ((g & 1) * 4);

  const int gp = blockIdx.x*4 + w;
  const int b = gp >> 12, n = gp & (NN-1);
  const int mi = idx_ws[gp*KK + p];

  uint32_t bw0 = 0u, bw1 = 0u;
  if (g == 0){
    const float* posb = pos + (size_t)b*3*NN;
    const float rx = posb[n]      - posb[mi];
    const float ry = posb[NN+n]   - posb[NN+mi];
    const float rz = posb[2*NN+n] - posb[2*NN+mi];
    bw0 = pk2(rx, ry);
    bw1 = pk2(rz, 0.f);
  }
  u32x4 bwv = {bw0, bw1, 0u, 0u};
  const bf16x8 bv = __builtin_bit_cast(bf16x8, bwv);

  H1_STEP(0) H1_STEP(1) H1_STEP(2) H1_STEP(3)
  H1_STEP(4) H1_STEP(5) H1_STEP(6) H1_STEP(7)

  f32x4 pe0, pe1, pe2, pe3, pe4, pe5, pe6, pe7;
  {
    RD_B()
    PE_STEP(0, pe0) PE_STEP(1, pe1) PE_STEP(2, pe2) PE_STEP(3, pe3)
    PE_STEP(4, pe4) PE_STEP(5, pe5) PE_STEP(6, pe6) PE_STEP(7, pe7)
  }

  f32x4 vp0, vp1, vp2, vp3, vp4, vp5, vp6, vp7;
  {
    const unsigned short* vrow = vbf + ((size_t)(b*NN) + mi)*DM;
    const bf16x8 xv0 = *reinterpret_cast<const bf16x8*>(&vrow[ 0 + g*8]);
    const bf16x8 xv1 = *reinterpret_cast<const bf16x8*>(&vrow[32 + g*8]);
    const bf16x8 xv2 = *reinterpret_cast<const bf16x8*>(&vrow[64 + g*8]);
    const bf16x8 xv3 = *reinterpret_cast<const bf16x8*>(&vrow[96 + g*8]);
    *reinterpret_cast<bf16x8*>(&hb[p*128 + ((0*4+g)^p)*8]) = xv0;
    *reinterpret_cast<bf16x8*>(&hb[p*128 + ((1*4+g)^p)*8]) = xv1;
    *reinterpret_cast<bf16x8*>(&hb[p*128 + ((2*4+g)^p)*8]) = xv2;
    *reinterpret_cast<bf16x8*>(&hb[p*128 + ((3*4+g)^p)*8]) = xv3;
    VPER_STEP(0, pe0, vp0) VPER_STEP(1, pe1, vp1) VPER_STEP(2, pe2, vp2) VPER_STEP(3, pe3, vp3)
    VPER_STEP(4, pe4, vp4) VPER_STEP(5, pe5, vp5) VPER_STEP(6, pe6, vp6) VPER_STEP(7, pe7, vp7)
  }

  QPE_STEP(0, pe0) QPE_STEP(1, pe1) QPE_STEP(2, pe2) QPE_STEP(3, pe3)
  QPE_STEP(4, pe4) QPE_STEP(5, pe5) QPE_STEP(6, pe6) QPE_STEP(7, pe7)

  {
    const unsigned short* krow = kbf + ((size_t)(b*NN) + mi)*DM;
    const bf16x8 xk0 = *reinterpret_cast<const bf16x8*>(&krow[ 0 + g*8]);
    const bf16x8 xk1 = *reinterpret_cast<const bf16x8*>(&krow[32 + g*8]);
    const bf16x8 xk2 = *reinterpret_cast<const bf16x8*>(&krow[64 + g*8]);
    const bf16x8 xk3 = *reinterpret_cast<const bf16x8*>(&krow[96 + g*8]);
    RD_B()
    const bf16x8 ai0 = __builtin_bit_cast(bf16x8, sub8(__builtin_bit_cast(u32x4, b0), __builtin_bit_cast(u32x4, xk0)));
    const bf16x8 ai1 = __builtin_bit_cast(bf16x8, sub8(__builtin_bit_cast(u32x4, b1), __builtin_bit_cast(u32x4, xk1)));
    const bf16x8 ai2 = __builtin_bit_cast(bf16x8, sub8(__builtin_bit_cast(u32x4, b2), __builtin_bit_cast(u32x4, xk2)));
    const bf16x8 ai3 = __builtin_bit_cast(bf16x8, sub8(__builtin_bit_cast(u32x4, b3), __builtin_bit_cast(u32x4, xk3)));
    G1A_STEP(0) G1A_STEP(1) G1A_STEP(2) G1A_STEP(3)
    G1A_STEP(4) G1A_STEP(5) G1A_STEP(6) G1A_STEP(7)
  }

  f32x4 e0, e1, e2, e3, e4, e5, e6, e7;
  {
    RD_B()
    E_STEP(0, e0) E_STEP(1, e1) E_STEP(2, e2) E_STEP(3, e3)
    E_STEP(4, e4) E_STEP(5, e5) E_STEP(6, e6) E_STEP(7, e7)
  }

  EXP0_STEP(e0) EXP0_STEP(e1) EXP0_STEP(e2) EXP0_STEP(e3)
  EXP0_STEP(e4) EXP0_STEP(e5) EXP0_STEP(e6) EXP0_STEP(e7)

  REDF_STEP(0, e0, vp0) REDF_STEP(1, e1, vp1) REDF_STEP(2, e2, vp2) REDF_STEP(3, e3, vp3)
  REDF_STEP(4, e4, vp4) REDF_STEP(5, e5, vp5) REDF_STEP(6, e6, vp6) REDF_STEP(7, e7, vp7)
}

// ---------------------------------------------------------------- out = lrelu(bn2(W2@res)) + feats  (res is bf16)
__global__ __launch_bounds__(256, 1) void k_out(const unsigned short* __restrict__ resbf,
                                             const float* __restrict__ W2,
                                             const float* __restrict__ bn2,
                                             const float* __restrict__ feats,
                                             float* __restrict__ out){
  __shared__ float W2s[DP][DM+4];
  __shared__ float rt[128][DM+4];
  __shared__ float ob[DP][132];
  __shared__ float bS[DP], bT[DP];
  const int t = threadIdx.x;
  const int b = blockIdx.x >> 5;
  const int n0 = (blockIdx.x & 31) * 128;
  for (int i=t; i<DP*DM; i+=256){ W2s[i>>7][i&127] = W2[i]; }
  if (t < DP){
    float g=bn2[t], be=bn2[DP+t], mn=bn2[2*DP+t], vr=bn2[3*DP+t];
    float s = g*rsqrtf(vr+EPS); bS[t]=s; bT[t]=be-mn*s;
  }
  for (int i=t; i<128*(DM/4); i+=256){
    const int j=i>>5, c4=(i&31)*4;
    const ushort4 u = *reinterpret_cast<const ushort4*>(&resbf[((size_t)(b*NN)+n0+j)*DM + c4]);
    rt[j][c4+0] = bf2f(u.x); rt[j][c4+1] = bf2f(u.y);
    rt[j][c4+2] = bf2f(u.z); rt[j][c4+3] = bf2f(u.w);
  }
  __syncthreads();
  const int j = t>>1, cq = t&1;
  float acc[32];
  #pragma unroll
  for (int i=0;i<32;i++) acc[i]=0.f;
  for (int c=0;c<DM;c+=4){
    const float4 rv = *reinterpret_cast<const float4*>(&rt[j][c]);
    #pragma unroll
    for (int i=0;i<32;i++){
      const float4 wv = *reinterpret_cast<const float4*>(&W2s[cq+2*i][c]);
      acc[i] += wv.x*rv.x + wv.y*rv.y + wv.z*rv.z + wv.w*rv.w;
    }
  }
  #pragma unroll
  for (int i=0;i<32;i++) ob[cq+2*i][j] = acc[i];
  __syncthreads();
  for (int i=t; i<DP*128; i+=256){
    const int ch=i>>7, jj=i&127;
    const size_t o = (size_t)b*DP*NN + (size_t)ch*NN + n0 + jj;
    out[o] = lrelu(ob[ch][jj]*bS[ch] + bT[ch]) + feats[o];
  }
}

// ----------------------------------------------------------------
extern "C" void kernel_launch(void* const* d_in, const int* in_sizes, int n_in,
                              void* d_out, int out_size, void* d_ws, size_t ws_size,
                              hipStream_t stream) {
  const float* feats = (const float*)d_in[0];
  const float* pos   = (const float*)d_in[1];
  const float* W1    = (const float*)d_in[2];
  const float* bn1   = (const float*)d_in[3];
  const float* W2    = (const float*)d_in[4];
  const float* bn2   = (const float*)d_in[5];
  const float* Wq    = (const float*)d_in[6];
  const float* Wk    = (const float*)d_in[7];
  const float* Wv    = (const float*)d_in[8];
  const float* Wd1   = (const float*)d_in[9];
  const float* bnd1  = (const float*)d_in[10];
  const float* Wd2   = (const float*)d_in[11];
  const float* bnd2  = (const float*)d_in[12];
  const float* Wg1   = (const float*)d_in[13];
  const float* bng1  = (const float*)d_in[14];
  const float* Wg2   = (const float*)d_in[15];
  const float* bng2  = (const float*)d_in[16];
  float* out = (float*)d_out;

  unsigned short* qbf = (unsigned short*)d_ws;              // 4 MiB
  unsigned short* kbf = qbf + 2097152;                      // 4 MiB
  unsigned short* vbf = kbf + 2097152;                      // 4 MiB
  float* sqn = (float*)(vbf + 2097152);                     // 64 KiB
  int*   idx = (int*)(sqn + 16384);                         // 1 MiB
  unsigned short* wfrag = (unsigned short*)(idx + 262144);  // 216 KiB
  unsigned short* poolu = wfrag + 110592;                   // 20 MiB pool
  // knn phase overlays
  float* fpm = (float*)poolu;                               // 4 MiB
  unsigned short* cfrag = (unsigned short*)(fpm + 1048576); // 4 MiB
  unsigned short* qfrag = cfrag + 2097152;                  // 4 MiB
  uint32_t* cand = (uint32_t*)(qfrag + 2097152);            // 8 MiB (128 packed/query)
  // post-refine overlay: res (bf16, 4 MiB) over fpm (dead after k_refine3)
  unsigned short* resbf = poolu;

  k_fprep  <<<NB*(NN/64), 256, 0, stream>>>(feats, cfrag, qfrag, fpm, sqn);
  k_knn5   <<<NB*512, 256, 0, stream>>>(cfrag, qfrag, sqn, cand);
  k_refine3<<<(NB*NN)/4, 256, 0, stream>>>(fpm, sqn, cand, idx);
  k_wprep2 <<<54, 256, 0, stream>>>(Wd1, bnd1, Wd2, bnd2, Wg1, bng1, Wg2, bng2,
                                    W1, bn1, Wq, Wk, Wv, wfrag);
  k_xqkv2  <<<NB*64, 256, 0, stream>>>(qfrag, wfrag, bn1, qbf, kbf, vbf);
  k_fa     <<<(NB*NN)/4, 256, 0, stream>>>(pos, qbf, kbf, vbf, idx, wfrag,
                                           bnd1, bnd2, bng1, bng2, resbf);
  k_out    <<<NB*(NN/128), 256, 0, stream>>>(resbf, W2, bn2, feats, out);
}